// Round 1
// baseline (1207.882 us; speedup 1.0000x reference)
//
#include <hip/hip_runtime.h>
#include <hip/hip_bf16.h>

#define B_   2
#define T_   2048
#define DM   2048
#define H_   16
#define DK_  128
#define DV_  128
#define CDIM 6144
#define EPSF 1e-6f
#define CGRP 16   // scan: timesteps staged per LDS group

typedef __hip_bfloat16 bf16;
typedef short bf16x8 __attribute__((ext_vector_type(8)));
typedef float f32x4 __attribute__((ext_vector_type(4)));

// ---- workspace layout (bytes); peak = 227,540,992 < proven-OK 228,589,568 --
#define FLAG_OFF   0
#define DT_OFF     1024
#define AL_OFF     2048
#define NW_OFF     4096
#define CW_OFF     8192          // 98,304 B -> 106,496
#define WBF_OFF    131072        // f32 131,072 -> 262,144
#define WAF_OFF    262144        // -> 393,216
#define BETA_OFF   393216        // 262,144 -> 655,360
#define DEC_OFF    655360        // -> 917,504
#define XH_OFF     1048576       // 16,777,216 -> 17,825,792
#define XL_OFF     17825792      // -> 34,603,008
#define WQH_OFF    34603008      // 25,165,824 -> 59,768,832
#define WQL_OFF    59768832      // -> 84,934,656
#define WZ_OFF     84934656      // 8,388,608 -> 93,323,264
#define MIX_OFF    101711872     // f32 100,663,296 -> 202,375,168
#define WOUT_OFF   202375168     // 8,388,608 -> 210,763,776
#define Z_OFF      210763776     // bf16 16,777,216 -> 227,540,992 (peak)
#define Y_OFF      1048576       // f32 100,663,296 -> 101,711,872 (overlay)
#define O_OFF      101711872     // f32 33,554,432 -> 135,266,304 (over MIX)
#define ONH_OFF    1048576       // 16,777,216 -> 17,825,792 (over dead Y)
#define ONL_OFF    17825792      // -> 34,603,008

__device__ inline float bf2f(unsigned int u) {
  union { unsigned int i; float f; } v; v.i = u << 16; return v.f;
}
__device__ inline void up8(uint4 p, float* d) {
  d[0] = bf2f(p.x & 0xffffu); d[1] = bf2f(p.x >> 16);
  d[2] = bf2f(p.y & 0xffffu); d[3] = bf2f(p.y >> 16);
  d[4] = bf2f(p.z & 0xffffu); d[5] = bf2f(p.z >> 16);
  d[6] = bf2f(p.w & 0xffffu); d[7] = bf2f(p.w >> 16);
}
__device__ inline void gl2lds16(const bf16* g, bf16* lds) {
  __builtin_amdgcn_global_load_lds(
      (const __attribute__((address_space(1))) unsigned int*)g,
      (__attribute__((address_space(3))) unsigned int*)lds, 16, 0, 0);
}

// DPP butterfly add over a 16-lane row — stays on the VALU pipe.
// (xor16 would need ds_swizzle = LDS pipe on the serial chain: R8 regression.)
template <int CTRL>
__device__ inline float radd(float v) {
  int t = __builtin_amdgcn_update_dpp(0, __float_as_int(v), CTRL, 0xF, 0xF, true);
  return v + __int_as_float(t);
}
__device__ inline float row_sum16(float v) {
  v = radd<0xB1>(v);   // quad_perm [1,0,3,2] : + xor1
  v = radd<0x4E>(v);   // quad_perm [2,3,0,1] : + xor2
  v = radd<0x141>(v);  // row_half_mirror     : + xor4
  v = radd<0x140>(v);  // row_mirror          : + xor8
  return v;
}

// ---------------- dtype detector: flag=1 if inputs are f32 -----------------
__global__ __launch_bounds__(256) void detect_dtype(
    const unsigned short* __restrict__ xh, int* __restrict__ flag) {
  __shared__ int cnt;
  if (threadIdx.x == 0) cnt = 0;
  __syncthreads();
  int c = 0;
  for (int i = threadIdx.x; i < 8192; i += 256) {
    unsigned int e = (xh[i] >> 7) & 0xFFu;
    if (e > 140u) c++;
  }
  atomicAdd(&cnt, c);
  __syncthreads();
  if (threadIdx.x == 0) *flag = (cnt > 512) ? 1 : 0;
}

// ---------------- fused canonicalize: 10 segments in one launch ------------
// mode 0: ->f32, mode 1: ->bf16, mode 2: ->split(hi,lo)
__device__ inline void canon_seg(const void* in, char* d0, char* d1, int n,
                                 int mode, int f32in, int i) {
  if (i >= n) return;
  float v[8];
  if (f32in) {
    const float* f = (const float*)in;
    *(float4*)(v)     = *(const float4*)(f + i);
    *(float4*)(v + 4) = *(const float4*)(f + i + 4);
  } else {
    up8(*(const uint4*)((const bf16*)in + i), v);
  }
  if (mode == 0) {
    *(float4*)((float*)d0 + i)     = *(const float4*)(v);
    *(float4*)((float*)d0 + i + 4) = *(const float4*)(v + 4);
  } else if (mode == 1) {
    bf16 t[8];
#pragma unroll
    for (int j = 0; j < 8; j++) t[j] = __float2bfloat16(v[j]);
    *(uint4*)((bf16*)d0 + i) = *(const uint4*)t;
  } else {
    bf16 th[8], tl[8];
#pragma unroll
    for (int j = 0; j < 8; j++) {
      th[j] = __float2bfloat16(v[j]);
      tl[j] = __float2bfloat16(v[j] - __bfloat162float(th[j]));
    }
    *(uint4*)((bf16*)d0 + i) = *(const uint4*)th;
    *(uint4*)((bf16*)d1 + i) = *(const uint4*)tl;
  }
}

// block ranges (2048 elems per block):
// [0,1) dt | [1,2) al | [2,3) nw | [3,15) cw | [15,31) wb | [31,47) wa |
// [47,4143) x-split | [4143,10287) wqkv-split | [10287,12335) wz |
// [12335,14383) wout
__global__ __launch_bounds__(256) void canon_all(
    const void* x, const void* wqkv, const void* cw, const void* wz,
    const void* wb, const void* wa, const void* dt, const void* al,
    const void* nw, const void* wout, char* ws, const int* __restrict__ flag) {
  const int bk = blockIdx.x;
  const int f32in = *flag;
  if (bk < 1)
    canon_seg(dt, ws + DT_OFF, 0, 16, 0, f32in, (bk - 0) * 2048 + threadIdx.x * 8);
  else if (bk < 2)
    canon_seg(al, ws + AL_OFF, 0, 16, 0, f32in, (bk - 1) * 2048 + threadIdx.x * 8);
  else if (bk < 3)
    canon_seg(nw, ws + NW_OFF, 0, 128, 0, f32in, (bk - 2) * 2048 + threadIdx.x * 8);
  else if (bk < 15)
    canon_seg(cw, ws + CW_OFF, 0, CDIM * 4, 0, f32in, (bk - 3) * 2048 + threadIdx.x * 8);
  else if (bk < 31)
    canon_seg(wb, ws + WBF_OFF, 0, H_ * DM, 0, f32in, (bk - 15) * 2048 + threadIdx.x * 8);
  else if (bk < 47)
    canon_seg(wa, ws + WAF_OFF, 0, H_ * DM, 0, f32in, (bk - 31) * 2048 + threadIdx.x * 8);
  else if (bk < 4143)
    canon_seg(x, ws + XH_OFF, ws + XL_OFF, B_ * T_ * DM, 2, f32in,
              (bk - 47) * 2048 + threadIdx.x * 8);
  else if (bk < 10287)
    canon_seg(wqkv, ws + WQH_OFF, ws + WQL_OFF, CDIM * DM, 2, f32in,
              (bk - 4143) * 2048 + threadIdx.x * 8);
  else if (bk < 12335)
    canon_seg(wz, ws + WZ_OFF, 0, H_ * DV_ * DM, 1, f32in,
              (bk - 10287) * 2048 + threadIdx.x * 8);
  else
    canon_seg(wout, ws + WOUT_OFF, 0, DM * H_ * DV_, 1, f32in,
              (bk - 12335) * 2048 + threadIdx.x * 8);
}

// -------- GEMM split x split: C = (Ah+Al)(Bh+Bl)^T (3-term), f32 out -------
__global__ __launch_bounds__(256) void gemm_ss(
    const bf16* __restrict__ Ah, const bf16* __restrict__ Al,
    const bf16* __restrict__ Bh, const bf16* __restrict__ Bl,
    float* __restrict__ C, int M, int N, int K) {
  __shared__ __align__(16) bf16 sAh[128 * 32];
  __shared__ __align__(16) bf16 sAl[128 * 32];
  __shared__ __align__(16) bf16 sBh[128 * 32];
  __shared__ __align__(16) bf16 sBl[128 * 32];
  const int tid  = threadIdx.x;
  const int wave = tid >> 6;
  const int lane = tid & 63;
  const int m0 = blockIdx.y * 128;
  const int n0 = blockIdx.x * 128;
  const int wm = (wave >> 1) * 64;
  const int wn = (wave & 1) * 64;
  const int lrow = lane & 15;
  const int kq   = lane >> 4;

  f32x4 acc[4][4];
#pragma unroll
  for (int i = 0; i < 4; i++)
#pragma unroll
    for (int j = 0; j < 4; j++) acc[i][j] = (f32x4){0.f, 0.f, 0.f, 0.f};

  const int row0 = tid >> 2;
  const int cb   = (tid & 3) * 8;
  const size_t aoff = (size_t)(m0 + row0) * K + cb;
  const size_t boff = (size_t)(n0 + row0) * K + cb;

  for (int k0 = 0; k0 < K; k0 += 32) {
    gl2lds16(Ah + aoff + k0,                  sAh + wave * 512);
    gl2lds16(Ah + aoff + k0 + (size_t)64 * K, sAh + 2048 + wave * 512);
    gl2lds16(Al + aoff + k0,                  sAl + wave * 512);
    gl2lds16(Al + aoff + k0 + (size_t)64 * K, sAl + 2048 + wave * 512);
    gl2lds16(Bh + boff + k0,                  sBh + wave * 512);
    gl2lds16(Bh + boff + k0 + (size_t)64 * K, sBh + 2048 + wave * 512);
    gl2lds16(Bl + boff + k0,                  sBl + wave * 512);
    gl2lds16(Bl + boff + k0 + (size_t)64 * K, sBl + 2048 + wave * 512);
    __syncthreads();

    bf16x8 afh[4], afl[4], bfh[4], bfl[4];
#pragma unroll
    for (int i = 0; i < 4; i++) {
      const int ao = (wm + i * 16 + lrow) * 32 + kq * 8;
      const int bo = (wn + i * 16 + lrow) * 32 + kq * 8;
      afh[i] = *(const bf16x8*)(sAh + ao);
      afl[i] = *(const bf16x8*)(sAl + ao);
      bfh[i] = *(const bf16x8*)(sBh + bo);
      bfl[i] = *(const bf16x8*)(sBl + bo);
    }
#pragma unroll
    for (int i = 0; i < 4; i++)
#pragma unroll
      for (int j = 0; j < 4; j++) {
        acc[i][j] = __builtin_amdgcn_mfma_f32_16x16x32_bf16(afh[i], bfh[j], acc[i][j], 0, 0, 0);
        acc[i][j] = __builtin_amdgcn_mfma_f32_16x16x32_bf16(afh[i], bfl[j], acc[i][j], 0, 0, 0);
        acc[i][j] = __builtin_amdgcn_mfma_f32_16x16x32_bf16(afl[i], bfh[j], acc[i][j], 0, 0, 0);
      }
    __syncthreads();
  }

#pragma unroll
  for (int i = 0; i < 4; i++) {
    const int r0 = m0 + wm + i * 16 + kq * 4;
#pragma unroll
    for (int j = 0; j < 4; j++) {
      const int c = n0 + wn + j * 16 + lrow;
#pragma unroll
      for (int r = 0; r < 4; r++)
        C[(size_t)(r0 + r) * N + c] = acc[i][j][r];
    }
  }
}

// -------- GEMM split-A x single-B: C = (Ah+Al)B^T. OMODE 0: bf16, 2: dual --
template <int OMODE>
__global__ __launch_bounds__(256) void gemm_bt_split(
    const bf16* __restrict__ Ah, const bf16* __restrict__ Al,
    const bf16* __restrict__ Bm, void* __restrict__ C,
    int M, int N, int K, const int* __restrict__ flag) {
  __shared__ __align__(16) bf16 sAh[128 * 32];
  __shared__ __align__(16) bf16 sAl[128 * 32];
  __shared__ __align__(16) bf16 sB[128 * 32];
  const int tid  = threadIdx.x;
  const int wave = tid >> 6;
  const int lane = tid & 63;
  const int m0 = blockIdx.y * 128;
  const int n0 = blockIdx.x * 128;
  const int wm = (wave >> 1) * 64;
  const int wn = (wave & 1) * 64;
  const int lrow = lane & 15;
  const int kq   = lane >> 4;

  f32x4 acc[4][4];
#pragma unroll
  for (int i = 0; i < 4; i++)
#pragma unroll
    for (int j = 0; j < 4; j++) acc[i][j] = (f32x4){0.f, 0.f, 0.f, 0.f};

  const int row0 = tid >> 2;
  const int cb   = (tid & 3) * 8;
  const size_t aoff = (size_t)(m0 + row0) * K + cb;
  const size_t boff = (size_t)(n0 + row0) * K + cb;

  for (int k0 = 0; k0 < K; k0 += 32) {
    gl2lds16(Ah + aoff + k0,                  sAh + wave * 512);
    gl2lds16(Ah + aoff + k0 + (size_t)64 * K, sAh + 2048 + wave * 512);
    gl2lds16(Al + aoff + k0,                  sAl + wave * 512);
    gl2lds16(Al + aoff + k0 + (size_t)64 * K, sAl + 2048 + wave * 512);
    gl2lds16(Bm + boff + k0,                  sB + wave * 512);
    gl2lds16(Bm + boff + k0 + (size_t)64 * K, sB + 2048 + wave * 512);
    __syncthreads();

    bf16x8 afh[4], afl[4], bfr[4];
#pragma unroll
    for (int i = 0; i < 4; i++) {
      const int ao = (wm + i * 16 + lrow) * 32 + kq * 8;
      afh[i] = *(const bf16x8*)(sAh + ao);
      afl[i] = *(const bf16x8*)(sAl + ao);
      bfr[i] = *(const bf16x8*)(sB + (wn + i * 16 + lrow) * 32 + kq * 8);
    }
#pragma unroll
    for (int i = 0; i < 4; i++)
#pragma unroll
      for (int j = 0; j < 4; j++) {
        acc[i][j] = __builtin_amdgcn_mfma_f32_16x16x32_bf16(afh[i], bfr[j], acc[i][j], 0, 0, 0);
        acc[i][j] = __builtin_amdgcn_mfma_f32_16x16x32_bf16(afl[i], bfr[j], acc[i][j], 0, 0, 0);
      }
    __syncthreads();
  }

  const int f32o = (OMODE == 2) ? *flag : 0;
#pragma unroll
  for (int i = 0; i < 4; i++) {
    const int r0 = m0 + wm + i * 16 + kq * 4;
#pragma unroll
    for (int j = 0; j < 4; j++) {
      const int c = n0 + wn + j * 16 + lrow;
#pragma unroll
      for (int r = 0; r < 4; r++) {
        const size_t idx = (size_t)(r0 + r) * N + c;
        if (f32o) ((float*)C)[idx] = acc[i][j][r];
        else      ((bf16*)C)[idx] = __float2bfloat16(acc[i][j][r]);
      }
    }
  }
}

// ---------------- conv (causal, KW=4) + SiLU + per-head l2norm (f32) -------
__global__ __launch_bounds__(128) void conv_silu_norm(
    const float* __restrict__ mixed, const float* __restrict__ convw,
    float* __restrict__ y) {
  const int g = blockIdx.x;
  const int n = blockIdx.y;
  const int t = n & (T_ - 1);
  const int c = g * 128 + threadIdx.x;

  const float4 w = *(const float4*)(convw + (size_t)c * 4);

  const float* mc = mixed + (size_t)n * CDIM + c;
  float a = mc[0] * w.w;
  if (t >= 1) a += mc[-CDIM] * w.z;
  if (t >= 2) a += mc[-2 * CDIM] * w.y;
  if (t >= 3) a += mc[-3 * CDIM] * w.x;
  float s = a / (1.f + expf(-a));

  if (g < 32) {
    float ss = s * s;
#pragma unroll
    for (int o = 32; o > 0; o >>= 1) ss += __shfl_xor(ss, o);
    __shared__ float red[2];
    if ((threadIdx.x & 63) == 0) red[threadIdx.x >> 6] = ss;
    __syncthreads();
    s *= rsqrtf(red[0] + red[1] + EPSF);
  }
  y[(size_t)n * CDIM + c] = s;
}

// ---------------- gate projections: beta, decay (full f32) -----------------
__global__ __launch_bounds__(256) void gates_kernel(
    const bf16* __restrict__ xh, const bf16* __restrict__ xl,
    const float* __restrict__ w_b, const float* __restrict__ w_a,
    const float* __restrict__ dtb, const float* __restrict__ alog,
    float* __restrict__ beta, float* __restrict__ decay) {
  const int n = blockIdx.x, tid = threadIdx.x;
  __shared__ float xs[DM];
  __shared__ float red[32][8];
  {
    uint4 ph = ((const uint4*)(xh + (size_t)n * DM))[tid];
    uint4 pl = ((const uint4*)(xl + (size_t)n * DM))[tid];
    float h[8], l[8]; up8(ph, h); up8(pl, l);
    const int b = tid * 8;
#pragma unroll
    for (int j = 0; j < 8; j++) xs[b + j] = h[j] + l[j];
  }
  __syncthreads();
  const int hh = tid >> 3, part = tid & 7;
  const float* wrow =
      (hh < 16 ? w_b + (size_t)hh * DM : w_a + (size_t)(hh - 16) * DM) + part * 256;
  const float* xp = xs + part * 256;
  float sum = 0.f;
#pragma unroll 4
  for (int i = 0; i < 256; i += 4) {
    float4 p = *(const float4*)(wrow + i);
    sum += xp[i + 0] * p.x + xp[i + 1] * p.y + xp[i + 2] * p.z + xp[i + 3] * p.w;
  }
  red[hh][part] = sum;
  __syncthreads();
  if (tid < 32) {
    float d = 0.f;
#pragma unroll
    for (int p = 0; p < 8; p++) d += red[tid][p];
    if (tid < 16) {
      beta[(size_t)n * H_ + tid] = 1.f / (1.f + expf(-d));
    } else {
      const int h = tid - 16;
      float u = d + dtb[h];
      float sp = (u > 20.f) ? u : log1pf(expf(u));
      decay[(size_t)n * H_ + h] = expf(-expf(alog[h]) * sp);
    }
  }
}

// ---------------- delta-rule scan: LDS-staged, all-DPP, deferred op --------
// R7-proven config: 382 us, 0 bank conflicts. grid (DV/16, H, B), block 256
// = 16 kg x 16 vl; lane k-slice {kg*4..+3} u {64+kg*4..+3} (16B LDS stride,
// free 2-way aliasing); 16-lane all-DPP reduction (VALU pipe only).
__global__ __launch_bounds__(256, 1) void scan_kernel(
    const float* __restrict__ y, const float* __restrict__ beta,
    const float* __restrict__ decay, float* __restrict__ o) {
  const int vb = blockIdx.x, h = blockIdx.y, b = blockIdx.z;
  const int tid = threadIdx.x;
  const int kg = tid & 15;
  const int vl = tid >> 4;

  __shared__ __align__(16) float sq[2][CGRP][128];
  __shared__ __align__(16) float sk[2][CGRP][128];
  __shared__ __align__(16) float sv[2][CGRP][16];
  __shared__ float sd[2][CGRP];
  __shared__ float sb[2][CGRP];

  const size_t rowbase = (size_t)b * T_ * CDIM;
  const int qoff = h * 128;
  const int koff = 2048 + h * 128;
  const int voff = 4096 + h * 128 + vb * 16;
  const float* bb = beta + (size_t)b * T_ * H_ + h;
  const float* db = decay + (size_t)b * T_ * H_ + h;
  float* ob = o + (size_t)b * T_ * (H_ * DV_) + h * 128 + vb * 16 + vl;

  const int ls = tid >> 4;       // staging: step within group
  const int lj = tid & 15;       // staging: float4 pair {lj*4, 64+lj*4}

  float S[8];
#pragma unroll
  for (int j = 0; j < 8; j++) S[j] = 0.f;

  float4 ga0, ga1, gb0, gb1, gv4;
  float gdd = 0.f, gbt = 0.f;

#define STAGE_ISSUE(t0)                                                      \
  {                                                                          \
    const float* r = y + rowbase + (size_t)((t0) + ls) * CDIM;               \
    ga0 = *(const float4*)(r + qoff + lj * 4);                               \
    ga1 = *(const float4*)(r + qoff + 64 + lj * 4);                          \
    gb0 = *(const float4*)(r + koff + lj * 4);                               \
    gb1 = *(const float4*)(r + koff + 64 + lj * 4);                          \
    if (tid < 64)                                                            \
      gv4 = *(const float4*)(y + rowbase + (size_t)((t0) + (tid >> 2)) * CDIM\
                             + voff + (tid & 3) * 4);                        \
    if (tid < 16) gdd = db[(size_t)((t0) + tid) * H_];                       \
    else if (tid < 32) gbt = bb[(size_t)((t0) + tid - 16) * H_];             \
  }

#define STAGE_WRITE(buf)                                                     \
  {                                                                          \
    *(float4*)&sq[buf][ls][lj * 4]      = ga0;                               \
    *(float4*)&sq[buf][ls][64 + lj * 4] = ga1;                               \
    *(float4*)&sk[buf][ls][lj * 4]      = gb0;                               \
    *(float4*)&sk[buf][ls][64 + lj * 4] = gb1;                               \
    if (tid < 64) *(float4*)&sv[buf][tid >> 2][(tid & 3) * 4] = gv4;         \
    if (tid < 16) sd[buf][tid] = gdd;                                        \
    else if (tid < 32) sb[buf][tid - 16] = gbt;                              \
  }

#define READ_STEP(buf, s, qd, kd, vvd, ddd, btd)                             \
  {                                                                          \
    *(float4*)(qd)       = *(const float4*)&sq[buf][s][kg * 4];              \
    *(float4*)((qd) + 4) = *(const float4*)&sq[buf][s][64 + kg * 4];         \
    *(float4*)(kd)       = *(const float4*)&sk[buf][s][kg * 4];              \
    *(float4*)((kd) + 4) = *(const float4*)&sk[buf][s][64 + kg * 4];         \
    vvd = sv[buf][s][vl]; ddd = sd[buf][s]; btd = sb[buf][s];                \
  }

  // prime group 0
  STAGE_ISSUE(0);
  STAGE_WRITE(0);
  __syncthreads();

  float q[8], k[8], nq[8], nk[8];
  float vv, dd, bt, nvv, ndd, nbt;
  float pp[CGRP];
  READ_STEP(0, 0, q, k, vv, dd, bt);

  const int NGRP = T_ / CGRP;
  for (int g = 0; g < NGRP; g++) {
    const int cbuf = g & 1, nbuf = cbuf ^ 1;
    const bool more = (g + 1 < NGRP);
    if (more) STAGE_ISSUE((g + 1) * CGRP);
#pragma unroll
    for (int s = 0; s < CGRP; s++) {
      if (s < CGRP - 1) READ_STEP(cbuf, s + 1, nq, nk, nvv, ndd, nbt);
      // kv = k . S, tree + DPP rowsum (the serial chain)
      float t0 = fmaf(S[1], k[1], S[0] * k[0]);
      float t1 = fmaf(S[3], k[3], S[2] * k[2]);
      float t2 = fmaf(S[5], k[5], S[4] * k[4]);
      float t3 = fmaf(S[7], k[7], S[6] * k[6]);
      float kv = (t0 + t1) + (t2 + t3);
      kv = row_sum16(kv);
      const float u = fmaf(-dd, kv, vv) * bt;
#pragma unroll
      for (int j = 0; j < 8; j++) S[j] = fmaf(dd, S[j], k[j] * u);
      // op partial only; rowsum + store deferred to group end
      float p0 = fmaf(S[1], q[1], S[0] * q[0]);
      float p1 = fmaf(S[3], q[3], S[2] * q[2]);
      float p2 = fmaf(S[5], q[5], S[4] * q[4]);
      float p3 = fmaf(S[7], q[7], S[6] * q[6]);
      pp[s] = (p0 + p1) + (p2 + p3);
      if (s < CGRP - 1) {
#pragma unroll
        for (int j = 0; j < 8; j++) { q[j] = nq[j]; k[j] = nk[j]; }
        vv = nvv; dd = ndd; bt = nbt;
      }
    }
    // deferred: 16 independent rowsums (pipelined DPP) + stores
#pragma unroll
    for (int s = 0; s < CGRP; s++) pp[s] = row_sum16(pp[s]);
    if (kg == 0) {
#pragma unroll
      for (int s = 0; s < CGRP; s++)
        ob[(size_t)(g * CGRP + s) * (H_ * DV_)] = pp[s];
    }
    if (more) {
      STAGE_WRITE(nbuf);
      __syncthreads();
      READ_STEP(nbuf, 0, q, k, vv, dd, bt);
    }
  }
#undef STAGE_ISSUE
#undef STAGE_WRITE
#undef READ_STEP
}

// -------- gated RMSNorm + SiLU(z) gate -> split bf16 (hi + lo) -------------
__global__ __launch_bounds__(128) void norm_gate(
    const float* __restrict__ o, const bf16* __restrict__ z,
    const float* __restrict__ norm_w, bf16* __restrict__ on_hi,
    bf16* __restrict__ on_lo) {
  const int n = blockIdx.x, h = blockIdx.y, v = threadIdx.x;
  const size_t idx = (size_t)n * (H_ * DV_) + h * 128 + v;
  const float ov = o[idx];
  float ss = ov * ov;
#pragma unroll
  for (int w = 32; w > 0; w >>= 1) ss += __shfl_xor(ss, w);
  __shared__ float red[2];
  if ((v & 63) == 0) red[v >> 6] = ss;
  __syncthreads();
  const float ms = (red[0] + red[1]) * (1.f / 128.f);
  const float zv = __bfloat162float(z[idx]);
  const float res = ov * rsqrtf(ms + EPSF) * norm_w[v] *
                    (zv / (1.f + expf(-zv)));
  const bf16 hi = __float2bfloat16(res);
  on_hi[idx] = hi;
  on_lo[idx] = __float2bfloat16(res - __bfloat162float(hi));
}

// ---------------------------------------------------------------------------
extern "C" void kernel_launch(void* const* d_in, const int* in_sizes, int n_in,
                              void* d_out, int out_size, void* d_ws, size_t ws_size,
                              hipStream_t stream) {
  const int NT = B_ * T_;  // 4096
  char* ws = (char*)d_ws;
  int*   flag   = (int*)(ws + FLAG_OFF);
  float* dt_f   = (float*)(ws + DT_OFF);
  float* al_f   = (float*)(ws + AL_OFF);
  float* nw_f   = (float*)(ws + NW_OFF);
  float* cw_f   = (float*)(ws + CW_OFF);
  float* wb_f   = (float*)(ws + WBF_OFF);
  float* wa_f   = (float*)(ws + WAF_OFF);
  float* betab  = (float*)(ws + BETA_OFF);
  float* decayb = (float*)(ws + DEC_OFF);
  bf16*  x_hi   = (bf16*)(ws + XH_OFF);
  bf16*  x_lo   = (bf16*)(ws + XL_OFF);
  bf16*  wq_hi  = (bf16*)(ws + WQH_OFF);
  bf16*  wq_lo  = (bf16*)(ws + WQL_OFF);
  bf16*  wz_bf  = (bf16*)(ws + WZ_OFF);
  float* mixed  = (float*)(ws + MIX_OFF);
  bf16*  wout_bf= (bf16*)(ws + WOUT_OFF);
  bf16*  z      = (bf16*)(ws + Z_OFF);
  float* y      = (float*)(ws + Y_OFF);
  float* o      = (float*)(ws + O_OFF);
  bf16*  on_hi  = (bf16*)(ws + ONH_OFF);
  bf16*  on_lo  = (bf16*)(ws + ONL_OFF);

  // 0. detect input dtype (flag=1 -> f32)
  detect_dtype<<<1, 256, 0, stream>>>((const unsigned short*)d_in[0], flag);

  // 1. canonicalize everything in one launch
  canon_all<<<14383, 256, 0, stream>>>(
      d_in[0], d_in[1], d_in[2], d_in[3], d_in[4], d_in[5], d_in[6], d_in[7],
      d_in[8], d_in[9], ws, flag);

  // 2. gates (f32-precision beta/decay)
  gates_kernel<<<NT, 256, 0, stream>>>(x_hi, x_lo, wb_f, wa_f, dt_f, al_f,
                                       betab, decayb);
  // 3. mixed = x @ w_qkv^T  (split x split, 3-term) -> f32
  gemm_ss<<<dim3(CDIM / 128, NT / 128), 256, 0, stream>>>(
      x_hi, x_lo, wq_hi, wq_lo, mixed, NT, CDIM, DM);
  // 4. z = x @ w_z^T  (split-A) -> bf16
  gemm_bt_split<0><<<dim3((H_ * DV_) / 128, NT / 128), 256, 0, stream>>>(
      x_hi, x_lo, wz_bf, z, NT, H_ * DV_, DM, flag);
  // 5. conv + SiLU + l2norm -> y f32 (overlays dead x/wq/wz)
  conv_silu_norm<<<dim3(CDIM / 128, NT), 128, 0, stream>>>(mixed, cw_f, y);
  // 6. delta-rule scan -> o f32 (overlays dead mixed)
  scan_kernel<<<dim3(DV_ / 16, H_, B_), 256, 0, stream>>>(y, betab, decayb, o);
  // 7. gated RMSNorm -> on hi/lo (overlays dead y)
  norm_gate<<<dim3(NT, H_), 128, 0, stream>>>(o, z, nw_f, on_hi, on_lo);
  // 8. out = on @ w_out^T (split-A, dual-dtype out)
  gemm_bt_split<2><<<dim3(DM / 128, NT / 128), 256, 0, stream>>>(
      on_hi, on_lo, wout_bf, d_out, NT, DM, H_ * DV_, flag);
}

// Round 2
// 1095.631 us; speedup vs baseline: 1.1025x; 1.1025x over previous
//
#include <hip/hip_runtime.h>
#include <hip/hip_bf16.h>

#define B_   2
#define T_   2048
#define DM   2048
#define H_   16
#define DK_  128
#define DV_  128
#define CDIM 6144
#define EPSF 1e-6f
#define CGRP 16   // scan: timesteps staged per LDS group

typedef __hip_bfloat16 bf16;
typedef _Float16 f16;
typedef short bf16x8 __attribute__((ext_vector_type(8)));
typedef _Float16 f16x8 __attribute__((ext_vector_type(8)));
typedef float f32x4 __attribute__((ext_vector_type(4)));

// ---- workspace layout (bytes); peak = 227,540,992 < proven-OK 228,589,568 --
// R1: GEMM dtype bf16-split -> fp16. x: fp16 hi/lo; wqkv/wz/wout: fp16 single.
// Offsets unchanged (fp16 == 2 B like bf16); WQL region now dead.
#define FLAG_OFF   0
#define DT_OFF     1024
#define AL_OFF     2048
#define NW_OFF     4096
#define CW_OFF     8192          // 98,304 B -> 106,496
#define WBF_OFF    131072        // f32 131,072 -> 262,144
#define WAF_OFF    262144        // -> 393,216
#define BETA_OFF   393216        // 262,144 -> 655,360
#define DEC_OFF    655360        // -> 917,504
#define XH_OFF     1048576       // 16,777,216 -> 17,825,792
#define XL_OFF     17825792      // -> 34,603,008
#define WQH_OFF    34603008      // 25,165,824 -> 59,768,832
#define WQL_OFF    59768832      // (dead in R1)
#define WZ_OFF     84934656      // 8,388,608 -> 93,323,264
#define MIX_OFF    101711872     // f32 100,663,296 -> 202,375,168
#define WOUT_OFF   202375168     // 8,388,608 -> 210,763,776
#define Z_OFF      210763776     // bf16 16,777,216 -> 227,540,992 (peak)
#define Y_OFF      1048576       // f32 100,663,296 -> 101,711,872 (overlay)
#define O_OFF      101711872     // f32 33,554,432 -> 135,266,304 (over MIX)
#define ONH_OFF    1048576       // 16,777,216 -> 17,825,792 (over dead Y)

__device__ inline float bf2f(unsigned int u) {
  union { unsigned int i; float f; } v; v.i = u << 16; return v.f;
}
__device__ inline void up8(uint4 p, float* d) {
  d[0] = bf2f(p.x & 0xffffu); d[1] = bf2f(p.x >> 16);
  d[2] = bf2f(p.y & 0xffffu); d[3] = bf2f(p.y >> 16);
  d[4] = bf2f(p.z & 0xffffu); d[5] = bf2f(p.z >> 16);
  d[6] = bf2f(p.w & 0xffffu); d[7] = bf2f(p.w >> 16);
}
// fp16 x8 unpack (v_cvt_f32_f16)
__device__ inline void up8h(uint4 p, float* d) {
  union { unsigned int i; _Float16 h[2]; } c;
  c.i = p.x; d[0] = (float)c.h[0]; d[1] = (float)c.h[1];
  c.i = p.y; d[2] = (float)c.h[0]; d[3] = (float)c.h[1];
  c.i = p.z; d[4] = (float)c.h[0]; d[5] = (float)c.h[1];
  c.i = p.w; d[6] = (float)c.h[0]; d[7] = (float)c.h[1];
}
__device__ inline void gl2lds16(const void* g, void* lds) {
  __builtin_amdgcn_global_load_lds(
      (const __attribute__((address_space(1))) unsigned int*)g,
      (__attribute__((address_space(3))) unsigned int*)lds, 16, 0, 0);
}

// DPP butterfly add over a 16-lane row — stays on the VALU pipe.
template <int CTRL>
__device__ inline float radd(float v) {
  int t = __builtin_amdgcn_update_dpp(0, __float_as_int(v), CTRL, 0xF, 0xF, true);
  return v + __int_as_float(t);
}
__device__ inline float row_sum16(float v) {
  v = radd<0xB1>(v);   // quad_perm [1,0,3,2] : + xor1
  v = radd<0x4E>(v);   // quad_perm [2,3,0,1] : + xor2
  v = radd<0x141>(v);  // row_half_mirror     : + xor4
  v = radd<0x140>(v);  // row_mirror          : + xor8
  return v;
}

// ---------------- dtype detector: flag=1 if inputs are f32 -----------------
__global__ __launch_bounds__(256) void detect_dtype(
    const unsigned short* __restrict__ xh, int* __restrict__ flag) {
  __shared__ int cnt;
  if (threadIdx.x == 0) cnt = 0;
  __syncthreads();
  int c = 0;
  for (int i = threadIdx.x; i < 8192; i += 256) {
    unsigned int e = (xh[i] >> 7) & 0xFFu;
    if (e > 140u) c++;
  }
  atomicAdd(&cnt, c);
  __syncthreads();
  if (threadIdx.x == 0) *flag = (cnt > 512) ? 1 : 0;
}

// ---------------- fused canonicalize: 10 segments in one launch ------------
// mode 0: ->f32, mode 3: ->fp16 single, mode 4: ->fp16 split(hi,lo)
__device__ inline void canon_seg(const void* in, char* d0, char* d1, int n,
                                 int mode, int f32in, int i) {
  if (i >= n) return;
  float v[8];
  if (f32in) {
    const float* f = (const float*)in;
    *(float4*)(v)     = *(const float4*)(f + i);
    *(float4*)(v + 4) = *(const float4*)(f + i + 4);
  } else {
    up8(*(const uint4*)((const bf16*)in + i), v);
  }
  if (mode == 0) {
    *(float4*)((float*)d0 + i)     = *(const float4*)(v);
    *(float4*)((float*)d0 + i + 4) = *(const float4*)(v + 4);
  } else if (mode == 3) {
    f16 t[8];
#pragma unroll
    for (int j = 0; j < 8; j++) t[j] = (f16)v[j];
    *(uint4*)((f16*)d0 + i) = *(const uint4*)t;
  } else {
    f16 th[8], tl[8];
#pragma unroll
    for (int j = 0; j < 8; j++) {
      th[j] = (f16)v[j];
      tl[j] = (f16)(v[j] - (float)th[j]);
    }
    *(uint4*)((f16*)d0 + i) = *(const uint4*)th;
    *(uint4*)((f16*)d1 + i) = *(const uint4*)tl;
  }
}

// block ranges (2048 elems per block):
// [0,1) dt | [1,2) al | [2,3) nw | [3,15) cw | [15,31) wb | [31,47) wa |
// [47,4143) x-split16 | [4143,10287) wqkv-fp16 | [10287,12335) wz-fp16 |
// [12335,14383) wout-fp16
__global__ __launch_bounds__(256) void canon_all(
    const void* x, const void* wqkv, const void* cw, const void* wz,
    const void* wb, const void* wa, const void* dt, const void* al,
    const void* nw, const void* wout, char* ws, const int* __restrict__ flag) {
  const int bk = blockIdx.x;
  const int f32in = *flag;
  if (bk < 1)
    canon_seg(dt, ws + DT_OFF, 0, 16, 0, f32in, (bk - 0) * 2048 + threadIdx.x * 8);
  else if (bk < 2)
    canon_seg(al, ws + AL_OFF, 0, 16, 0, f32in, (bk - 1) * 2048 + threadIdx.x * 8);
  else if (bk < 3)
    canon_seg(nw, ws + NW_OFF, 0, 128, 0, f32in, (bk - 2) * 2048 + threadIdx.x * 8);
  else if (bk < 15)
    canon_seg(cw, ws + CW_OFF, 0, CDIM * 4, 0, f32in, (bk - 3) * 2048 + threadIdx.x * 8);
  else if (bk < 31)
    canon_seg(wb, ws + WBF_OFF, 0, H_ * DM, 0, f32in, (bk - 15) * 2048 + threadIdx.x * 8);
  else if (bk < 47)
    canon_seg(wa, ws + WAF_OFF, 0, H_ * DM, 0, f32in, (bk - 31) * 2048 + threadIdx.x * 8);
  else if (bk < 4143)
    canon_seg(x, ws + XH_OFF, ws + XL_OFF, B_ * T_ * DM, 4, f32in,
              (bk - 47) * 2048 + threadIdx.x * 8);
  else if (bk < 10287)
    canon_seg(wqkv, ws + WQH_OFF, 0, CDIM * DM, 3, f32in,
              (bk - 4143) * 2048 + threadIdx.x * 8);
  else if (bk < 12335)
    canon_seg(wz, ws + WZ_OFF, 0, H_ * DV_ * DM, 3, f32in,
              (bk - 10287) * 2048 + threadIdx.x * 8);
  else
    canon_seg(wout, ws + WOUT_OFF, 0, DM * H_ * DV_, 3, f32in,
              (bk - 12335) * 2048 + threadIdx.x * 8);
}

// -------- fp16 GEMM, m97 structure. ASPLIT: A = hi+lo (2 MFMA/pair).
// OMODE 0: f32 out, 1: bf16 out, 2: dual (flag ? f32 : bf16).
template <int ASPLIT, int OMODE>
__global__ __launch_bounds__(256) void gemm_f16(
    const f16* __restrict__ Ah, const f16* __restrict__ Al,
    const f16* __restrict__ Bm, void* __restrict__ C,
    int M, int N, int K, const int* __restrict__ flag) {
  __shared__ __align__(16) f16 sAh[128 * 32];
  __shared__ __align__(16) f16 sAl[ASPLIT ? 128 * 32 : 16];
  __shared__ __align__(16) f16 sB[128 * 32];
  const int tid  = threadIdx.x;
  const int wave = tid >> 6;
  const int lane = tid & 63;
  const int m0 = blockIdx.y * 128;
  const int n0 = blockIdx.x * 128;
  const int wm = (wave >> 1) * 64;
  const int wn = (wave & 1) * 64;
  const int lrow = lane & 15;
  const int kq   = lane >> 4;

  f32x4 acc[4][4];
#pragma unroll
  for (int i = 0; i < 4; i++)
#pragma unroll
    for (int j = 0; j < 4; j++) acc[i][j] = (f32x4){0.f, 0.f, 0.f, 0.f};

  const int row0 = tid >> 2;
  const int cb   = (tid & 3) * 8;
  const size_t aoff = (size_t)(m0 + row0) * K + cb;
  const size_t boff = (size_t)(n0 + row0) * K + cb;

  for (int k0 = 0; k0 < K; k0 += 32) {
    gl2lds16(Ah + aoff + k0,                  sAh + wave * 512);
    gl2lds16(Ah + aoff + k0 + (size_t)64 * K, sAh + 2048 + wave * 512);
    if (ASPLIT) {
      gl2lds16(Al + aoff + k0,                  sAl + wave * 512);
      gl2lds16(Al + aoff + k0 + (size_t)64 * K, sAl + 2048 + wave * 512);
    }
    gl2lds16(Bm + boff + k0,                  sB + wave * 512);
    gl2lds16(Bm + boff + k0 + (size_t)64 * K, sB + 2048 + wave * 512);
    __syncthreads();

    f16x8 afh[4], afl[4], bfr[4];
#pragma unroll
    for (int i = 0; i < 4; i++) {
      const int ao = (wm + i * 16 + lrow) * 32 + kq * 8;
      afh[i] = *(const f16x8*)(sAh + ao);
      if (ASPLIT) afl[i] = *(const f16x8*)(sAl + ao);
      bfr[i] = *(const f16x8*)(sB + (wn + i * 16 + lrow) * 32 + kq * 8);
    }
#pragma unroll
    for (int i = 0; i < 4; i++)
#pragma unroll
      for (int j = 0; j < 4; j++) {
        acc[i][j] = __builtin_amdgcn_mfma_f32_16x16x32_f16(afh[i], bfr[j], acc[i][j], 0, 0, 0);
        if (ASPLIT)
          acc[i][j] = __builtin_amdgcn_mfma_f32_16x16x32_f16(afl[i], bfr[j], acc[i][j], 0, 0, 0);
      }
    __syncthreads();
  }

  const int f32o = (OMODE == 0) ? 1 : ((OMODE == 2) ? *flag : 0);
#pragma unroll
  for (int i = 0; i < 4; i++) {
    const int r0 = m0 + wm + i * 16 + kq * 4;
#pragma unroll
    for (int j = 0; j < 4; j++) {
      const int c = n0 + wn + j * 16 + lrow;
#pragma unroll
      for (int r = 0; r < 4; r++) {
        const size_t idx = (size_t)(r0 + r) * N + c;
        if (f32o) ((float*)C)[idx] = acc[i][j][r];
        else      ((bf16*)C)[idx] = __float2bfloat16(acc[i][j][r]);
      }
    }
  }
}

// ---------------- conv (causal, KW=4) + SiLU + per-head l2norm (f32) -------
__global__ __launch_bounds__(128) void conv_silu_norm(
    const float* __restrict__ mixed, const float* __restrict__ convw,
    float* __restrict__ y) {
  const int g = blockIdx.x;
  const int n = blockIdx.y;
  const int t = n & (T_ - 1);
  const int c = g * 128 + threadIdx.x;

  const float4 w = *(const float4*)(convw + (size_t)c * 4);

  const float* mc = mixed + (size_t)n * CDIM + c;
  float a = mc[0] * w.w;
  if (t >= 1) a += mc[-CDIM] * w.z;
  if (t >= 2) a += mc[-2 * CDIM] * w.y;
  if (t >= 3) a += mc[-3 * CDIM] * w.x;
  float s = a / (1.f + expf(-a));

  if (g < 32) {
    float ss = s * s;
#pragma unroll
    for (int o = 32; o > 0; o >>= 1) ss += __shfl_xor(ss, o);
    __shared__ float red[2];
    if ((threadIdx.x & 63) == 0) red[threadIdx.x >> 6] = ss;
    __syncthreads();
    s *= rsqrtf(red[0] + red[1] + EPSF);
  }
  y[(size_t)n * CDIM + c] = s;
}

// ---------------- gate projections: beta, decay (full f32) -----------------
__global__ __launch_bounds__(256) void gates_kernel(
    const f16* __restrict__ xh, const f16* __restrict__ xl,
    const float* __restrict__ w_b, const float* __restrict__ w_a,
    const float* __restrict__ dtb, const float* __restrict__ alog,
    float* __restrict__ beta, float* __restrict__ decay) {
  const int n = blockIdx.x, tid = threadIdx.x;
  __shared__ float xs[DM];
  __shared__ float red[32][8];
  {
    uint4 ph = ((const uint4*)(xh + (size_t)n * DM))[tid];
    uint4 pl = ((const uint4*)(xl + (size_t)n * DM))[tid];
    float h[8], l[8]; up8h(ph, h); up8h(pl, l);
    const int b = tid * 8;
#pragma unroll
    for (int j = 0; j < 8; j++) xs[b + j] = h[j] + l[j];
  }
  __syncthreads();
  const int hh = tid >> 3, part = tid & 7;
  const float* wrow =
      (hh < 16 ? w_b + (size_t)hh * DM : w_a + (size_t)(hh - 16) * DM) + part * 256;
  const float* xp = xs + part * 256;
  float sum = 0.f;
#pragma unroll 4
  for (int i = 0; i < 256; i += 4) {
    float4 p = *(const float4*)(wrow + i);
    sum += xp[i + 0] * p.x + xp[i + 1] * p.y + xp[i + 2] * p.z + xp[i + 3] * p.w;
  }
  red[hh][part] = sum;
  __syncthreads();
  if (tid < 32) {
    float d = 0.f;
#pragma unroll
    for (int p = 0; p < 8; p++) d += red[tid][p];
    if (tid < 16) {
      beta[(size_t)n * H_ + tid] = 1.f / (1.f + expf(-d));
    } else {
      const int h = tid - 16;
      float u = d + dtb[h];
      float sp = (u > 20.f) ? u : log1pf(expf(u));
      decay[(size_t)n * H_ + h] = expf(-expf(alog[h]) * sp);
    }
  }
}

// ---------------- delta-rule scan: LDS-staged, all-DPP, deferred op --------
// R7-proven config: 382 us, 0 bank conflicts. grid (DV/16, H, B), block 256
__global__ __launch_bounds__(256, 1) void scan_kernel(
    const float* __restrict__ y, const float* __restrict__ beta,
    const float* __restrict__ decay, float* __restrict__ o) {
  const int vb = blockIdx.x, h = blockIdx.y, b = blockIdx.z;
  const int tid = threadIdx.x;
  const int kg = tid & 15;
  const int vl = tid >> 4;

  __shared__ __align__(16) float sq[2][CGRP][128];
  __shared__ __align__(16) float sk[2][CGRP][128];
  __shared__ __align__(16) float sv[2][CGRP][16];
  __shared__ float sd[2][CGRP];
  __shared__ float sb[2][CGRP];

  const size_t rowbase = (size_t)b * T_ * CDIM;
  const int qoff = h * 128;
  const int koff = 2048 + h * 128;
  const int voff = 4096 + h * 128 + vb * 16;
  const float* bb = beta + (size_t)b * T_ * H_ + h;
  const float* db = decay + (size_t)b * T_ * H_ + h;
  float* ob = o + (size_t)b * T_ * (H_ * DV_) + h * 128 + vb * 16 + vl;

  const int ls = tid >> 4;       // staging: step within group
  const int lj = tid & 15;       // staging: float4 pair {lj*4, 64+lj*4}

  float S[8];
#pragma unroll
  for (int j = 0; j < 8; j++) S[j] = 0.f;

  float4 ga0, ga1, gb0, gb1, gv4;
  float gdd = 0.f, gbt = 0.f;

#define STAGE_ISSUE(t0)                                                      \
  {                                                                          \
    const float* r = y + rowbase + (size_t)((t0) + ls) * CDIM;               \
    ga0 = *(const float4*)(r + qoff + lj * 4);                               \
    ga1 = *(const float4*)(r + qoff + 64 + lj * 4);                          \
    gb0 = *(const float4*)(r + koff + lj * 4);                               \
    gb1 = *(const float4*)(r + koff + 64 + lj * 4);                          \
    if (tid < 64)                                                            \
      gv4 = *(const float4*)(y + rowbase + (size_t)((t0) + (tid >> 2)) * CDIM\
                             + voff + (tid & 3) * 4);                        \
    if (tid < 16) gdd = db[(size_t)((t0) + tid) * H_];                       \
    else if (tid < 32) gbt = bb[(size_t)((t0) + tid - 16) * H_];             \
  }

#define STAGE_WRITE(buf)                                                     \
  {                                                                          \
    *(float4*)&sq[buf][ls][lj * 4]      = ga0;                               \
    *(float4*)&sq[buf][ls][64 + lj * 4] = ga1;                               \
    *(float4*)&sk[buf][ls][lj * 4]      = gb0;                               \
    *(float4*)&sk[buf][ls][64 + lj * 4] = gb1;                               \
    if (tid < 64) *(float4*)&sv[buf][tid >> 2][(tid & 3) * 4] = gv4;         \
    if (tid < 16) sd[buf][tid] = gdd;                                        \
    else if (tid < 32) sb[buf][tid - 16] = gbt;                              \
  }

#define READ_STEP(buf, s, qd, kd, vvd, ddd, btd)                             \
  {                                                                          \
    *(float4*)(qd)       = *(const float4*)&sq[buf][s][kg * 4];              \
    *(float4*)((qd) + 4) = *(const float4*)&sq[buf][s][64 + kg * 4];         \
    *(float4*)(kd)       = *(const float4*)&sk[buf][s][kg * 4];              \
    *(float4*)((kd) + 4) = *(const float4*)&sk[buf][s][64 + kg * 4];         \
    vvd = sv[buf][s][vl]; ddd = sd[buf][s]; btd = sb[buf][s];                \
  }

  // prime group 0
  STAGE_ISSUE(0);
  STAGE_WRITE(0);
  __syncthreads();

  float q[8], k[8], nq[8], nk[8];
  float vv, dd, bt, nvv, ndd, nbt;
  float pp[CGRP];
  READ_STEP(0, 0, q, k, vv, dd, bt);

  const int NGRP = T_ / CGRP;
  for (int g = 0; g < NGRP; g++) {
    const int cbuf = g & 1, nbuf = cbuf ^ 1;
    const bool more = (g + 1 < NGRP);
    if (more) STAGE_ISSUE((g + 1) * CGRP);
#pragma unroll
    for (int s = 0; s < CGRP; s++) {
      if (s < CGRP - 1) READ_STEP(cbuf, s + 1, nq, nk, nvv, ndd, nbt);
      // kv = k . S, tree + DPP rowsum (the serial chain)
      float t0 = fmaf(S[1], k[1], S[0] * k[0]);
      float t1 = fmaf(S[3], k[3], S[2] * k[2]);
      float t2 = fmaf(S[5], k[5], S[4] * k[4]);
      float t3 = fmaf(S[7], k[7], S[6] * k[6]);
      float kv = (t0 + t1) + (t2 + t3);
      kv = row_sum16(kv);
      const float u = fmaf(-dd, kv, vv) * bt;
#pragma unroll
      for (int j = 0; j < 8; j++) S[j] = fmaf(dd, S[j], k[j] * u);
      // op partial only; rowsum + store deferred to group end
      float p0 = fmaf(S[1], q[1], S[0] * q[0]);
      float p1 = fmaf(S[3], q[3], S[2] * q[2]);
      float p2 = fmaf(S[5], q[5], S[4] * q[4]);
      float p3 = fmaf(S[7], q[7], S[6] * q[6]);
      pp[s] = (p0 + p1) + (p2 + p3);
      if (s < CGRP - 1) {
#pragma unroll
        for (int j = 0; j < 8; j++) { q[j] = nq[j]; k[j] = nk[j]; }
        vv = nvv; dd = ndd; bt = nbt;
      }
    }
    // deferred: 16 independent rowsums (pipelined DPP) + stores
#pragma unroll
    for (int s = 0; s < CGRP; s++) pp[s] = row_sum16(pp[s]);
    if (kg == 0) {
#pragma unroll
      for (int s = 0; s < CGRP; s++)
        ob[(size_t)(g * CGRP + s) * (H_ * DV_)] = pp[s];
    }
    if (more) {
      STAGE_WRITE(nbuf);
      __syncthreads();
      READ_STEP(nbuf, 0, q, k, vv, dd, bt);
    }
  }
#undef STAGE_ISSUE
#undef STAGE_WRITE
#undef READ_STEP
}

// -------- gated RMSNorm + SiLU(z) gate -> single fp16 ----------------------
__global__ __launch_bounds__(128) void norm_gate(
    const float* __restrict__ o, const bf16* __restrict__ z,
    const float* __restrict__ norm_w, f16* __restrict__ on_h) {
  const int n = blockIdx.x, h = blockIdx.y, v = threadIdx.x;
  const size_t idx = (size_t)n * (H_ * DV_) + h * 128 + v;
  const float ov = o[idx];
  float ss = ov * ov;
#pragma unroll
  for (int w = 32; w > 0; w >>= 1) ss += __shfl_xor(ss, w);
  __shared__ float red[2];
  if ((v & 63) == 0) red[v >> 6] = ss;
  __syncthreads();
  const float ms = (red[0] + red[1]) * (1.f / 128.f);
  const float zv = __bfloat162float(z[idx]);
  const float res = ov * rsqrtf(ms + EPSF) * norm_w[v] *
                    (zv / (1.f + expf(-zv)));
  on_h[idx] = (f16)res;
}

// ---------------------------------------------------------------------------
extern "C" void kernel_launch(void* const* d_in, const int* in_sizes, int n_in,
                              void* d_out, int out_size, void* d_ws, size_t ws_size,
                              hipStream_t stream) {
  const int NT = B_ * T_;  // 4096
  char* ws = (char*)d_ws;
  int*   flag   = (int*)(ws + FLAG_OFF);
  float* dt_f   = (float*)(ws + DT_OFF);
  float* al_f   = (float*)(ws + AL_OFF);
  float* nw_f   = (float*)(ws + NW_OFF);
  float* cw_f   = (float*)(ws + CW_OFF);
  float* wb_f   = (float*)(ws + WBF_OFF);
  float* wa_f   = (float*)(ws + WAF_OFF);
  float* betab  = (float*)(ws + BETA_OFF);
  float* decayb = (float*)(ws + DEC_OFF);
  f16*   x_hi   = (f16*)(ws + XH_OFF);
  f16*   x_lo   = (f16*)(ws + XL_OFF);
  f16*   wq_hi  = (f16*)(ws + WQH_OFF);
  f16*   wz_h   = (f16*)(ws + WZ_OFF);
  float* mixed  = (float*)(ws + MIX_OFF);
  f16*   wout_h = (f16*)(ws + WOUT_OFF);
  bf16*  z      = (bf16*)(ws + Z_OFF);
  float* y      = (float*)(ws + Y_OFF);
  float* o      = (float*)(ws + O_OFF);
  f16*   on_h   = (f16*)(ws + ONH_OFF);

  // 0. detect input dtype (flag=1 -> f32)
  detect_dtype<<<1, 256, 0, stream>>>((const unsigned short*)d_in[0], flag);

  // 1. canonicalize everything in one launch
  canon_all<<<14383, 256, 0, stream>>>(
      d_in[0], d_in[1], d_in[2], d_in[3], d_in[4], d_in[5], d_in[6], d_in[7],
      d_in[8], d_in[9], ws, flag);

  // 2. gates (f32-precision beta/decay; x = fp16 hi+lo ~22-bit)
  gates_kernel<<<NT, 256, 0, stream>>>(x_hi, x_lo, wb_f, wa_f, dt_f, al_f,
                                       betab, decayb);
  // 3. mixed = x @ w_qkv^T  (A split fp16, B single fp16, 2-term) -> f32
  gemm_f16<1, 0><<<dim3(CDIM / 128, NT / 128), 256, 0, stream>>>(
      x_hi, x_lo, wq_hi, mixed, NT, CDIM, DM, flag);
  // 4. z = x @ w_z^T  (single-term fp16) -> bf16
  gemm_f16<0, 1><<<dim3((H_ * DV_) / 128, NT / 128), 256, 0, stream>>>(
      x_hi, (const f16*)0, wz_h, z, NT, H_ * DV_, DM, flag);
  // 5. conv + SiLU + l2norm -> y f32 (overlays dead x/wq/wz)
  conv_silu_norm<<<dim3(CDIM / 128, NT), 128, 0, stream>>>(mixed, cw_f, y);
  // 6. delta-rule scan -> o f32 (overlays dead mixed)
  scan_kernel<<<dim3(DV_ / 16, H_, B_), 256, 0, stream>>>(y, betab, decayb, o);
  // 7. gated RMSNorm -> on fp16 (overlays dead y)
  norm_gate<<<dim3(NT, H_), 128, 0, stream>>>(o, z, nw_f, on_h);
  // 8. out = on @ w_out^T (single-term fp16, dual-dtype out)
  gemm_f16<0, 2><<<dim3(DM / 128, NT / 128), 256, 0, stream>>>(
      on_h, (const f16*)0, wout_h, d_out, NT, DM, H_ * DV_, flag);
}

// Round 3
// 1077.366 us; speedup vs baseline: 1.1211x; 1.0170x over previous
//
#include <hip/hip_runtime.h>
#include <hip/hip_bf16.h>

#define B_   2
#define T_   2048
#define DM   2048
#define H_   16
#define DK_  128
#define DV_  128
#define CDIM 6144
#define EPSF 1e-6f
#define CGRP 16   // scan: timesteps staged per LDS group

typedef __hip_bfloat16 bf16;
typedef _Float16 f16;
typedef short bf16x8 __attribute__((ext_vector_type(8)));
typedef _Float16 f16x8 __attribute__((ext_vector_type(8)));
typedef float f32x4 __attribute__((ext_vector_type(4)));

// ---- workspace layout (bytes); peak = 227,540,992 < proven-OK 228,589,568 --
#define FLAG_OFF   0
#define DT_OFF     1024
#define AL_OFF     2048
#define NW_OFF     4096
#define CW_OFF     8192
#define WBF_OFF    131072
#define WAF_OFF    262144
#define BETA_OFF   393216
#define DEC_OFF    655360
#define XH_OFF     1048576
#define XL_OFF     17825792
#define WQH_OFF    34603008
#define WZ_OFF     84934656
#define MIX_OFF    101711872
#define WOUT_OFF   202375168
#define Z_OFF      210763776
#define Y_OFF      1048576
#define O_OFF      101711872
#define ONH_OFF    1048576

__device__ inline float bf2f(unsigned int u) {
  union { unsigned int i; float f; } v; v.i = u << 16; return v.f;
}
__device__ inline void up8(uint4 p, float* d) {
  d[0] = bf2f(p.x & 0xffffu); d[1] = bf2f(p.x >> 16);
  d[2] = bf2f(p.y & 0xffffu); d[3] = bf2f(p.y >> 16);
  d[4] = bf2f(p.z & 0xffffu); d[5] = bf2f(p.z >> 16);
  d[6] = bf2f(p.w & 0xffffu); d[7] = bf2f(p.w >> 16);
}
// fp16 x8 unpack (v_cvt_f32_f16)
__device__ inline void up8h(uint4 p, float* d) {
  union { unsigned int i; _Float16 h[2]; } c;
  c.i = p.x; d[0] = (float)c.h[0]; d[1] = (float)c.h[1];
  c.i = p.y; d[2] = (float)c.h[0]; d[3] = (float)c.h[1];
  c.i = p.z; d[4] = (float)c.h[0]; d[5] = (float)c.h[1];
  c.i = p.w; d[6] = (float)c.h[0]; d[7] = (float)c.h[1];
}
__device__ inline void gl2lds16(const void* g, void* lds) {
  __builtin_amdgcn_global_load_lds(
      (const __attribute__((address_space(1))) unsigned int*)g,
      (__attribute__((address_space(3))) unsigned int*)lds, 16, 0, 0);
}

// DPP butterfly add over a 16-lane row — stays on the VALU pipe.
template <int CTRL>
__device__ inline float radd(float v) {
  int t = __builtin_amdgcn_update_dpp(0, __float_as_int(v), CTRL, 0xF, 0xF, true);
  return v + __int_as_float(t);
}
__device__ inline float row_sum16(float v) {
  v = radd<0xB1>(v);   // quad_perm [1,0,3,2] : + xor1
  v = radd<0x4E>(v);   // quad_perm [2,3,0,1] : + xor2
  v = radd<0x141>(v);  // row_half_mirror     : + xor4
  v = radd<0x140>(v);  // row_mirror          : + xor8
  return v;
}

// ---------------- dtype detector: flag=1 if inputs are f32 -----------------
__global__ __launch_bounds__(256) void detect_dtype(
    const unsigned short* __restrict__ xh, int* __restrict__ flag) {
  __shared__ int cnt;
  if (threadIdx.x == 0) cnt = 0;
  __syncthreads();
  int c = 0;
  for (int i = threadIdx.x; i < 8192; i += 256) {
    unsigned int e = (xh[i] >> 7) & 0xFFu;
    if (e > 140u) c++;
  }
  atomicAdd(&cnt, c);
  __syncthreads();
  if (threadIdx.x == 0) *flag = (cnt > 512) ? 1 : 0;
}

// ---------------- fused canonicalize: 10 segments in one launch ------------
// mode 0: ->f32, mode 3: ->fp16 single, mode 4: ->fp16 split(hi,lo)
__device__ inline void canon_seg(const void* in, char* d0, char* d1, int n,
                                 int mode, int f32in, int i) {
  if (i >= n) return;
  float v[8];
  if (f32in) {
    const float* f = (const float*)in;
    *(float4*)(v)     = *(const float4*)(f + i);
    *(float4*)(v + 4) = *(const float4*)(f + i + 4);
  } else {
    up8(*(const uint4*)((const bf16*)in + i), v);
  }
  if (mode == 0) {
    *(float4*)((float*)d0 + i)     = *(const float4*)(v);
    *(float4*)((float*)d0 + i + 4) = *(const float4*)(v + 4);
  } else if (mode == 3) {
    f16 t[8];
#pragma unroll
    for (int j = 0; j < 8; j++) t[j] = (f16)v[j];
    *(uint4*)((f16*)d0 + i) = *(const uint4*)t;
  } else {
    f16 th[8], tl[8];
#pragma unroll
    for (int j = 0; j < 8; j++) {
      th[j] = (f16)v[j];
      tl[j] = (f16)(v[j] - (float)th[j]);
    }
    *(uint4*)((f16*)d0 + i) = *(const uint4*)th;
    *(uint4*)((f16*)d1 + i) = *(const uint4*)tl;
  }
}

// block ranges (2048 elems per block):
// [0,1) dt | [1,2) al | [2,3) nw | [3,15) cw | [15,31) wb | [31,47) wa |
// [47,4143) x-split16 | [4143,10287) wqkv-fp16 | [10287,12335) wz-fp16 |
// [12335,14383) wout-fp16
__global__ __launch_bounds__(256) void canon_all(
    const void* x, const void* wqkv, const void* cw, const void* wz,
    const void* wb, const void* wa, const void* dt, const void* al,
    const void* nw, const void* wout, char* ws, const int* __restrict__ flag) {
  const int bk = blockIdx.x;
  const int f32in = *flag;
  if (bk < 1)
    canon_seg(dt, ws + DT_OFF, 0, 16, 0, f32in, (bk - 0) * 2048 + threadIdx.x * 8);
  else if (bk < 2)
    canon_seg(al, ws + AL_OFF, 0, 16, 0, f32in, (bk - 1) * 2048 + threadIdx.x * 8);
  else if (bk < 3)
    canon_seg(nw, ws + NW_OFF, 0, 128, 0, f32in, (bk - 2) * 2048 + threadIdx.x * 8);
  else if (bk < 15)
    canon_seg(cw, ws + CW_OFF, 0, CDIM * 4, 0, f32in, (bk - 3) * 2048 + threadIdx.x * 8);
  else if (bk < 31)
    canon_seg(wb, ws + WBF_OFF, 0, H_ * DM, 0, f32in, (bk - 15) * 2048 + threadIdx.x * 8);
  else if (bk < 47)
    canon_seg(wa, ws + WAF_OFF, 0, H_ * DM, 0, f32in, (bk - 31) * 2048 + threadIdx.x * 8);
  else if (bk < 4143)
    canon_seg(x, ws + XH_OFF, ws + XL_OFF, B_ * T_ * DM, 4, f32in,
              (bk - 47) * 2048 + threadIdx.x * 8);
  else if (bk < 10287)
    canon_seg(wqkv, ws + WQH_OFF, 0, CDIM * DM, 3, f32in,
              (bk - 4143) * 2048 + threadIdx.x * 8);
  else if (bk < 12335)
    canon_seg(wz, ws + WZ_OFF, 0, H_ * DV_ * DM, 3, f32in,
              (bk - 10287) * 2048 + threadIdx.x * 8);
  else
    canon_seg(wout, ws + WOUT_OFF, 0, DM * H_ * DV_, 3, f32in,
              (bk - 12335) * 2048 + threadIdx.x * 8);
}

// -------- fp16 GEMM, m97 structure. ASPLIT: A = hi+lo (2 MFMA/pair).
// OMODE 0: f32 out, 1: bf16 out, 2: dual (flag ? f32 : bf16).
template <int ASPLIT, int OMODE>
__global__ __launch_bounds__(256) void gemm_f16(
    const f16* __restrict__ Ah, const f16* __restrict__ Al,
    const f16* __restrict__ Bm, void* __restrict__ C,
    int M, int N, int K, const int* __restrict__ flag) {
  __shared__ __align__(16) f16 sAh[128 * 32];
  __shared__ __align__(16) f16 sAl[ASPLIT ? 128 * 32 : 16];
  __shared__ __align__(16) f16 sB[128 * 32];
  const int tid  = threadIdx.x;
  const int wave = tid >> 6;
  const int lane = tid & 63;
  const int m0 = blockIdx.y * 128;
  const int n0 = blockIdx.x * 128;
  const int wm = (wave >> 1) * 64;
  const int wn = (wave & 1) * 64;
  const int lrow = lane & 15;
  const int kq   = lane >> 4;

  f32x4 acc[4][4];
#pragma unroll
  for (int i = 0; i < 4; i++)
#pragma unroll
    for (int j = 0; j < 4; j++) acc[i][j] = (f32x4){0.f, 0.f, 0.f, 0.f};

  const int row0 = tid >> 2;
  const int cb   = (tid & 3) * 8;
  const size_t aoff = (size_t)(m0 + row0) * K + cb;
  const size_t boff = (size_t)(n0 + row0) * K + cb;

  for (int k0 = 0; k0 < K; k0 += 32) {
    gl2lds16(Ah + aoff + k0,                  sAh + wave * 512);
    gl2lds16(Ah + aoff + k0 + (size_t)64 * K, sAh + 2048 + wave * 512);
    if (ASPLIT) {
      gl2lds16(Al + aoff + k0,                  sAl + wave * 512);
      gl2lds16(Al + aoff + k0 + (size_t)64 * K, sAl + 2048 + wave * 512);
    }
    gl2lds16(Bm + boff + k0,                  sB + wave * 512);
    gl2lds16(Bm + boff + k0 + (size_t)64 * K, sB + 2048 + wave * 512);
    __syncthreads();

    f16x8 afh[4], afl[4], bfr[4];
#pragma unroll
    for (int i = 0; i < 4; i++) {
      const int ao = (wm + i * 16 + lrow) * 32 + kq * 8;
      afh[i] = *(const f16x8*)(sAh + ao);
      if (ASPLIT) afl[i] = *(const f16x8*)(sAl + ao);
      bfr[i] = *(const f16x8*)(sB + (wn + i * 16 + lrow) * 32 + kq * 8);
    }
#pragma unroll
    for (int i = 0; i < 4; i++)
#pragma unroll
      for (int j = 0; j < 4; j++) {
        acc[i][j] = __builtin_amdgcn_mfma_f32_16x16x32_f16(afh[i], bfr[j], acc[i][j], 0, 0, 0);
        if (ASPLIT)
          acc[i][j] = __builtin_amdgcn_mfma_f32_16x16x32_f16(afl[i], bfr[j], acc[i][j], 0, 0, 0);
      }
    __syncthreads();
  }

  const int f32o = (OMODE == 0) ? 1 : ((OMODE == 2) ? *flag : 0);
#pragma unroll
  for (int i = 0; i < 4; i++) {
    const int r0 = m0 + wm + i * 16 + kq * 4;
#pragma unroll
    for (int j = 0; j < 4; j++) {
      const int c = n0 + wn + j * 16 + lrow;
#pragma unroll
      for (int r = 0; r < 4; r++) {
        const size_t idx = (size_t)(r0 + r) * N + c;
        if (f32o) ((float*)C)[idx] = acc[i][j][r];
        else      ((bf16*)C)[idx] = __float2bfloat16(acc[i][j][r]);
      }
    }
  }
}

// ---------------- conv (causal, KW=4) + SiLU + per-head l2norm (f32) -------
__global__ __launch_bounds__(128) void conv_silu_norm(
    const float* __restrict__ mixed, const float* __restrict__ convw,
    float* __restrict__ y) {
  const int g = blockIdx.x;
  const int n = blockIdx.y;
  const int t = n & (T_ - 1);
  const int c = g * 128 + threadIdx.x;

  const float4 w = *(const float4*)(convw + (size_t)c * 4);

  const float* mc = mixed + (size_t)n * CDIM + c;
  float a = mc[0] * w.w;
  if (t >= 1) a += mc[-CDIM] * w.z;
  if (t >= 2) a += mc[-2 * CDIM] * w.y;
  if (t >= 3) a += mc[-3 * CDIM] * w.x;
  float s = a / (1.f + expf(-a));

  if (g < 32) {
    float ss = s * s;
#pragma unroll
    for (int o = 32; o > 0; o >>= 1) ss += __shfl_xor(ss, o);
    __shared__ float red[2];
    if ((threadIdx.x & 63) == 0) red[threadIdx.x >> 6] = ss;
    __syncthreads();
    s *= rsqrtf(red[0] + red[1] + EPSF);
  }
  y[(size_t)n * CDIM + c] = s;
}

// ---------------- gate projections: beta, decay (full f32) -----------------
__global__ __launch_bounds__(256) void gates_kernel(
    const f16* __restrict__ xh, const f16* __restrict__ xl,
    const float* __restrict__ w_b, const float* __restrict__ w_a,
    const float* __restrict__ dtb, const float* __restrict__ alog,
    float* __restrict__ beta, float* __restrict__ decay) {
  const int n = blockIdx.x, tid = threadIdx.x;
  __shared__ float xs[DM];
  __shared__ float red[32][8];
  {
    uint4 ph = ((const uint4*)(xh + (size_t)n * DM))[tid];
    uint4 pl = ((const uint4*)(xl + (size_t)n * DM))[tid];
    float h[8], l[8]; up8h(ph, h); up8h(pl, l);
    const int b = tid * 8;
#pragma unroll
    for (int j = 0; j < 8; j++) xs[b + j] = h[j] + l[j];
  }
  __syncthreads();
  const int hh = tid >> 3, part = tid & 7;
  const float* wrow =
      (hh < 16 ? w_b + (size_t)hh * DM : w_a + (size_t)(hh - 16) * DM) + part * 256;
  const float* xp = xs + part * 256;
  float sum = 0.f;
#pragma unroll 4
  for (int i = 0; i < 256; i += 4) {
    float4 p = *(const float4*)(wrow + i);
    sum += xp[i + 0] * p.x + xp[i + 1] * p.y + xp[i + 2] * p.z + xp[i + 3] * p.w;
  }
  red[hh][part] = sum;
  __syncthreads();
  if (tid < 32) {
    float d = 0.f;
#pragma unroll
    for (int p = 0; p < 8; p++) d += red[tid][p];
    if (tid < 16) {
      beta[(size_t)n * H_ + tid] = 1.f / (1.f + expf(-d));
    } else {
      const int h = tid - 16;
      float u = d + dtb[h];
      float sp = (u > 20.f) ? u : log1pf(expf(u));
      decay[(size_t)n * H_ + h] = expf(-expf(alog[h]) * sp);
    }
  }
}

// ---------------- delta-rule scan: 2-step fused rounds (R2) ----------------
// Rank-2 composition: per round (t1,t2) the two S₀-dependent rowsums
// c1=k1ᵀS₀ and w2=k2ᵀS₀ are computed in PARALLEL (one DPP-chain depth
// instead of two); kv₂ = d1·w2 + (k2·k1)·u1 with m=k2·k1 off-chain.
// Same lane layout / LDS staging / deferred-store as R7-proven config.
__global__ __launch_bounds__(256, 1) void scan_kernel(
    const float* __restrict__ y, const float* __restrict__ beta,
    const float* __restrict__ decay, float* __restrict__ o) {
  const int vb = blockIdx.x, h = blockIdx.y, b = blockIdx.z;
  const int tid = threadIdx.x;
  const int kg = tid & 15;
  const int vl = tid >> 4;

  __shared__ __align__(16) float sq[2][CGRP][128];
  __shared__ __align__(16) float sk[2][CGRP][128];
  __shared__ __align__(16) float sv[2][CGRP][16];
  __shared__ float sd[2][CGRP];
  __shared__ float sb[2][CGRP];

  const size_t rowbase = (size_t)b * T_ * CDIM;
  const int qoff = h * 128;
  const int koff = 2048 + h * 128;
  const int voff = 4096 + h * 128 + vb * 16;
  const float* bb = beta + (size_t)b * T_ * H_ + h;
  const float* db = decay + (size_t)b * T_ * H_ + h;
  float* ob = o + (size_t)b * T_ * (H_ * DV_) + h * 128 + vb * 16 + vl;

  const int ls = tid >> 4;       // staging: step within group
  const int lj = tid & 15;       // staging: float4 pair {lj*4, 64+lj*4}

  float S[8];
#pragma unroll
  for (int j = 0; j < 8; j++) S[j] = 0.f;

  float4 ga0, ga1, gb0, gb1, gv4;
  float gdd = 0.f, gbt = 0.f;

#define STAGE_ISSUE(t0)                                                      \
  {                                                                          \
    const float* r = y + rowbase + (size_t)((t0) + ls) * CDIM;               \
    ga0 = *(const float4*)(r + qoff + lj * 4);                               \
    ga1 = *(const float4*)(r + qoff + 64 + lj * 4);                          \
    gb0 = *(const float4*)(r + koff + lj * 4);                               \
    gb1 = *(const float4*)(r + koff + 64 + lj * 4);                          \
    if (tid < 64)                                                            \
      gv4 = *(const float4*)(y + rowbase + (size_t)((t0) + (tid >> 2)) * CDIM\
                             + voff + (tid & 3) * 4);                        \
    if (tid < 16) gdd = db[(size_t)((t0) + tid) * H_];                       \
    else if (tid < 32) gbt = bb[(size_t)((t0) + tid - 16) * H_];             \
  }

#define STAGE_WRITE(buf)                                                     \
  {                                                                          \
    *(float4*)&sq[buf][ls][lj * 4]      = ga0;                               \
    *(float4*)&sq[buf][ls][64 + lj * 4] = ga1;                               \
    *(float4*)&sk[buf][ls][lj * 4]      = gb0;                               \
    *(float4*)&sk[buf][ls][64 + lj * 4] = gb1;                               \
    if (tid < 64) *(float4*)&sv[buf][tid >> 2][(tid & 3) * 4] = gv4;         \
    if (tid < 16) sd[buf][tid] = gdd;                                        \
    else if (tid < 32) sb[buf][tid - 16] = gbt;                              \
  }

// read BOTH steps of round r (steps 2r, 2r+1) into registers
#define READ_PAIR(buf, r, Q1, K1, Q2, K2, P)                                 \
  {                                                                          \
    *(float4*)(Q1)       = *(const float4*)&sq[buf][2*(r)][kg * 4];          \
    *(float4*)((Q1) + 4) = *(const float4*)&sq[buf][2*(r)][64 + kg * 4];     \
    *(float4*)(K1)       = *(const float4*)&sk[buf][2*(r)][kg * 4];          \
    *(float4*)((K1) + 4) = *(const float4*)&sk[buf][2*(r)][64 + kg * 4];     \
    *(float4*)(Q2)       = *(const float4*)&sq[buf][2*(r)+1][kg * 4];        \
    *(float4*)((Q2) + 4) = *(const float4*)&sq[buf][2*(r)+1][64 + kg * 4];   \
    *(float4*)(K2)       = *(const float4*)&sk[buf][2*(r)+1][kg * 4];        \
    *(float4*)((K2) + 4) = *(const float4*)&sk[buf][2*(r)+1][64 + kg * 4];   \
    P##v1 = sv[buf][2*(r)][vl];   P##d1 = sd[buf][2*(r)];   P##b1 = sb[buf][2*(r)];   \
    P##v2 = sv[buf][2*(r)+1][vl]; P##d2 = sd[buf][2*(r)+1]; P##b2 = sb[buf][2*(r)+1]; \
  }

  // prime group 0
  STAGE_ISSUE(0);
  STAGE_WRITE(0);
  __syncthreads();

  float q1[8], k1[8], q2[8], k2[8];
  float nq1[8], nk1[8], nq2[8], nk2[8];
  float cv1, cd1, cb1, cv2, cd2, cb2;
  float nv1, nd1, nb1, nv2, nd2, nb2;
  float pp[CGRP];
  READ_PAIR(0, 0, q1, k1, q2, k2, c);

  const int NGRP = T_ / CGRP;
  const int NRND = CGRP / 2;
  for (int g = 0; g < NGRP; g++) {
    const int cbuf = g & 1, nbuf = cbuf ^ 1;
    const bool more = (g + 1 < NGRP);
    if (more) STAGE_ISSUE((g + 1) * CGRP);
#pragma unroll
    for (int r = 0; r < NRND; r++) {
      if (r < NRND - 1) READ_PAIR(cbuf, r + 1, nq1, nk1, nq2, nk2, n);
      // off-chain: m = k2 . k1 (full 128-dot)
      float m0 = fmaf(k2[1], k1[1], k2[0] * k1[0]);
      float m1 = fmaf(k2[3], k1[3], k2[2] * k1[2]);
      float m2 = fmaf(k2[5], k1[5], k2[4] * k1[4]);
      float m3 = fmaf(k2[7], k1[7], k2[6] * k1[6]);
      float mm = row_sum16((m0 + m1) + (m2 + m3));
      // chain: c1 = k1ᵀS₀ and w2 = k2ᵀS₀ in parallel (single DPP depth)
      float c0 = fmaf(S[1], k1[1], S[0] * k1[0]);
      float c1t = fmaf(S[3], k1[3], S[2] * k1[2]);
      float c2t = fmaf(S[5], k1[5], S[4] * k1[4]);
      float c3t = fmaf(S[7], k1[7], S[6] * k1[6]);
      float w0 = fmaf(S[1], k2[1], S[0] * k2[0]);
      float w1t = fmaf(S[3], k2[3], S[2] * k2[2]);
      float w2t = fmaf(S[5], k2[5], S[4] * k2[4]);
      float w3t = fmaf(S[7], k2[7], S[6] * k2[6]);
      float c1s = row_sum16((c0 + c1t) + (c2t + c3t));
      float w2s = row_sum16((w0 + w1t) + (w2t + w3t));
      // scalar chain
      const float u1 = fmaf(-cd1, c1s, cv1) * cb1;
      const float kv2 = fmaf(mm, u1, cd1 * w2s);
      const float u2 = fmaf(-cd2, kv2, cv2) * cb2;
      // S₁ = d1·S₀ + k1·u1 ; output partial for t1
#pragma unroll
      for (int j = 0; j < 8; j++) S[j] = fmaf(cd1, S[j], k1[j] * u1);
      {
        float p0 = fmaf(S[1], q1[1], S[0] * q1[0]);
        float p1 = fmaf(S[3], q1[3], S[2] * q1[2]);
        float p2 = fmaf(S[5], q1[5], S[4] * q1[4]);
        float p3 = fmaf(S[7], q1[7], S[6] * q1[6]);
        pp[2 * r] = (p0 + p1) + (p2 + p3);
      }
      // S₂ = d2·S₁ + k2·u2 ; output partial for t2
#pragma unroll
      for (int j = 0; j < 8; j++) S[j] = fmaf(cd2, S[j], k2[j] * u2);
      {
        float p0 = fmaf(S[1], q2[1], S[0] * q2[0]);
        float p1 = fmaf(S[3], q2[3], S[2] * q2[2]);
        float p2 = fmaf(S[5], q2[5], S[4] * q2[4]);
        float p3 = fmaf(S[7], q2[7], S[6] * q2[6]);
        pp[2 * r + 1] = (p0 + p1) + (p2 + p3);
      }
      if (r < NRND - 1) {
#pragma unroll
        for (int j = 0; j < 8; j++) {
          q1[j] = nq1[j]; k1[j] = nk1[j]; q2[j] = nq2[j]; k2[j] = nk2[j];
        }
        cv1 = nv1; cd1 = nd1; cb1 = nb1; cv2 = nv2; cd2 = nd2; cb2 = nb2;
      }
    }
    // deferred: 16 independent rowsums (pipelined DPP) + stores
#pragma unroll
    for (int s = 0; s < CGRP; s++) pp[s] = row_sum16(pp[s]);
    if (kg == 0) {
#pragma unroll
      for (int s = 0; s < CGRP; s++)
        ob[(size_t)(g * CGRP + s) * (H_ * DV_)] = pp[s];
    }
    if (more) {
      STAGE_WRITE(nbuf);
      __syncthreads();
      READ_PAIR(nbuf, 0, q1, k1, q2, k2, c);
    }
  }
#undef STAGE_ISSUE
#undef STAGE_WRITE
#undef READ_PAIR
}

// -------- gated RMSNorm + SiLU(z) gate -> single fp16 ----------------------
__global__ __launch_bounds__(128) void norm_gate(
    const float* __restrict__ o, const bf16* __restrict__ z,
    const float* __restrict__ norm_w, f16* __restrict__ on_h) {
  const int n = blockIdx.x, h = blockIdx.y, v = threadIdx.x;
  const size_t idx = (size_t)n * (H_ * DV_) + h * 128 + v;
  const float ov = o[idx];
  float ss = ov * ov;
#pragma unroll
  for (int w = 32; w > 0; w >>= 1) ss += __shfl_xor(ss, w);
  __shared__ float red[2];
  if ((v & 63) == 0) red[v >> 6] = ss;
  __syncthreads();
  const float ms = (red[0] + red[1]) * (1.f / 128.f);
  const float zv = __bfloat162float(z[idx]);
  const float res = ov * rsqrtf(ms + EPSF) * norm_w[v] *
                    (zv / (1.f + expf(-zv)));
  on_h[idx] = (f16)res;
}

// ---------------------------------------------------------------------------
extern "C" void kernel_launch(void* const* d_in, const int* in_sizes, int n_in,
                              void* d_out, int out_size, void* d_ws, size_t ws_size,
                              hipStream_t stream) {
  const int NT = B_ * T_;  // 4096
  char* ws = (char*)d_ws;
  int*   flag   = (int*)(ws + FLAG_OFF);
  float* dt_f   = (float*)(ws + DT_OFF);
  float* al_f   = (float*)(ws + AL_OFF);
  float* nw_f   = (float*)(ws + NW_OFF);
  float* cw_f   = (float*)(ws + CW_OFF);
  float* wb_f   = (float*)(ws + WBF_OFF);
  float* wa_f   = (float*)(ws + WAF_OFF);
  float* betab  = (float*)(ws + BETA_OFF);
  float* decayb = (float*)(ws + DEC_OFF);
  f16*   x_hi   = (f16*)(ws + XH_OFF);
  f16*   x_lo   = (f16*)(ws + XL_OFF);
  f16*   wq_hi  = (f16*)(ws + WQH_OFF);
  f16*   wz_h   = (f16*)(ws + WZ_OFF);
  float* mixed  = (float*)(ws + MIX_OFF);
  f16*   wout_h = (f16*)(ws + WOUT_OFF);
  bf16*  z      = (bf16*)(ws + Z_OFF);
  float* y      = (float*)(ws + Y_OFF);
  float* o      = (float*)(ws + O_OFF);
  f16*   on_h   = (f16*)(ws + ONH_OFF);

  // 0. detect input dtype (flag=1 -> f32)
  detect_dtype<<<1, 256, 0, stream>>>((const unsigned short*)d_in[0], flag);

  // 1. canonicalize everything in one launch
  canon_all<<<14383, 256, 0, stream>>>(
      d_in[0], d_in[1], d_in[2], d_in[3], d_in[4], d_in[5], d_in[6], d_in[7],
      d_in[8], d_in[9], ws, flag);

  // 2. gates (f32-precision beta/decay; x = fp16 hi+lo ~22-bit)
  gates_kernel<<<NT, 256, 0, stream>>>(x_hi, x_lo, wb_f, wa_f, dt_f, al_f,
                                       betab, decayb);
  // 3. mixed = x @ w_qkv^T  (A split fp16, B single fp16, 2-term) -> f32
  gemm_f16<1, 0><<<dim3(CDIM / 128, NT / 128), 256, 0, stream>>>(
      x_hi, x_lo, wq_hi, mixed, NT, CDIM, DM, flag);
  // 4. z = x @ w_z^T  (single-term fp16) -> bf16
  gemm_f16<0, 1><<<dim3((H_ * DV_) / 128, NT / 128), 256, 0, stream>>>(
      x_hi, (const f16*)0, wz_h, z, NT, H_ * DV_, DM, flag);
  // 5. conv + SiLU + l2norm -> y f32 (overlays dead x/wq/wz)
  conv_silu_norm<<<dim3(CDIM / 128, NT), 128, 0, stream>>>(mixed, cw_f, y);
  // 6. delta-rule scan (2-step fused) -> o f32 (overlays dead mixed)
  scan_kernel<<<dim3(DV_ / 16, H_, B_), 256, 0, stream>>>(y, betab, decayb, o);
  // 7. gated RMSNorm -> on fp16 (overlays dead y)
  norm_gate<<<dim3(NT, H_), 128, 0, stream>>>(o, z, nw_f, on_h);
  // 8. out = on @ w_out^T (single-term fp16, dual-dtype out)
  gemm_f16<0, 2><<<dim3(DM / 128, NT / 128), 256, 0, stream>>>(
      on_h, (const f16*)0, wout_h, d_out, NT, DM, H_ * DV_, flag);
}

// Round 5
// 983.458 us; speedup vs baseline: 1.2282x; 1.0955x over previous
//
#include <hip/hip_runtime.h>
#include <hip/hip_bf16.h>

#define B_   2
#define T_   2048
#define DM   2048
#define H_   16
#define DK_  128
#define DV_  128
#define CDIM 6144
#define EPSF 1e-6f
#define CGRP 16   // scan: timesteps staged per LDS group

typedef __hip_bfloat16 bf16;
typedef _Float16 f16;
typedef short bf16x8 __attribute__((ext_vector_type(8)));
typedef _Float16 f16x8 __attribute__((ext_vector_type(8)));
typedef float f32x4 __attribute__((ext_vector_type(4)));

// ---- workspace layout (bytes); peak = 227,540,992 < proven-OK 228,589,568 --
#define FLAG_OFF   0
#define DT_OFF     1024
#define AL_OFF     2048
#define NW_OFF     4096
#define CW_OFF     8192
#define WBF_OFF    131072
#define WAF_OFF    262144
#define BETA_OFF   393216
#define DEC_OFF    655360
#define XH_OFF     1048576
#define XL_OFF     17825792
#define WQH_OFF    34603008
#define WZ_OFF     84934656
#define MIX_OFF    101711872
#define WOUT_OFF   202375168
#define Z_OFF      210763776
#define Y_OFF      1048576
#define O_OFF      101711872
#define ONH_OFF    1048576

__device__ inline float bf2f(unsigned int u) {
  union { unsigned int i; float f; } v; v.i = u << 16; return v.f;
}
__device__ inline void up8(uint4 p, float* d) {
  d[0] = bf2f(p.x & 0xffffu); d[1] = bf2f(p.x >> 16);
  d[2] = bf2f(p.y & 0xffffu); d[3] = bf2f(p.y >> 16);
  d[4] = bf2f(p.z & 0xffffu); d[5] = bf2f(p.z >> 16);
  d[6] = bf2f(p.w & 0xffffu); d[7] = bf2f(p.w >> 16);
}
// fp16 x8 unpack (v_cvt_f32_f16)
__device__ inline void up8h(uint4 p, float* d) {
  union { unsigned int i; _Float16 h[2]; } c;
  c.i = p.x; d[0] = (float)c.h[0]; d[1] = (float)c.h[1];
  c.i = p.y; d[2] = (float)c.h[0]; d[3] = (float)c.h[1];
  c.i = p.z; d[4] = (float)c.h[0]; d[5] = (float)c.h[1];
  c.i = p.w; d[6] = (float)c.h[0]; d[7] = (float)c.h[1];
}
__device__ inline void gl2lds16(const void* g, void* lds) {
  __builtin_amdgcn_global_load_lds(
      (const __attribute__((address_space(1))) unsigned int*)g,
      (__attribute__((address_space(3))) unsigned int*)lds, 16, 0, 0);
}
// R4: explicit drain of the global_load_lds DMA queue before a staging
// barrier. The compiler normally emits this; making it unconditional
// removes the suspected replay-timing race from R3's post-timing failure.
__device__ inline void stage_fence() {
  asm volatile("s_waitcnt vmcnt(0) lgkmcnt(0)" ::: "memory");
}

// DPP butterfly add over a 16-lane row — stays on the VALU pipe.
template <int CTRL>
__device__ inline float radd(float v) {
  int t = __builtin_amdgcn_update_dpp(0, __float_as_int(v), CTRL, 0xF, 0xF, true);
  return v + __int_as_float(t);
}
__device__ inline float row_sum16(float v) {
  v = radd<0xB1>(v);   // quad_perm [1,0,3,2] : + xor1
  v = radd<0x4E>(v);   // quad_perm [2,3,0,1] : + xor2
  v = radd<0x141>(v);  // row_half_mirror     : + xor4
  v = radd<0x140>(v);  // row_mirror          : + xor8
  return v;
}

// ---------------- dtype detector: flag=1 if inputs are f32 -----------------
__global__ __launch_bounds__(256) void detect_dtype(
    const unsigned short* __restrict__ xh, int* __restrict__ flag) {
  __shared__ int cnt;
  if (threadIdx.x == 0) cnt = 0;
  __syncthreads();
  int c = 0;
  for (int i = threadIdx.x; i < 8192; i += 256) {
    unsigned int e = (xh[i] >> 7) & 0xFFu;
    if (e > 140u) c++;
  }
  atomicAdd(&cnt, c);
  __syncthreads();
  if (threadIdx.x == 0) *flag = (cnt > 512) ? 1 : 0;
}

// ---------------- fused canonicalize: 10 segments in one launch ------------
// mode 0: ->f32, mode 3: ->fp16 single, mode 4: ->fp16 split(hi,lo)
__device__ inline void canon_seg(const void* in, char* d0, char* d1, int n,
                                 int mode, int f32in, int i) {
  if (i >= n) return;
  float v[8];
  if (f32in) {
    const float* f = (const float*)in;
    *(float4*)(v)     = *(const float4*)(f + i);
    *(float4*)(v + 4) = *(const float4*)(f + i + 4);
  } else {
    up8(*(const uint4*)((const bf16*)in + i), v);
  }
  if (mode == 0) {
    *(float4*)((float*)d0 + i)     = *(const float4*)(v);
    *(float4*)((float*)d0 + i + 4) = *(const float4*)(v + 4);
  } else if (mode == 3) {
    f16 t[8];
#pragma unroll
    for (int j = 0; j < 8; j++) t[j] = (f16)v[j];
    *(uint4*)((f16*)d0 + i) = *(const uint4*)t;
  } else {
    f16 th[8], tl[8];
#pragma unroll
    for (int j = 0; j < 8; j++) {
      th[j] = (f16)v[j];
      tl[j] = (f16)(v[j] - (float)th[j]);
    }
    *(uint4*)((f16*)d0 + i) = *(const uint4*)th;
    *(uint4*)((f16*)d1 + i) = *(const uint4*)tl;
  }
}

// block ranges (2048 elems per block):
// [0,1) dt | [1,2) al | [2,3) nw | [3,15) cw | [15,31) wb | [31,47) wa |
// [47,4143) x-split16 | [4143,10287) wqkv-fp16 | [10287,12335) wz-fp16 |
// [12335,14383) wout-fp16
__global__ __launch_bounds__(256) void canon_all(
    const void* x, const void* wqkv, const void* cw, const void* wz,
    const void* wb, const void* wa, const void* dt, const void* al,
    const void* nw, const void* wout, char* ws, const int* __restrict__ flag) {
  const int bk = blockIdx.x;
  const int f32in = *flag;
  if (bk < 1)
    canon_seg(dt, ws + DT_OFF, 0, 16, 0, f32in, (bk - 0) * 2048 + threadIdx.x * 8);
  else if (bk < 2)
    canon_seg(al, ws + AL_OFF, 0, 16, 0, f32in, (bk - 1) * 2048 + threadIdx.x * 8);
  else if (bk < 3)
    canon_seg(nw, ws + NW_OFF, 0, 128, 0, f32in, (bk - 2) * 2048 + threadIdx.x * 8);
  else if (bk < 15)
    canon_seg(cw, ws + CW_OFF, 0, CDIM * 4, 0, f32in, (bk - 3) * 2048 + threadIdx.x * 8);
  else if (bk < 31)
    canon_seg(wb, ws + WBF_OFF, 0, H_ * DM, 0, f32in, (bk - 15) * 2048 + threadIdx.x * 8);
  else if (bk < 47)
    canon_seg(wa, ws + WAF_OFF, 0, H_ * DM, 0, f32in, (bk - 31) * 2048 + threadIdx.x * 8);
  else if (bk < 4143)
    canon_seg(x, ws + XH_OFF, ws + XL_OFF, B_ * T_ * DM, 4, f32in,
              (bk - 47) * 2048 + threadIdx.x * 8);
  else if (bk < 10287)
    canon_seg(wqkv, ws + WQH_OFF, 0, CDIM * DM, 3, f32in,
              (bk - 4143) * 2048 + threadIdx.x * 8);
  else if (bk < 12335)
    canon_seg(wz, ws + WZ_OFF, 0, H_ * DV_ * DM, 3, f32in,
              (bk - 10287) * 2048 + threadIdx.x * 8);
  else
    canon_seg(wout, ws + WOUT_OFF, 0, DM * H_ * DV_, 3, f32in,
              (bk - 12335) * 2048 + threadIdx.x * 8);
}

// -------- fp16 GEMM, m97 structure. ASPLIT: A = hi+lo (2 MFMA/pair).
// OMODE 0: f32 out, 1: bf16 out, 2: dual (flag ? f32 : bf16).
template <int ASPLIT, int OMODE>
__global__ __launch_bounds__(256) void gemm_f16(
    const f16* __restrict__ Ah, const f16* __restrict__ Al,
    const f16* __restrict__ Bm, void* __restrict__ C,
    int M, int N, int K, const int* __restrict__ flag) {
  __shared__ __align__(16) f16 sAh[128 * 32];
  __shared__ __align__(16) f16 sAl[ASPLIT ? 128 * 32 : 16];
  __shared__ __align__(16) f16 sB[128 * 32];
  const int tid  = threadIdx.x;
  const int wave = tid >> 6;
  const int lane = tid & 63;
  const int m0 = blockIdx.y * 128;
  const int n0 = blockIdx.x * 128;
  const int wm = (wave >> 1) * 64;
  const int wn = (wave & 1) * 64;
  const int lrow = lane & 15;
  const int kq   = lane >> 4;

  f32x4 acc[4][4];
#pragma unroll
  for (int i = 0; i < 4; i++)
#pragma unroll
    for (int j = 0; j < 4; j++) acc[i][j] = (f32x4){0.f, 0.f, 0.f, 0.f};

  const int row0 = tid >> 2;
  const int cb   = (tid & 3) * 8;
  const size_t aoff = (size_t)(m0 + row0) * K + cb;
  const size_t boff = (size_t)(n0 + row0) * K + cb;

  for (int k0 = 0; k0 < K; k0 += 32) {
    gl2lds16(Ah + aoff + k0,                  sAh + wave * 512);
    gl2lds16(Ah + aoff + k0 + (size_t)64 * K, sAh + 2048 + wave * 512);
    if (ASPLIT) {
      gl2lds16(Al + aoff + k0,                  sAl + wave * 512);
      gl2lds16(Al + aoff + k0 + (size_t)64 * K, sAl + 2048 + wave * 512);
    }
    gl2lds16(Bm + boff + k0,                  sB + wave * 512);
    gl2lds16(Bm + boff + k0 + (size_t)64 * K, sB + 2048 + wave * 512);
    stage_fence();        // R4: unconditional DMA drain before the barrier
    __syncthreads();

    f16x8 afh[4], afl[4], bfr[4];
#pragma unroll
    for (int i = 0; i < 4; i++) {
      const int ao = (wm + i * 16 + lrow) * 32 + kq * 8;
      afh[i] = *(const f16x8*)(sAh + ao);
      if (ASPLIT) afl[i] = *(const f16x8*)(sAl + ao);
      bfr[i] = *(const f16x8*)(sB + (wn + i * 16 + lrow) * 32 + kq * 8);
    }
#pragma unroll
    for (int i = 0; i < 4; i++)
#pragma unroll
      for (int j = 0; j < 4; j++) {
        acc[i][j] = __builtin_amdgcn_mfma_f32_16x16x32_f16(afh[i], bfr[j], acc[i][j], 0, 0, 0);
        if (ASPLIT)
          acc[i][j] = __builtin_amdgcn_mfma_f32_16x16x32_f16(afl[i], bfr[j], acc[i][j], 0, 0, 0);
      }
    __syncthreads();
  }

  const int f32o = (OMODE == 0) ? 1 : ((OMODE == 2) ? *flag : 0);
#pragma unroll
  for (int i = 0; i < 4; i++) {
    const int r0 = m0 + wm + i * 16 + kq * 4;
#pragma unroll
    for (int j = 0; j < 4; j++) {
      const int c = n0 + wn + j * 16 + lrow;
#pragma unroll
      for (int r = 0; r < 4; r++) {
        const size_t idx = (size_t)(r0 + r) * N + c;
        if (f32o) ((float*)C)[idx] = acc[i][j][r];
        else      ((bf16*)C)[idx] = __float2bfloat16(acc[i][j][r]);
      }
    }
  }
}

// ---------------- conv (causal, KW=4) + SiLU + per-head l2norm (f32) -------
__global__ __launch_bounds__(128) void conv_silu_norm(
    const float* __restrict__ mixed, const float* __restrict__ convw,
    float* __restrict__ y) {
  const int g = blockIdx.x;
  const int n = blockIdx.y;
  const int t = n & (T_ - 1);
  const int c = g * 128 + threadIdx.x;

  const float4 w = *(const float4*)(convw + (size_t)c * 4);

  const float* mc = mixed + (size_t)n * CDIM + c;
  float a = mc[0] * w.w;
  if (t >= 1) a += mc[-CDIM] * w.z;
  if (t >= 2) a += mc[-2 * CDIM] * w.y;
  if (t >= 3) a += mc[-3 * CDIM] * w.x;
  float s = a / (1.f + expf(-a));

  if (g < 32) {
    float ss = s * s;
#pragma unroll
    for (int o = 32; o > 0; o >>= 1) ss += __shfl_xor(ss, o);
    __shared__ float red[2];
    if ((threadIdx.x & 63) == 0) red[threadIdx.x >> 6] = ss;
    __syncthreads();
    s *= rsqrtf(red[0] + red[1] + EPSF);
  }
  y[(size_t)n * CDIM + c] = s;
}

// ---------------- gate projections: beta, decay (full f32) -----------------
__global__ __launch_bounds__(256) void gates_kernel(
    const f16* __restrict__ xh, const f16* __restrict__ xl,
    const float* __restrict__ w_b, const float* __restrict__ w_a,
    const float* __restrict__ dtb, const float* __restrict__ alog,
    float* __restrict__ beta, float* __restrict__ decay) {
  const int n = blockIdx.x, tid = threadIdx.x;
  __shared__ float xs[DM];
  __shared__ float red[32][8];
  {
    uint4 ph = ((const uint4*)(xh + (size_t)n * DM))[tid];
    uint4 pl = ((const uint4*)(xl + (size_t)n * DM))[tid];
    float h[8], l[8]; up8h(ph, h); up8h(pl, l);
    const int b = tid * 8;
#pragma unroll
    for (int j = 0; j < 8; j++) xs[b + j] = h[j] + l[j];
  }
  __syncthreads();
  const int hh = tid >> 3, part = tid & 7;
  const float* wrow =
      (hh < 16 ? w_b + (size_t)hh * DM : w_a + (size_t)(hh - 16) * DM) + part * 256;
  const float* xp = xs + part * 256;
  float sum = 0.f;
#pragma unroll 4
  for (int i = 0; i < 256; i += 4) {
    float4 p = *(const float4*)(wrow + i);
    sum += xp[i + 0] * p.x + xp[i + 1] * p.y + xp[i + 2] * p.z + xp[i + 3] * p.w;
  }
  red[hh][part] = sum;
  __syncthreads();
  if (tid < 32) {
    float d = 0.f;
#pragma unroll
    for (int p = 0; p < 8; p++) d += red[tid][p];
    if (tid < 16) {
      beta[(size_t)n * H_ + tid] = 1.f / (1.f + expf(-d));
    } else {
      const int h = tid - 16;
      float u = d + dtb[h];
      float sp = (u > 20.f) ? u : log1pf(expf(u));
      decay[(size_t)n * H_ + h] = expf(-expf(alog[h]) * sp);
    }
  }
}

// ---------------- delta-rule scan: 2-step fused rounds (R2) ----------------
// Rank-2 composition: per round (t1,t2) the two S₀-dependent rowsums
// c1=k1ᵀS₀ and w2=k2ᵀS₀ are computed in PARALLEL (one DPP-chain depth
// instead of two); kv₂ = d1·w2 + (k2·k1)·u1 with m=k2·k1 off-chain.
// Same lane layout / LDS staging / deferred-store as R7-proven config.
__global__ __launch_bounds__(256, 1) void scan_kernel(
    const float* __restrict__ y, const float* __restrict__ beta,
    const float* __restrict__ decay, float* __restrict__ o) {
  const int vb = blockIdx.x, h = blockIdx.y, b = blockIdx.z;
  const int tid = threadIdx.x;
  const int kg = tid & 15;
  const int vl = tid >> 4;

  __shared__ __align__(16) float sq[2][CGRP][128];
  __shared__ __align__(16) float sk[2][CGRP][128];
  __shared__ __align__(16) float sv[2][CGRP][16];
  __shared__ float sd[2][CGRP];
  __shared__ float sb[2][CGRP];

  const size_t rowbase = (size_t)b * T_ * CDIM;
  const int qoff = h * 128;
  const int koff = 2048 + h * 128;
  const int voff = 4096 + h * 128 + vb * 16;
  const float* bb = beta + (size_t)b * T_ * H_ + h;
  const float* db = decay + (size_t)b * T_ * H_ + h;
  float* ob = o + (size_t)b * T_ * (H_ * DV_) + h * 128 + vb * 16 + vl;

  const int ls = tid >> 4;       // staging: step within group
  const int lj = tid & 15;       // staging: float4 pair {lj*4, 64+lj*4}

  float S[8];
#pragma unroll
  for (int j = 0; j < 8; j++) S[j] = 0.f;

  float4 ga0, ga1, gb0, gb1, gv4;
  float gdd = 0.f, gbt = 0.f;

#define STAGE_ISSUE(t0)                                                      \
  {                                                                          \
    const float* r = y + rowbase + (size_t)((t0) + ls) * CDIM;               \
    ga0 = *(const float4*)(r + qoff + lj * 4);                               \
    ga1 = *(const float4*)(r + qoff + 64 + lj * 4);                          \
    gb0 = *(const float4*)(r + koff + lj * 4);                               \
    gb1 = *(const float4*)(r + koff + 64 + lj * 4);                          \
    if (tid < 64)                                                            \
      gv4 = *(const float4*)(y + rowbase + (size_t)((t0) + (tid >> 2)) * CDIM\
                             + voff + (tid & 3) * 4);                        \
    if (tid < 16) gdd = db[(size_t)((t0) + tid) * H_];                       \
    else if (tid < 32) gbt = bb[(size_t)((t0) + tid - 16) * H_];             \
  }

#define STAGE_WRITE(buf)                                                     \
  {                                                                          \
    *(float4*)&sq[buf][ls][lj * 4]      = ga0;                               \
    *(float4*)&sq[buf][ls][64 + lj * 4] = ga1;                               \
    *(float4*)&sk[buf][ls][lj * 4]      = gb0;                               \
    *(float4*)&sk[buf][ls][64 + lj * 4] = gb1;                               \
    if (tid < 64) *(float4*)&sv[buf][tid >> 2][(tid & 3) * 4] = gv4;         \
    if (tid < 16) sd[buf][tid] = gdd;                                        \
    else if (tid < 32) sb[buf][tid - 16] = gbt;                              \
  }

// read BOTH steps of round r (steps 2r, 2r+1) into registers
#define READ_PAIR(buf, r, Q1, K1, Q2, K2, P)                                 \
  {                                                                          \
    *(float4*)(Q1)       = *(const float4*)&sq[buf][2*(r)][kg * 4];          \
    *(float4*)((Q1) + 4) = *(const float4*)&sq[buf][2*(r)][64 + kg * 4];     \
    *(float4*)(K1)       = *(const float4*)&sk[buf][2*(r)][kg * 4];          \
    *(float4*)((K1) + 4) = *(const float4*)&sk[buf][2*(r)][64 + kg * 4];     \
    *(float4*)(Q2)       = *(const float4*)&sq[buf][2*(r)+1][kg * 4];        \
    *(float4*)((Q2) + 4) = *(const float4*)&sq[buf][2*(r)+1][64 + kg * 4];   \
    *(float4*)(K2)       = *(const float4*)&sk[buf][2*(r)+1][kg * 4];        \
    *(float4*)((K2) + 4) = *(const float4*)&sk[buf][2*(r)+1][64 + kg * 4];   \
    P##v1 = sv[buf][2*(r)][vl];   P##d1 = sd[buf][2*(r)];   P##b1 = sb[buf][2*(r)];   \
    P##v2 = sv[buf][2*(r)+1][vl]; P##d2 = sd[buf][2*(r)+1]; P##b2 = sb[buf][2*(r)+1]; \
  }

  // prime group 0
  STAGE_ISSUE(0);
  STAGE_WRITE(0);
  __syncthreads();

  float q1[8], k1[8], q2[8], k2[8];
  float nq1[8], nk1[8], nq2[8], nk2[8];
  float cv1, cd1, cb1, cv2, cd2, cb2;
  float nv1, nd1, nb1, nv2, nd2, nb2;
  float pp[CGRP];
  READ_PAIR(0, 0, q1, k1, q2, k2, c);

  const int NGRP = T_ / CGRP;
  const int NRND = CGRP / 2;
  for (int g = 0; g < NGRP; g++) {
    const int cbuf = g & 1, nbuf = cbuf ^ 1;
    const bool more = (g + 1 < NGRP);
    if (more) STAGE_ISSUE((g + 1) * CGRP);
#pragma unroll
    for (int r = 0; r < NRND; r++) {
      if (r < NRND - 1) READ_PAIR(cbuf, r + 1, nq1, nk1, nq2, nk2, n);
      // off-chain: m = k2 . k1 (full 128-dot)
      float m0 = fmaf(k2[1], k1[1], k2[0] * k1[0]);
      float m1 = fmaf(k2[3], k1[3], k2[2] * k1[2]);
      float m2 = fmaf(k2[5], k1[5], k2[4] * k1[4]);
      float m3 = fmaf(k2[7], k1[7], k2[6] * k1[6]);
      float mm = row_sum16((m0 + m1) + (m2 + m3));
      // chain: c1 = k1ᵀS₀ and w2 = k2ᵀS₀ in parallel (single DPP depth)
      float c0 = fmaf(S[1], k1[1], S[0] * k1[0]);
      float c1t = fmaf(S[3], k1[3], S[2] * k1[2]);
      float c2t = fmaf(S[5], k1[5], S[4] * k1[4]);
      float c3t = fmaf(S[7], k1[7], S[6] * k1[6]);
      float w0 = fmaf(S[1], k2[1], S[0] * k2[0]);
      float w1t = fmaf(S[3], k2[3], S[2] * k2[2]);
      float w2t = fmaf(S[5], k2[5], S[4] * k2[4]);
      float w3t = fmaf(S[7], k2[7], S[6] * k2[6]);
      float c1s = row_sum16((c0 + c1t) + (c2t + c3t));
      float w2s = row_sum16((w0 + w1t) + (w2t + w3t));
      // scalar chain
      const float u1 = fmaf(-cd1, c1s, cv1) * cb1;
      const float kv2 = fmaf(mm, u1, cd1 * w2s);
      const float u2 = fmaf(-cd2, kv2, cv2) * cb2;
      // S₁ = d1·S₀ + k1·u1 ; output partial for t1
#pragma unroll
      for (int j = 0; j < 8; j++) S[j] = fmaf(cd1, S[j], k1[j] * u1);
      {
        float p0 = fmaf(S[1], q1[1], S[0] * q1[0]);
        float p1 = fmaf(S[3], q1[3], S[2] * q1[2]);
        float p2 = fmaf(S[5], q1[5], S[4] * q1[4]);
        float p3 = fmaf(S[7], q1[7], S[6] * q1[6]);
        pp[2 * r] = (p0 + p1) + (p2 + p3);
      }
      // S₂ = d2·S₁ + k2·u2 ; output partial for t2
#pragma unroll
      for (int j = 0; j < 8; j++) S[j] = fmaf(cd2, S[j], k2[j] * u2);
      {
        float p0 = fmaf(S[1], q2[1], S[0] * q2[0]);
        float p1 = fmaf(S[3], q2[3], S[2] * q2[2]);
        float p2 = fmaf(S[5], q2[5], S[4] * q2[4]);
        float p3 = fmaf(S[7], q2[7], S[6] * q2[6]);
        pp[2 * r + 1] = (p0 + p1) + (p2 + p3);
      }
      if (r < NRND - 1) {
#pragma unroll
        for (int j = 0; j < 8; j++) {
          q1[j] = nq1[j]; k1[j] = nk1[j]; q2[j] = nq2[j]; k2[j] = nk2[j];
        }
        cv1 = nv1; cd1 = nd1; cb1 = nb1; cv2 = nv2; cd2 = nd2; cb2 = nb2;
      }
    }
    // deferred: 16 independent rowsums (pipelined DPP) + stores
#pragma unroll
    for (int s = 0; s < CGRP; s++) pp[s] = row_sum16(pp[s]);
    if (kg == 0) {
#pragma unroll
      for (int s = 0; s < CGRP; s++)
        ob[(size_t)(g * CGRP + s) * (H_ * DV_)] = pp[s];
    }
    if (more) {
      STAGE_WRITE(nbuf);
      __syncthreads();
      READ_PAIR(nbuf, 0, q1, k1, q2, k2, c);
    }
  }
#undef STAGE_ISSUE
#undef STAGE_WRITE
#undef READ_PAIR
}

// -------- gated RMSNorm + SiLU(z) gate -> single fp16 ----------------------
__global__ __launch_bounds__(128) void norm_gate(
    const float* __restrict__ o, const bf16* __restrict__ z,
    const float* __restrict__ norm_w, f16* __restrict__ on_h) {
  const int n = blockIdx.x, h = blockIdx.y, v = threadIdx.x;
  const size_t idx = (size_t)n * (H_ * DV_) + h * 128 + v;
  const float ov = o[idx];
  float ss = ov * ov;
#pragma unroll
  for (int w = 32; w > 0; w >>= 1) ss += __shfl_xor(ss, w);
  __shared__ float red[2];
  if ((v & 63) == 0) red[v >> 6] = ss;
  __syncthreads();
  const float ms = (red[0] + red[1]) * (1.f / 128.f);
  const float zv = __bfloat162float(z[idx]);
  const float res = ov * rsqrtf(ms + EPSF) * norm_w[v] *
                    (zv / (1.f + expf(-zv)));
  on_h[idx] = (f16)res;
}

// ---------------------------------------------------------------------------
extern "C" void kernel_launch(void* const* d_in, const int* in_sizes, int n_in,
                              void* d_out, int out_size, void* d_ws, size_t ws_size,
                              hipStream_t stream) {
  const int NT = B_ * T_;  // 4096
  char* ws = (char*)d_ws;
  int*   flag   = (int*)(ws + FLAG_OFF);
  float* dt_f   = (float*)(ws + DT_OFF);
  float* al_f   = (float*)(ws + AL_OFF);
  float* nw_f   = (float*)(ws + NW_OFF);
  float* cw_f   = (float*)(ws + CW_OFF);
  float* wb_f   = (float*)(ws + WBF_OFF);
  float* wa_f   = (float*)(ws + WAF_OFF);
  float* betab  = (float*)(ws + BETA_OFF);
  float* decayb = (float*)(ws + DEC_OFF);
  f16*   x_hi   = (f16*)(ws + XH_OFF);
  f16*   x_lo   = (f16*)(ws + XL_OFF);
  f16*   wq_hi  = (f16*)(ws + WQH_OFF);
  f16*   wz_h   = (f16*)(ws + WZ_OFF);
  float* mixed  = (float*)(ws + MIX_OFF);
  f16*   wout_h = (f16*)(ws + WOUT_OFF);
  bf16*  z      = (bf16*)(ws + Z_OFF);
  float* y      = (float*)(ws + Y_OFF);
  float* o      = (float*)(ws + O_OFF);
  f16*   on_h   = (f16*)(ws + ONH_OFF);

  // 0. detect input dtype (flag=1 -> f32)
  detect_dtype<<<1, 256, 0, stream>>>((const unsigned short*)d_in[0], flag);

  // 1. canonicalize everything in one launch
  canon_all<<<14383, 256, 0, stream>>>(
      d_in[0], d_in[1], d_in[2], d_in[3], d_in[4], d_in[5], d_in[6], d_in[7],
      d_in[8], d_in[9], ws, flag);

  // 2. gates (f32-precision beta/decay; x = fp16 hi+lo ~22-bit)
  gates_kernel<<<NT, 256, 0, stream>>>(x_hi, x_lo, wb_f, wa_f, dt_f, al_f,
                                       betab, decayb);
  // 3. mixed = x @ w_qkv^T  (single-term fp16; R1 null-result anchors the
  //    precision: B-side single fp16 left absmax bit-identical) -> f32
  gemm_f16<0, 0><<<dim3(CDIM / 128, NT / 128), 256, 0, stream>>>(
      x_hi, (const f16*)0, wq_hi, mixed, NT, CDIM, DM, flag);
  // 4. z = x @ w_z^T  (single-term fp16) -> bf16
  gemm_f16<0, 1><<<dim3((H_ * DV_) / 128, NT / 128), 256, 0, stream>>>(
      x_hi, (const f16*)0, wz_h, z, NT, H_ * DV_, DM, flag);
  // 5. conv + SiLU + l2norm -> y f32 (overlays dead x/wq/wz)
  conv_silu_norm<<<dim3(CDIM / 128, NT), 128, 0, stream>>>(mixed, cw_f, y);
  // 6. delta-rule scan (2-step fused) -> o f32 (overlays dead mixed)
  scan_kernel<<<dim3(DV_ / 16, H_, B_), 256, 0, stream>>>(y, betab, decayb, o);
  // 7. gated RMSNorm -> on fp16 (overlays dead y)
  norm_gate<<<dim3(NT, H_), 128, 0, stream>>>(o, z, nw_f, on_h);
  // 8. out = on @ w_out^T (single-term fp16, dual-dtype out)
  gemm_f16<0, 2><<<dim3(DM / 128, NT / 128), 256, 0, stream>>>(
      on_h, (const f16*)0, wout_h, d_out, NT, DM, H_ * DV_, flag);
}

// Round 6
// 926.619 us; speedup vs baseline: 1.3035x; 1.0613x over previous
//
#include <hip/hip_runtime.h>
#include <hip/hip_bf16.h>

#define B_   2
#define T_   2048
#define DM   2048
#define H_   16
#define DK_  128
#define DV_  128
#define CDIM 6144
#define EPSF 1e-6f
#define CGRP 16   // scan: timesteps staged per LDS group

typedef __hip_bfloat16 bf16;
typedef _Float16 f16;
typedef short bf16x8 __attribute__((ext_vector_type(8)));
typedef _Float16 f16x8 __attribute__((ext_vector_type(8)));
typedef float f32x4 __attribute__((ext_vector_type(4)));
typedef float f32x2 __attribute__((ext_vector_type(2)));

// ---- workspace layout (bytes); peak = 227,540,992 < proven-OK 228,589,568 --
#define FLAG_OFF   0
#define DT_OFF     1024
#define AL_OFF     2048
#define NW_OFF     4096
#define CW_OFF     8192
#define WBF_OFF    131072
#define WAF_OFF    262144
#define BETA_OFF   393216
#define DEC_OFF    655360
#define XH_OFF     1048576
#define XL_OFF     17825792
#define WQH_OFF    34603008
#define WZ_OFF     84934656
#define MIX_OFF    101711872
#define WOUT_OFF   202375168
#define Z_OFF      210763776
#define Y_OFF      1048576
#define O_OFF      101711872
#define ONH_OFF    1048576

__device__ inline float bf2f(unsigned int u) {
  union { unsigned int i; float f; } v; v.i = u << 16; return v.f;
}
__device__ inline void up8(uint4 p, float* d) {
  d[0] = bf2f(p.x & 0xffffu); d[1] = bf2f(p.x >> 16);
  d[2] = bf2f(p.y & 0xffffu); d[3] = bf2f(p.y >> 16);
  d[4] = bf2f(p.z & 0xffffu); d[5] = bf2f(p.z >> 16);
  d[6] = bf2f(p.w & 0xffffu); d[7] = bf2f(p.w >> 16);
}
// fp16 x8 unpack (v_cvt_f32_f16)
__device__ inline void up8h(uint4 p, float* d) {
  union { unsigned int i; _Float16 h[2]; } c;
  c.i = p.x; d[0] = (float)c.h[0]; d[1] = (float)c.h[1];
  c.i = p.y; d[2] = (float)c.h[0]; d[3] = (float)c.h[1];
  c.i = p.z; d[4] = (float)c.h[0]; d[5] = (float)c.h[1];
  c.i = p.w; d[6] = (float)c.h[0]; d[7] = (float)c.h[1];
}
__device__ inline void gl2lds16(const void* g, void* lds) {
  __builtin_amdgcn_global_load_lds(
      (const __attribute__((address_space(1))) unsigned int*)g,
      (__attribute__((address_space(3))) unsigned int*)lds, 16, 0, 0);
}
// R4 (proven): explicit drain of the global_load_lds DMA queue before the
// staging barrier — fixed the R3 post-timing replay race at ~zero cost.
__device__ inline void stage_fence() {
  asm volatile("s_waitcnt vmcnt(0) lgkmcnt(0)" ::: "memory");
}

// packed 2xf32 FMA -> v_pk_fma_f32 (VOP3P, gfx90a+/gfx950)
__device__ inline f32x2 pkfma(f32x2 a, f32x2 b, f32x2 c) {
  return __builtin_elementwise_fma(a, b, c);
}

// DPP butterfly add over a 16-lane row — stays on the VALU pipe.
template <int CTRL>
__device__ inline float radd(float v) {
  int t = __builtin_amdgcn_update_dpp(0, __float_as_int(v), CTRL, 0xF, 0xF, true);
  return v + __int_as_float(t);
}
__device__ inline float row_sum16(float v) {
  v = radd<0xB1>(v);   // quad_perm [1,0,3,2] : + xor1
  v = radd<0x4E>(v);   // quad_perm [2,3,0,1] : + xor2
  v = radd<0x141>(v);  // row_half_mirror     : + xor4
  v = radd<0x140>(v);  // row_mirror          : + xor8
  return v;
}

// ---------------- dtype detector: flag=1 if inputs are f32 -----------------
__global__ __launch_bounds__(256) void detect_dtype(
    const unsigned short* __restrict__ xh, int* __restrict__ flag) {
  __shared__ int cnt;
  if (threadIdx.x == 0) cnt = 0;
  __syncthreads();
  int c = 0;
  for (int i = threadIdx.x; i < 8192; i += 256) {
    unsigned int e = (xh[i] >> 7) & 0xFFu;
    if (e > 140u) c++;
  }
  atomicAdd(&cnt, c);
  __syncthreads();
  if (threadIdx.x == 0) *flag = (cnt > 512) ? 1 : 0;
}

// ---------------- fused canonicalize: 10 segments in one launch ------------
// mode 0: ->f32, mode 3: ->fp16 single, mode 4: ->fp16 split(hi,lo)
__device__ inline void canon_seg(const void* in, char* d0, char* d1, int n,
                                 int mode, int f32in, int i) {
  if (i >= n) return;
  float v[8];
  if (f32in) {
    const float* f = (const float*)in;
    *(float4*)(v)     = *(const float4*)(f + i);
    *(float4*)(v + 4) = *(const float4*)(f + i + 4);
  } else {
    up8(*(const uint4*)((const bf16*)in + i), v);
  }
  if (mode == 0) {
    *(float4*)((float*)d0 + i)     = *(const float4*)(v);
    *(float4*)((float*)d0 + i + 4) = *(const float4*)(v + 4);
  } else if (mode == 3) {
    f16 t[8];
#pragma unroll
    for (int j = 0; j < 8; j++) t[j] = (f16)v[j];
    *(uint4*)((f16*)d0 + i) = *(const uint4*)t;
  } else {
    f16 th[8], tl[8];
#pragma unroll
    for (int j = 0; j < 8; j++) {
      th[j] = (f16)v[j];
      tl[j] = (f16)(v[j] - (float)th[j]);
    }
    *(uint4*)((f16*)d0 + i) = *(const uint4*)th;
    *(uint4*)((f16*)d1 + i) = *(const uint4*)tl;
  }
}

// block ranges (2048 elems per block):
// [0,1) dt | [1,2) al | [2,3) nw | [3,15) cw | [15,31) wb | [31,47) wa |
// [47,4143) x-split16 | [4143,10287) wqkv-fp16 | [10287,12335) wz-fp16 |
// [12335,14383) wout-fp16
__global__ __launch_bounds__(256) void canon_all(
    const void* x, const void* wqkv, const void* cw, const void* wz,
    const void* wb, const void* wa, const void* dt, const void* al,
    const void* nw, const void* wout, char* ws, const int* __restrict__ flag) {
  const int bk = blockIdx.x;
  const int f32in = *flag;
  if (bk < 1)
    canon_seg(dt, ws + DT_OFF, 0, 16, 0, f32in, (bk - 0) * 2048 + threadIdx.x * 8);
  else if (bk < 2)
    canon_seg(al, ws + AL_OFF, 0, 16, 0, f32in, (bk - 1) * 2048 + threadIdx.x * 8);
  else if (bk < 3)
    canon_seg(nw, ws + NW_OFF, 0, 128, 0, f32in, (bk - 2) * 2048 + threadIdx.x * 8);
  else if (bk < 15)
    canon_seg(cw, ws + CW_OFF, 0, CDIM * 4, 0, f32in, (bk - 3) * 2048 + threadIdx.x * 8);
  else if (bk < 31)
    canon_seg(wb, ws + WBF_OFF, 0, H_ * DM, 0, f32in, (bk - 15) * 2048 + threadIdx.x * 8);
  else if (bk < 47)
    canon_seg(wa, ws + WAF_OFF, 0, H_ * DM, 0, f32in, (bk - 31) * 2048 + threadIdx.x * 8);
  else if (bk < 4143)
    canon_seg(x, ws + XH_OFF, ws + XL_OFF, B_ * T_ * DM, 4, f32in,
              (bk - 47) * 2048 + threadIdx.x * 8);
  else if (bk < 10287)
    canon_seg(wqkv, ws + WQH_OFF, 0, CDIM * DM, 3, f32in,
              (bk - 4143) * 2048 + threadIdx.x * 8);
  else if (bk < 12335)
    canon_seg(wz, ws + WZ_OFF, 0, H_ * DV_ * DM, 3, f32in,
              (bk - 10287) * 2048 + threadIdx.x * 8);
  else
    canon_seg(wout, ws + WOUT_OFF, 0, DM * H_ * DV_, 3, f32in,
              (bk - 12335) * 2048 + threadIdx.x * 8);
}

// -------- fp16 GEMM, m97 structure. ASPLIT: A = hi+lo (2 MFMA/pair).
// OMODE 0: f32 out, 1: bf16 out, 2: dual (flag ? f32 : bf16).
template <int ASPLIT, int OMODE>
__global__ __launch_bounds__(256) void gemm_f16(
    const f16* __restrict__ Ah, const f16* __restrict__ Al,
    const f16* __restrict__ Bm, void* __restrict__ C,
    int M, int N, int K, const int* __restrict__ flag) {
  __shared__ __align__(16) f16 sAh[128 * 32];
  __shared__ __align__(16) f16 sAl[ASPLIT ? 128 * 32 : 16];
  __shared__ __align__(16) f16 sB[128 * 32];
  const int tid  = threadIdx.x;
  const int wave = tid >> 6;
  const int lane = tid & 63;
  const int m0 = blockIdx.y * 128;
  const int n0 = blockIdx.x * 128;
  const int wm = (wave >> 1) * 64;
  const int wn = (wave & 1) * 64;
  const int lrow = lane & 15;
  const int kq   = lane >> 4;

  f32x4 acc[4][4];
#pragma unroll
  for (int i = 0; i < 4; i++)
#pragma unroll
    for (int j = 0; j < 4; j++) acc[i][j] = (f32x4){0.f, 0.f, 0.f, 0.f};

  const int row0 = tid >> 2;
  const int cb   = (tid & 3) * 8;
  const size_t aoff = (size_t)(m0 + row0) * K + cb;
  const size_t boff = (size_t)(n0 + row0) * K + cb;

  for (int k0 = 0; k0 < K; k0 += 32) {
    gl2lds16(Ah + aoff + k0,                  sAh + wave * 512);
    gl2lds16(Ah + aoff + k0 + (size_t)64 * K, sAh + 2048 + wave * 512);
    if (ASPLIT) {
      gl2lds16(Al + aoff + k0,                  sAl + wave * 512);
      gl2lds16(Al + aoff + k0 + (size_t)64 * K, sAl + 2048 + wave * 512);
    }
    gl2lds16(Bm + boff + k0,                  sB + wave * 512);
    gl2lds16(Bm + boff + k0 + (size_t)64 * K, sB + 2048 + wave * 512);
    stage_fence();        // R4: unconditional DMA drain before the barrier
    __syncthreads();

    f16x8 afh[4], afl[4], bfr[4];
#pragma unroll
    for (int i = 0; i < 4; i++) {
      const int ao = (wm + i * 16 + lrow) * 32 + kq * 8;
      afh[i] = *(const f16x8*)(sAh + ao);
      if (ASPLIT) afl[i] = *(const f16x8*)(sAl + ao);
      bfr[i] = *(const f16x8*)(sB + (wn + i * 16 + lrow) * 32 + kq * 8);
    }
#pragma unroll
    for (int i = 0; i < 4; i++)
#pragma unroll
      for (int j = 0; j < 4; j++) {
        acc[i][j] = __builtin_amdgcn_mfma_f32_16x16x32_f16(afh[i], bfr[j], acc[i][j], 0, 0, 0);
        if (ASPLIT)
          acc[i][j] = __builtin_amdgcn_mfma_f32_16x16x32_f16(afl[i], bfr[j], acc[i][j], 0, 0, 0);
      }
    __syncthreads();
  }

  const int f32o = (OMODE == 0) ? 1 : ((OMODE == 2) ? *flag : 0);
#pragma unroll
  for (int i = 0; i < 4; i++) {
    const int r0 = m0 + wm + i * 16 + kq * 4;
#pragma unroll
    for (int j = 0; j < 4; j++) {
      const int c = n0 + wn + j * 16 + lrow;
#pragma unroll
      for (int r = 0; r < 4; r++) {
        const size_t idx = (size_t)(r0 + r) * N + c;
        if (f32o) ((float*)C)[idx] = acc[i][j][r];
        else      ((bf16*)C)[idx] = __float2bfloat16(acc[i][j][r]);
      }
    }
  }
}

// ---------------- conv (causal, KW=4) + SiLU + per-head l2norm (f32) -------
__global__ __launch_bounds__(128) void conv_silu_norm(
    const float* __restrict__ mixed, const float* __restrict__ convw,
    float* __restrict__ y) {
  const int g = blockIdx.x;
  const int n = blockIdx.y;
  const int t = n & (T_ - 1);
  const int c = g * 128 + threadIdx.x;

  const float4 w = *(const float4*)(convw + (size_t)c * 4);

  const float* mc = mixed + (size_t)n * CDIM + c;
  float a = mc[0] * w.w;
  if (t >= 1) a += mc[-CDIM] * w.z;
  if (t >= 2) a += mc[-2 * CDIM] * w.y;
  if (t >= 3) a += mc[-3 * CDIM] * w.x;
  float s = a / (1.f + expf(-a));

  if (g < 32) {
    float ss = s * s;
#pragma unroll
    for (int o = 32; o > 0; o >>= 1) ss += __shfl_xor(ss, o);
    __shared__ float red[2];
    if ((threadIdx.x & 63) == 0) red[threadIdx.x >> 6] = ss;
    __syncthreads();
    s *= rsqrtf(red[0] + red[1] + EPSF);
  }
  y[(size_t)n * CDIM + c] = s;
}

// ---------------- gate projections: beta, decay (full f32) -----------------
__global__ __launch_bounds__(256) void gates_kernel(
    const f16* __restrict__ xh, const f16* __restrict__ xl,
    const float* __restrict__ w_b, const float* __restrict__ w_a,
    const float* __restrict__ dtb, const float* __restrict__ alog,
    float* __restrict__ beta, float* __restrict__ decay) {
  const int n = blockIdx.x, tid = threadIdx.x;
  __shared__ float xs[DM];
  __shared__ float red[32][8];
  {
    uint4 ph = ((const uint4*)(xh + (size_t)n * DM))[tid];
    uint4 pl = ((const uint4*)(xl + (size_t)n * DM))[tid];
    float h[8], l[8]; up8h(ph, h); up8h(pl, l);
    const int b = tid * 8;
#pragma unroll
    for (int j = 0; j < 8; j++) xs[b + j] = h[j] + l[j];
  }
  __syncthreads();
  const int hh = tid >> 3, part = tid & 7;
  const float* wrow =
      (hh < 16 ? w_b + (size_t)hh * DM : w_a + (size_t)(hh - 16) * DM) + part * 256;
  const float* xp = xs + part * 256;
  float sum = 0.f;
#pragma unroll 4
  for (int i = 0; i < 256; i += 4) {
    float4 p = *(const float4*)(wrow + i);
    sum += xp[i + 0] * p.x + xp[i + 1] * p.y + xp[i + 2] * p.z + xp[i + 3] * p.w;
  }
  red[hh][part] = sum;
  __syncthreads();
  if (tid < 32) {
    float d = 0.f;
#pragma unroll
    for (int p = 0; p < 8; p++) d += red[tid][p];
    if (tid < 16) {
      beta[(size_t)n * H_ + tid] = 1.f / (1.f + expf(-d));
    } else {
      const int h = tid - 16;
      float u = d + dtb[h];
      float sp = (u > 20.f) ? u : log1pf(expf(u));
      decay[(size_t)n * H_ + h] = expf(-expf(alog[h]) * sp);
    }
  }
}

// ---------------- delta-rule scan: 2-step rounds + packed f32 (R5) ---------
// R5: core dots / S-updates / output partials in f32x2 -> v_pk_fma_f32
// (one instruction = 2 FMAs; scan is VALU-issue-bound at 56% busy, R2/R4
// counters). Values are IEEE-identical to the scalar form. Rowsums (DPP)
// and the scalar u-chain unchanged. Same LDS staging / deferred stores.
__global__ __launch_bounds__(256, 1) void scan_kernel(
    const float* __restrict__ y, const float* __restrict__ beta,
    const float* __restrict__ decay, float* __restrict__ o) {
  const int vb = blockIdx.x, h = blockIdx.y, b = blockIdx.z;
  const int tid = threadIdx.x;
  const int kg = tid & 15;
  const int vl = tid >> 4;

  __shared__ __align__(16) float sq[2][CGRP][128];
  __shared__ __align__(16) float sk[2][CGRP][128];
  __shared__ __align__(16) float sv[2][CGRP][16];
  __shared__ float sd[2][CGRP];
  __shared__ float sb[2][CGRP];

  const size_t rowbase = (size_t)b * T_ * CDIM;
  const int qoff = h * 128;
  const int koff = 2048 + h * 128;
  const int voff = 4096 + h * 128 + vb * 16;
  const float* bb = beta + (size_t)b * T_ * H_ + h;
  const float* db = decay + (size_t)b * T_ * H_ + h;
  float* ob = o + (size_t)b * T_ * (H_ * DV_) + h * 128 + vb * 16 + vl;

  const int ls = tid >> 4;       // staging: step within group
  const int lj = tid & 15;       // staging: float4 pair {lj*4, 64+lj*4}

  f32x2 S2[4];
#pragma unroll
  for (int j = 0; j < 4; j++) S2[j] = (f32x2){0.f, 0.f};

  float4 ga0, ga1, gb0, gb1, gv4;
  float gdd = 0.f, gbt = 0.f;

#define STAGE_ISSUE(t0)                                                      \
  {                                                                          \
    const float* r = y + rowbase + (size_t)((t0) + ls) * CDIM;               \
    ga0 = *(const float4*)(r + qoff + lj * 4);                               \
    ga1 = *(const float4*)(r + qoff + 64 + lj * 4);                          \
    gb0 = *(const float4*)(r + koff + lj * 4);                               \
    gb1 = *(const float4*)(r + koff + 64 + lj * 4);                          \
    if (tid < 64)                                                            \
      gv4 = *(const float4*)(y + rowbase + (size_t)((t0) + (tid >> 2)) * CDIM\
                             + voff + (tid & 3) * 4);                        \
    if (tid < 16) gdd = db[(size_t)((t0) + tid) * H_];                       \
    else if (tid < 32) gbt = bb[(size_t)((t0) + tid - 16) * H_];             \
  }

#define STAGE_WRITE(buf)                                                     \
  {                                                                          \
    *(float4*)&sq[buf][ls][lj * 4]      = ga0;                               \
    *(float4*)&sq[buf][ls][64 + lj * 4] = ga1;                               \
    *(float4*)&sk[buf][ls][lj * 4]      = gb0;                               \
    *(float4*)&sk[buf][ls][64 + lj * 4] = gb1;                               \
    if (tid < 64) *(float4*)&sv[buf][tid >> 2][(tid & 3) * 4] = gv4;         \
    if (tid < 16) sd[buf][tid] = gdd;                                        \
    else if (tid < 32) sb[buf][tid - 16] = gbt;                              \
  }

// float4 -> 2x f32x2 (sub-register rename, no VALU cost)
#define CVT2(dst, a, bfour)                                                  \
  {                                                                          \
    float4 _a = (a), _b = (bfour);                                           \
    dst[0] = (f32x2){_a.x, _a.y}; dst[1] = (f32x2){_a.z, _a.w};              \
    dst[2] = (f32x2){_b.x, _b.y}; dst[3] = (f32x2){_b.z, _b.w};              \
  }

// read BOTH steps of round r (steps 2r, 2r+1) into f32x2 registers
#define READ_PAIR(buf, r, Q1, K1, Q2, K2, P)                                 \
  {                                                                          \
    CVT2(Q1, *(const float4*)&sq[buf][2*(r)][kg * 4],                        \
             *(const float4*)&sq[buf][2*(r)][64 + kg * 4]);                  \
    CVT2(K1, *(const float4*)&sk[buf][2*(r)][kg * 4],                        \
             *(const float4*)&sk[buf][2*(r)][64 + kg * 4]);                  \
    CVT2(Q2, *(const float4*)&sq[buf][2*(r)+1][kg * 4],                      \
             *(const float4*)&sq[buf][2*(r)+1][64 + kg * 4]);                \
    CVT2(K2, *(const float4*)&sk[buf][2*(r)+1][kg * 4],                      \
             *(const float4*)&sk[buf][2*(r)+1][64 + kg * 4]);                \
    P##v1 = sv[buf][2*(r)][vl];   P##d1 = sd[buf][2*(r)];   P##b1 = sb[buf][2*(r)];   \
    P##v2 = sv[buf][2*(r)+1][vl]; P##d2 = sd[buf][2*(r)+1]; P##b2 = sb[buf][2*(r)+1]; \
  }

  // prime group 0
  STAGE_ISSUE(0);
  STAGE_WRITE(0);
  __syncthreads();

  f32x2 q1[4], k1[4], q2[4], k2[4];
  f32x2 nq1[4], nk1[4], nq2[4], nk2[4];
  float cv1, cd1, cb1, cv2, cd2, cb2;
  float nv1, nd1, nb1, nv2, nd2, nb2;
  float pp[CGRP];
  READ_PAIR(0, 0, q1, k1, q2, k2, c);

  const int NGRP = T_ / CGRP;
  const int NRND = CGRP / 2;
  for (int g = 0; g < NGRP; g++) {
    const int cbuf = g & 1, nbuf = cbuf ^ 1;
    const bool more = (g + 1 < NGRP);
    if (more) STAGE_ISSUE((g + 1) * CGRP);
#pragma unroll
    for (int r = 0; r < NRND; r++) {
      if (r < NRND - 1) READ_PAIR(cbuf, r + 1, nq1, nk1, nq2, nk2, n);
      // off-chain: m = k2 . k1 (packed tree: 2 pk_mul + 2 pk_fma + 1 pk_add)
      f32x2 ma = pkfma(k2[1], k1[1], k2[0] * k1[0]);
      f32x2 mb = pkfma(k2[3], k1[3], k2[2] * k1[2]);
      f32x2 mv = ma + mb;
      float mm = row_sum16(mv.x + mv.y);
      // chain: c1 = k1'S0 and w2 = k2'S0 in parallel (packed, 1 DPP depth)
      f32x2 ca = pkfma(S2[1], k1[1], S2[0] * k1[0]);
      f32x2 cb_ = pkfma(S2[3], k1[3], S2[2] * k1[2]);
      f32x2 cvv = ca + cb_;
      f32x2 wa = pkfma(S2[1], k2[1], S2[0] * k2[0]);
      f32x2 wb = pkfma(S2[3], k2[3], S2[2] * k2[2]);
      f32x2 wvv = wa + wb;
      float c1s = row_sum16(cvv.x + cvv.y);
      float w2s = row_sum16(wvv.x + wvv.y);
      // scalar chain
      const float u1 = fmaf(-cd1, c1s, cv1) * cb1;
      const float kv2 = fmaf(mm, u1, cd1 * w2s);
      const float u2 = fmaf(-cd2, kv2, cv2) * cb2;
      // S1 = d1*S0 + k1*u1 ; output partial for t1 (packed)
      {
        const f32x2 dv = (f32x2){cd1, cd1}, uv = (f32x2){u1, u1};
#pragma unroll
        for (int j = 0; j < 4; j++) S2[j] = pkfma(dv, S2[j], k1[j] * uv);
        f32x2 pa = pkfma(S2[1], q1[1], S2[0] * q1[0]);
        f32x2 pb = pkfma(S2[3], q1[3], S2[2] * q1[2]);
        f32x2 pv = pa + pb;
        pp[2 * r] = pv.x + pv.y;
      }
      // S2 = d2*S1 + k2*u2 ; output partial for t2 (packed)
      {
        const f32x2 dv = (f32x2){cd2, cd2}, uv = (f32x2){u2, u2};
#pragma unroll
        for (int j = 0; j < 4; j++) S2[j] = pkfma(dv, S2[j], k2[j] * uv);
        f32x2 pa = pkfma(S2[1], q2[1], S2[0] * q2[0]);
        f32x2 pb = pkfma(S2[3], q2[3], S2[2] * q2[2]);
        f32x2 pv = pa + pb;
        pp[2 * r + 1] = pv.x + pv.y;
      }
      if (r < NRND - 1) {
#pragma unroll
        for (int j = 0; j < 4; j++) {
          q1[j] = nq1[j]; k1[j] = nk1[j]; q2[j] = nq2[j]; k2[j] = nk2[j];
        }
        cv1 = nv1; cd1 = nd1; cb1 = nb1; cv2 = nv2; cd2 = nd2; cb2 = nb2;
      }
    }
    // deferred: 16 independent rowsums (pipelined DPP) + stores
#pragma unroll
    for (int s = 0; s < CGRP; s++) pp[s] = row_sum16(pp[s]);
    if (kg == 0) {
#pragma unroll
      for (int s = 0; s < CGRP; s++)
        ob[(size_t)(g * CGRP + s) * (H_ * DV_)] = pp[s];
    }
    if (more) {
      STAGE_WRITE(nbuf);
      __syncthreads();
      READ_PAIR(nbuf, 0, q1, k1, q2, k2, c);
    }
  }
#undef STAGE_ISSUE
#undef STAGE_WRITE
#undef READ_PAIR
#undef CVT2
}

// -------- gated RMSNorm + SiLU(z) gate -> single fp16 ----------------------
__global__ __launch_bounds__(128) void norm_gate(
    const float* __restrict__ o, const bf16* __restrict__ z,
    const float* __restrict__ norm_w, f16* __restrict__ on_h) {
  const int n = blockIdx.x, h = blockIdx.y, v = threadIdx.x;
  const size_t idx = (size_t)n * (H_ * DV_) + h * 128 + v;
  const float ov = o[idx];
  float ss = ov * ov;
#pragma unroll
  for (int w = 32; w > 0; w >>= 1) ss += __shfl_xor(ss, w);
  __shared__ float red[2];
  if ((v & 63) == 0) red[v >> 6] = ss;
  __syncthreads();
  const float ms = (red[0] + red[1]) * (1.f / 128.f);
  const float zv = __bfloat162float(z[idx]);
  const float res = ov * rsqrtf(ms + EPSF) * norm_w[v] *
                    (zv / (1.f + expf(-zv)));
  on_h[idx] = (f16)res;
}

// ---------------------------------------------------------------------------
extern "C" void kernel_launch(void* const* d_in, const int* in_sizes, int n_in,
                              void* d_out, int out_size, void* d_ws, size_t ws_size,
                              hipStream_t stream) {
  const int NT = B_ * T_;  // 4096
  char* ws = (char*)d_ws;
  int*   flag   = (int*)(ws + FLAG_OFF);
  float* dt_f   = (float*)(ws + DT_OFF);
  float* al_f   = (float*)(ws + AL_OFF);
  float* nw_f   = (float*)(ws + NW_OFF);
  float* cw_f   = (float*)(ws + CW_OFF);
  float* wb_f   = (float*)(ws + WBF_OFF);
  float* wa_f   = (float*)(ws + WAF_OFF);
  float* betab  = (float*)(ws + BETA_OFF);
  float* decayb = (float*)(ws + DEC_OFF);
  f16*   x_hi   = (f16*)(ws + XH_OFF);
  f16*   x_lo   = (f16*)(ws + XL_OFF);
  f16*   wq_hi  = (f16*)(ws + WQH_OFF);
  f16*   wz_h   = (f16*)(ws + WZ_OFF);
  float* mixed  = (float*)(ws + MIX_OFF);
  f16*   wout_h = (f16*)(ws + WOUT_OFF);
  bf16*  z      = (bf16*)(ws + Z_OFF);
  float* y      = (float*)(ws + Y_OFF);
  float* o      = (float*)(ws + O_OFF);
  f16*   on_h   = (f16*)(ws + ONH_OFF);

  // 0. detect input dtype (flag=1 -> f32)
  detect_dtype<<<1, 256, 0, stream>>>((const unsigned short*)d_in[0], flag);

  // 1. canonicalize everything in one launch
  canon_all<<<14383, 256, 0, stream>>>(
      d_in[0], d_in[1], d_in[2], d_in[3], d_in[4], d_in[5], d_in[6], d_in[7],
      d_in[8], d_in[9], ws, flag);

  // 2. gates (f32-precision beta/decay; x = fp16 hi+lo ~22-bit)
  gates_kernel<<<NT, 256, 0, stream>>>(x_hi, x_lo, wb_f, wa_f, dt_f, al_f,
                                       betab, decayb);
  // 3. mixed = x @ w_qkv^T  (single-term fp16) -> f32
  gemm_f16<0, 0><<<dim3(CDIM / 128, NT / 128), 256, 0, stream>>>(
      x_hi, (const f16*)0, wq_hi, mixed, NT, CDIM, DM, flag);
  // 4. z = x @ w_z^T  (single-term fp16) -> bf16
  gemm_f16<0, 1><<<dim3((H_ * DV_) / 128, NT / 128), 256, 0, stream>>>(
      x_hi, (const f16*)0, wz_h, z, NT, H_ * DV_, DM, flag);
  // 5. conv + SiLU + l2norm -> y f32 (overlays dead x/wq/wz)
  conv_silu_norm<<<dim3(CDIM / 128, NT), 128, 0, stream>>>(mixed, cw_f, y);
  // 6. delta-rule scan (2-step fused, packed f32) -> o f32 (overlays MIX)
  scan_kernel<<<dim3(DV_ / 16, H_, B_), 256, 0, stream>>>(y, betab, decayb, o);
  // 7. gated RMSNorm -> on fp16 (overlays dead y)
  norm_gate<<<dim3(NT, H_), 128, 0, stream>>>(o, z, nw_f, on_h);
  // 8. out = on @ w_out^T (single-term fp16, dual-dtype out)
  gemm_f16<0, 2><<<dim3(DM / 128, NT / 128), 256, 0, stream>>>(
      on_h, (const f16*)0, wout_h, d_out, NT, DM, H_ * DV_, flag);
}

// Round 7
// 878.815 us; speedup vs baseline: 1.3744x; 1.0544x over previous
//
#include <hip/hip_runtime.h>
#include <hip/hip_bf16.h>

#define B_   2
#define T_   2048
#define DM   2048
#define H_   16
#define DK_  128
#define DV_  128
#define CDIM 6144
#define EPSF 1e-6f
#define CGRP 16   // scan: timesteps staged per LDS group
#define CROWS 16  // conv: rows per block (R6)

typedef __hip_bfloat16 bf16;
typedef _Float16 f16;
typedef short bf16x8 __attribute__((ext_vector_type(8)));
typedef _Float16 f16x8 __attribute__((ext_vector_type(8)));
typedef float f32x4 __attribute__((ext_vector_type(4)));
typedef float f32x2 __attribute__((ext_vector_type(2)));

// ---- workspace layout (bytes); peak = 227,540,992 < proven-OK 228,589,568 --
#define FLAG_OFF   0
#define DT_OFF     1024
#define AL_OFF     2048
#define NW_OFF     4096
#define CW_OFF     8192
#define WBF_OFF    131072
#define WAF_OFF    262144
#define BETA_OFF   393216
#define DEC_OFF    655360
#define XH_OFF     1048576
#define XL_OFF     17825792
#define WQH_OFF    34603008
#define WZ_OFF     84934656
#define MIX_OFF    101711872
#define WOUT_OFF   202375168
#define Z_OFF      210763776
#define Y_OFF      1048576
#define O_OFF      101711872
#define ONH_OFF    1048576

__device__ inline float bf2f(unsigned int u) {
  union { unsigned int i; float f; } v; v.i = u << 16; return v.f;
}
__device__ inline void up8(uint4 p, float* d) {
  d[0] = bf2f(p.x & 0xffffu); d[1] = bf2f(p.x >> 16);
  d[2] = bf2f(p.y & 0xffffu); d[3] = bf2f(p.y >> 16);
  d[4] = bf2f(p.z & 0xffffu); d[5] = bf2f(p.z >> 16);
  d[6] = bf2f(p.w & 0xffffu); d[7] = bf2f(p.w >> 16);
}
// fp16 x8 unpack (v_cvt_f32_f16)
__device__ inline void up8h(uint4 p, float* d) {
  union { unsigned int i; _Float16 h[2]; } c;
  c.i = p.x; d[0] = (float)c.h[0]; d[1] = (float)c.h[1];
  c.i = p.y; d[2] = (float)c.h[0]; d[3] = (float)c.h[1];
  c.i = p.z; d[4] = (float)c.h[0]; d[5] = (float)c.h[1];
  c.i = p.w; d[6] = (float)c.h[0]; d[7] = (float)c.h[1];
}
__device__ inline void gl2lds16(const void* g, void* lds) {
  __builtin_amdgcn_global_load_lds(
      (const __attribute__((address_space(1))) unsigned int*)g,
      (__attribute__((address_space(3))) unsigned int*)lds, 16, 0, 0);
}
// R4 (proven): explicit drain of the global_load_lds DMA queue before the
// staging barrier — fixed the R3 post-timing replay race at ~zero cost.
__device__ inline void stage_fence() {
  asm volatile("s_waitcnt vmcnt(0) lgkmcnt(0)" ::: "memory");
}

// packed 2xf32 FMA -> v_pk_fma_f32 (VOP3P, gfx90a+/gfx950)
__device__ inline f32x2 pkfma(f32x2 a, f32x2 b, f32x2 c) {
  return __builtin_elementwise_fma(a, b, c);
}

// DPP butterfly add over a 16-lane row — stays on the VALU pipe.
template <int CTRL>
__device__ inline float radd(float v) {
  int t = __builtin_amdgcn_update_dpp(0, __float_as_int(v), CTRL, 0xF, 0xF, true);
  return v + __int_as_float(t);
}
__device__ inline float row_sum16(float v) {
  v = radd<0xB1>(v);   // quad_perm [1,0,3,2] : + xor1
  v = radd<0x4E>(v);   // quad_perm [2,3,0,1] : + xor2
  v = radd<0x141>(v);  // row_half_mirror     : + xor4
  v = radd<0x140>(v);  // row_mirror          : + xor8
  return v;
}

// ---------------- dtype detector: flag=1 if inputs are f32 -----------------
__global__ __launch_bounds__(256) void detect_dtype(
    const unsigned short* __restrict__ xh, int* __restrict__ flag) {
  __shared__ int cnt;
  if (threadIdx.x == 0) cnt = 0;
  __syncthreads();
  int c = 0;
  for (int i = threadIdx.x; i < 8192; i += 256) {
    unsigned int e = (xh[i] >> 7) & 0xFFu;
    if (e > 140u) c++;
  }
  atomicAdd(&cnt, c);
  __syncthreads();
  if (threadIdx.x == 0) *flag = (cnt > 512) ? 1 : 0;
}

// ---------------- fused canonicalize: 10 segments in one launch ------------
// mode 0: ->f32, mode 3: ->fp16 single, mode 4: ->fp16 split(hi,lo)
__device__ inline void canon_seg(const void* in, char* d0, char* d1, int n,
                                 int mode, int f32in, int i) {
  if (i >= n) return;
  float v[8];
  if (f32in) {
    const float* f = (const float*)in;
    *(float4*)(v)     = *(const float4*)(f + i);
    *(float4*)(v + 4) = *(const float4*)(f + i + 4);
  } else {
    up8(*(const uint4*)((const bf16*)in + i), v);
  }
  if (mode == 0) {
    *(float4*)((float*)d0 + i)     = *(const float4*)(v);
    *(float4*)((float*)d0 + i + 4) = *(const float4*)(v + 4);
  } else if (mode == 3) {
    f16 t[8];
#pragma unroll
    for (int j = 0; j < 8; j++) t[j] = (f16)v[j];
    *(uint4*)((f16*)d0 + i) = *(const uint4*)t;
  } else {
    f16 th[8], tl[8];
#pragma unroll
    for (int j = 0; j < 8; j++) {
      th[j] = (f16)v[j];
      tl[j] = (f16)(v[j] - (float)th[j]);
    }
    *(uint4*)((f16*)d0 + i) = *(const uint4*)th;
    *(uint4*)((f16*)d1 + i) = *(const uint4*)tl;
  }
}

// block ranges (2048 elems per block):
// [0,1) dt | [1,2) al | [2,3) nw | [3,15) cw | [15,31) wb | [31,47) wa |
// [47,4143) x-split16 | [4143,10287) wqkv-fp16 | [10287,12335) wz-fp16 |
// [12335,14383) wout-fp16
__global__ __launch_bounds__(256) void canon_all(
    const void* x, const void* wqkv, const void* cw, const void* wz,
    const void* wb, const void* wa, const void* dt, const void* al,
    const void* nw, const void* wout, char* ws, const int* __restrict__ flag) {
  const int bk = blockIdx.x;
  const int f32in = *flag;
  if (bk < 1)
    canon_seg(dt, ws + DT_OFF, 0, 16, 0, f32in, (bk - 0) * 2048 + threadIdx.x * 8);
  else if (bk < 2)
    canon_seg(al, ws + AL_OFF, 0, 16, 0, f32in, (bk - 1) * 2048 + threadIdx.x * 8);
  else if (bk < 3)
    canon_seg(nw, ws + NW_OFF, 0, 128, 0, f32in, (bk - 2) * 2048 + threadIdx.x * 8);
  else if (bk < 15)
    canon_seg(cw, ws + CW_OFF, 0, CDIM * 4, 0, f32in, (bk - 3) * 2048 + threadIdx.x * 8);
  else if (bk < 31)
    canon_seg(wb, ws + WBF_OFF, 0, H_ * DM, 0, f32in, (bk - 15) * 2048 + threadIdx.x * 8);
  else if (bk < 47)
    canon_seg(wa, ws + WAF_OFF, 0, H_ * DM, 0, f32in, (bk - 31) * 2048 + threadIdx.x * 8);
  else if (bk < 4143)
    canon_seg(x, ws + XH_OFF, ws + XL_OFF, B_ * T_ * DM, 4, f32in,
              (bk - 47) * 2048 + threadIdx.x * 8);
  else if (bk < 10287)
    canon_seg(wqkv, ws + WQH_OFF, 0, CDIM * DM, 3, f32in,
              (bk - 4143) * 2048 + threadIdx.x * 8);
  else if (bk < 12335)
    canon_seg(wz, ws + WZ_OFF, 0, H_ * DV_ * DM, 3, f32in,
              (bk - 10287) * 2048 + threadIdx.x * 8);
  else
    canon_seg(wout, ws + WOUT_OFF, 0, DM * H_ * DV_, 3, f32in,
              (bk - 12335) * 2048 + threadIdx.x * 8);
}

// -------- fp16 GEMM, m97 structure. ASPLIT: A = hi+lo (2 MFMA/pair).
// OMODE 0: f32 out, 1: bf16 out, 2: dual (flag ? f32 : bf16).
template <int ASPLIT, int OMODE>
__global__ __launch_bounds__(256) void gemm_f16(
    const f16* __restrict__ Ah, const f16* __restrict__ Al,
    const f16* __restrict__ Bm, void* __restrict__ C,
    int M, int N, int K, const int* __restrict__ flag) {
  __shared__ __align__(16) f16 sAh[128 * 32];
  __shared__ __align__(16) f16 sAl[ASPLIT ? 128 * 32 : 16];
  __shared__ __align__(16) f16 sB[128 * 32];
  const int tid  = threadIdx.x;
  const int wave = tid >> 6;
  const int lane = tid & 63;
  const int m0 = blockIdx.y * 128;
  const int n0 = blockIdx.x * 128;
  const int wm = (wave >> 1) * 64;
  const int wn = (wave & 1) * 64;
  const int lrow = lane & 15;
  const int kq   = lane >> 4;

  f32x4 acc[4][4];
#pragma unroll
  for (int i = 0; i < 4; i++)
#pragma unroll
    for (int j = 0; j < 4; j++) acc[i][j] = (f32x4){0.f, 0.f, 0.f, 0.f};

  const int row0 = tid >> 2;
  const int cb   = (tid & 3) * 8;
  const size_t aoff = (size_t)(m0 + row0) * K + cb;
  const size_t boff = (size_t)(n0 + row0) * K + cb;

  for (int k0 = 0; k0 < K; k0 += 32) {
    gl2lds16(Ah + aoff + k0,                  sAh + wave * 512);
    gl2lds16(Ah + aoff + k0 + (size_t)64 * K, sAh + 2048 + wave * 512);
    if (ASPLIT) {
      gl2lds16(Al + aoff + k0,                  sAl + wave * 512);
      gl2lds16(Al + aoff + k0 + (size_t)64 * K, sAl + 2048 + wave * 512);
    }
    gl2lds16(Bm + boff + k0,                  sB + wave * 512);
    gl2lds16(Bm + boff + k0 + (size_t)64 * K, sB + 2048 + wave * 512);
    stage_fence();        // R4: unconditional DMA drain before the barrier
    __syncthreads();

    f16x8 afh[4], afl[4], bfr[4];
#pragma unroll
    for (int i = 0; i < 4; i++) {
      const int ao = (wm + i * 16 + lrow) * 32 + kq * 8;
      afh[i] = *(const f16x8*)(sAh + ao);
      if (ASPLIT) afl[i] = *(const f16x8*)(sAl + ao);
      bfr[i] = *(const f16x8*)(sB + (wn + i * 16 + lrow) * 32 + kq * 8);
    }
#pragma unroll
    for (int i = 0; i < 4; i++)
#pragma unroll
      for (int j = 0; j < 4; j++) {
        acc[i][j] = __builtin_amdgcn_mfma_f32_16x16x32_f16(afh[i], bfr[j], acc[i][j], 0, 0, 0);
        if (ASPLIT)
          acc[i][j] = __builtin_amdgcn_mfma_f32_16x16x32_f16(afl[i], bfr[j], acc[i][j], 0, 0, 0);
      }
    __syncthreads();
  }

  const int f32o = (OMODE == 0) ? 1 : ((OMODE == 2) ? *flag : 0);
#pragma unroll
  for (int i = 0; i < 4; i++) {
    const int r0 = m0 + wm + i * 16 + kq * 4;
#pragma unroll
    for (int j = 0; j < 4; j++) {
      const int c = n0 + wn + j * 16 + lrow;
#pragma unroll
      for (int r = 0; r < 4; r++) {
        const size_t idx = (size_t)(r0 + r) * N + c;
        if (f32o) ((float*)C)[idx] = acc[i][j][r];
        else      ((bf16*)C)[idx] = __float2bfloat16(acc[i][j][r]);
      }
    }
  }
}

// -------- conv (causal, KW=4) + SiLU + per-head l2norm, 16 rows/block ------
// R6: grid 196,608 -> 12,288 wgs (dispatch overhead); causal taps carried in
// registers across the row loop (each `mixed` element read exactly once,
// was <=4x); next-row prefetch hides the load latency. Chunks are 16-row
// aligned and 2048 % 16 == 0, so t==0 only at i==0 (prologue guards).
__global__ __launch_bounds__(128) void conv_silu_norm(
    const float* __restrict__ mixed, const float* __restrict__ convw,
    float* __restrict__ y) {
  const int g  = blockIdx.x;             // 48 channel groups of 128
  const int n0 = blockIdx.y * CROWS;     // first row of this chunk
  const int c  = g * 128 + threadIdx.x;

  const float4 w = *(const float4*)(convw + (size_t)c * 4);
  __shared__ float red[2];

  float x1, x2, x3;
  {
    const int t0 = n0 & (T_ - 1);
    const float* mc = mixed + (size_t)n0 * CDIM + c;
    x1 = (t0 >= 1) ? mc[-CDIM]     : 0.f;
    x2 = (t0 >= 2) ? mc[-2 * CDIM] : 0.f;
    x3 = (t0 >= 3) ? mc[-3 * CDIM] : 0.f;
  }
  float x0 = mixed[(size_t)n0 * CDIM + c];

#pragma unroll 4
  for (int i = 0; i < CROWS; i++) {
    const int n = n0 + i;
    // prefetch next row while computing this one
    float xn = 0.f;
    if (i + 1 < CROWS) xn = mixed[(size_t)(n + 1) * CDIM + c];

    float a = x0 * w.w + x1 * w.z + x2 * w.y + x3 * w.x;
    float s = a / (1.f + expf(-a));

    if (g < 32) {
      float ss = s * s;
#pragma unroll
      for (int o = 32; o > 0; o >>= 1) ss += __shfl_xor(ss, o);
      if ((threadIdx.x & 63) == 0) red[threadIdx.x >> 6] = ss;
      __syncthreads();
      s *= rsqrtf(red[0] + red[1] + EPSF);
      __syncthreads();   // red must be consumed before next iteration writes
    }
    y[(size_t)n * CDIM + c] = s;

    x3 = x2; x2 = x1; x1 = x0; x0 = xn;
  }
}

// ---------------- gate projections: beta, decay (full f32) -----------------
__global__ __launch_bounds__(256) void gates_kernel(
    const f16* __restrict__ xh, const f16* __restrict__ xl,
    const float* __restrict__ w_b, const float* __restrict__ w_a,
    const float* __restrict__ dtb, const float* __restrict__ alog,
    float* __restrict__ beta, float* __restrict__ decay) {
  const int n = blockIdx.x, tid = threadIdx.x;
  __shared__ float xs[DM];
  __shared__ float red[32][8];
  {
    uint4 ph = ((const uint4*)(xh + (size_t)n * DM))[tid];
    uint4 pl = ((const uint4*)(xl + (size_t)n * DM))[tid];
    float h[8], l[8]; up8h(ph, h); up8h(pl, l);
    const int b = tid * 8;
#pragma unroll
    for (int j = 0; j < 8; j++) xs[b + j] = h[j] + l[j];
  }
  __syncthreads();
  const int hh = tid >> 3, part = tid & 7;
  const float* wrow =
      (hh < 16 ? w_b + (size_t)hh * DM : w_a + (size_t)(hh - 16) * DM) + part * 256;
  const float* xp = xs + part * 256;
  float sum = 0.f;
#pragma unroll 4
  for (int i = 0; i < 256; i += 4) {
    float4 p = *(const float4*)(wrow + i);
    sum += xp[i + 0] * p.x + xp[i + 1] * p.y + xp[i + 2] * p.z + xp[i + 3] * p.w;
  }
  red[hh][part] = sum;
  __syncthreads();
  if (tid < 32) {
    float d = 0.f;
#pragma unroll
    for (int p = 0; p < 8; p++) d += red[tid][p];
    if (tid < 16) {
      beta[(size_t)n * H_ + tid] = 1.f / (1.f + expf(-d));
    } else {
      const int h = tid - 16;
      float u = d + dtb[h];
      float sp = (u > 20.f) ? u : log1pf(expf(u));
      decay[(size_t)n * H_ + h] = expf(-expf(alog[h]) * sp);
    }
  }
}

// ---------------- delta-rule scan: 2-step rounds + packed f32 (R5) ---------
__global__ __launch_bounds__(256, 1) void scan_kernel(
    const float* __restrict__ y, const float* __restrict__ beta,
    const float* __restrict__ decay, float* __restrict__ o) {
  const int vb = blockIdx.x, h = blockIdx.y, b = blockIdx.z;
  const int tid = threadIdx.x;
  const int kg = tid & 15;
  const int vl = tid >> 4;

  __shared__ __align__(16) float sq[2][CGRP][128];
  __shared__ __align__(16) float sk[2][CGRP][128];
  __shared__ __align__(16) float sv[2][CGRP][16];
  __shared__ float sd[2][CGRP];
  __shared__ float sb[2][CGRP];

  const size_t rowbase = (size_t)b * T_ * CDIM;
  const int qoff = h * 128;
  const int koff = 2048 + h * 128;
  const int voff = 4096 + h * 128 + vb * 16;
  const float* bb = beta + (size_t)b * T_ * H_ + h;
  const float* db = decay + (size_t)b * T_ * H_ + h;
  float* ob = o + (size_t)b * T_ * (H_ * DV_) + h * 128 + vb * 16 + vl;

  const int ls = tid >> 4;       // staging: step within group
  const int lj = tid & 15;       // staging: float4 pair {lj*4, 64+lj*4}

  f32x2 S2[4];
#pragma unroll
  for (int j = 0; j < 4; j++) S2[j] = (f32x2){0.f, 0.f};

  float4 ga0, ga1, gb0, gb1, gv4;
  float gdd = 0.f, gbt = 0.f;

#define STAGE_ISSUE(t0)                                                      \
  {                                                                          \
    const float* r = y + rowbase + (size_t)((t0) + ls) * CDIM;               \
    ga0 = *(const float4*)(r + qoff + lj * 4);                               \
    ga1 = *(const float4*)(r + qoff + 64 + lj * 4);                          \
    gb0 = *(const float4*)(r + koff + lj * 4);                               \
    gb1 = *(const float4*)(r + koff + 64 + lj * 4);                          \
    if (tid < 64)                                                            \
      gv4 = *(const float4*)(y + rowbase + (size_t)((t0) + (tid >> 2)) * CDIM\
                             + voff + (tid & 3) * 4);                        \
    if (tid < 16) gdd = db[(size_t)((t0) + tid) * H_];                       \
    else if (tid < 32) gbt = bb[(size_t)((t0) + tid - 16) * H_];             \
  }

#define STAGE_WRITE(buf)                                                     \
  {                                                                          \
    *(float4*)&sq[buf][ls][lj * 4]      = ga0;                               \
    *(float4*)&sq[buf][ls][64 + lj * 4] = ga1;                               \
    *(float4*)&sk[buf][ls][lj * 4]      = gb0;                               \
    *(float4*)&sk[buf][ls][64 + lj * 4] = gb1;                               \
    if (tid < 64) *(float4*)&sv[buf][tid >> 2][(tid & 3) * 4] = gv4;         \
    if (tid < 16) sd[buf][tid] = gdd;                                        \
    else if (tid < 32) sb[buf][tid - 16] = gbt;                              \
  }

// float4 -> 2x f32x2 (sub-register rename, no VALU cost)
#define CVT2(dst, a, bfour)                                                  \
  {                                                                          \
    float4 _a = (a), _b = (bfour);                                           \
    dst[0] = (f32x2){_a.x, _a.y}; dst[1] = (f32x2){_a.z, _a.w};              \
    dst[2] = (f32x2){_b.x, _b.y}; dst[3] = (f32x2){_b.z, _b.w};              \
  }

// read BOTH steps of round r (steps 2r, 2r+1) into f32x2 registers
#define READ_PAIR(buf, r, Q1, K1, Q2, K2, P)                                 \
  {                                                                          \
    CVT2(Q1, *(const float4*)&sq[buf][2*(r)][kg * 4],                        \
             *(const float4*)&sq[buf][2*(r)][64 + kg * 4]);                  \
    CVT2(K1, *(const float4*)&sk[buf][2*(r)][kg * 4],                        \
             *(const float4*)&sk[buf][2*(r)][64 + kg * 4]);                  \
    CVT2(Q2, *(const float4*)&sq[buf][2*(r)+1][kg * 4],                      \
             *(const float4*)&sq[buf][2*(r)+1][64 + kg * 4]);                \
    CVT2(K2, *(const float4*)&sk[buf][2*(r)+1][kg * 4],                      \
             *(const float4*)&sk[buf][2*(r)+1][64 + kg * 4]);                \
    P##v1 = sv[buf][2*(r)][vl];   P##d1 = sd[buf][2*(r)];   P##b1 = sb[buf][2*(r)];   \
    P##v2 = sv[buf][2*(r)+1][vl]; P##d2 = sd[buf][2*(r)+1]; P##b2 = sb[buf][2*(r)+1]; \
  }

  // prime group 0
  STAGE_ISSUE(0);
  STAGE_WRITE(0);
  __syncthreads();

  f32x2 q1[4], k1[4], q2[4], k2[4];
  f32x2 nq1[4], nk1[4], nq2[4], nk2[4];
  float cv1, cd1, cb1, cv2, cd2, cb2;
  float nv1, nd1, nb1, nv2, nd2, nb2;
  float pp[CGRP];
  READ_PAIR(0, 0, q1, k1, q2, k2, c);

  const int NGRP = T_ / CGRP;
  const int NRND = CGRP / 2;
  for (int g = 0; g < NGRP; g++) {
    const int cbuf = g & 1, nbuf = cbuf ^ 1;
    const bool more = (g + 1 < NGRP);
    if (more) STAGE_ISSUE((g + 1) * CGRP);
#pragma unroll
    for (int r = 0; r < NRND; r++) {
      if (r < NRND - 1) READ_PAIR(cbuf, r + 1, nq1, nk1, nq2, nk2, n);
      // off-chain: m = k2 . k1 (packed tree: 2 pk_mul + 2 pk_fma + 1 pk_add)
      f32x2 ma = pkfma(k2[1], k1[1], k2[0] * k1[0]);
      f32x2 mb = pkfma(k2[3], k1[3], k2[2] * k1[2]);
      f32x2 mv = ma + mb;
      float mm = row_sum16(mv.x + mv.y);
      // chain: c1 = k1'S0 and w2 = k2'S0 in parallel (packed, 1 DPP depth)
      f32x2 ca = pkfma(S2[1], k1[1], S2[0] * k1[0]);
      f32x2 cb_ = pkfma(S2[3], k1[3], S2[2] * k1[2]);
      f32x2 cvv = ca + cb_;
      f32x2 wa = pkfma(S2[1], k2[1], S2[0] * k2[0]);
      f32x2 wb = pkfma(S2[3], k2[3], S2[2] * k2[2]);
      f32x2 wvv = wa + wb;
      float c1s = row_sum16(cvv.x + cvv.y);
      float w2s = row_sum16(wvv.x + wvv.y);
      // scalar chain
      const float u1 = fmaf(-cd1, c1s, cv1) * cb1;
      const float kv2 = fmaf(mm, u1, cd1 * w2s);
      const float u2 = fmaf(-cd2, kv2, cv2) * cb2;
      // S1 = d1*S0 + k1*u1 ; output partial for t1 (packed)
      {
        const f32x2 dv = (f32x2){cd1, cd1}, uv = (f32x2){u1, u1};
#pragma unroll
        for (int j = 0; j < 4; j++) S2[j] = pkfma(dv, S2[j], k1[j] * uv);
        f32x2 pa = pkfma(S2[1], q1[1], S2[0] * q1[0]);
        f32x2 pb = pkfma(S2[3], q1[3], S2[2] * q1[2]);
        f32x2 pv = pa + pb;
        pp[2 * r] = pv.x + pv.y;
      }
      // S2 = d2*S1 + k2*u2 ; output partial for t2 (packed)
      {
        const f32x2 dv = (f32x2){cd2, cd2}, uv = (f32x2){u2, u2};
#pragma unroll
        for (int j = 0; j < 4; j++) S2[j] = pkfma(dv, S2[j], k2[j] * uv);
        f32x2 pa = pkfma(S2[1], q2[1], S2[0] * q2[0]);
        f32x2 pb = pkfma(S2[3], q2[3], S2[2] * q2[2]);
        f32x2 pv = pa + pb;
        pp[2 * r + 1] = pv.x + pv.y;
      }
      if (r < NRND - 1) {
#pragma unroll
        for (int j = 0; j < 4; j++) {
          q1[j] = nq1[j]; k1[j] = nk1[j]; q2[j] = nq2[j]; k2[j] = nk2[j];
        }
        cv1 = nv1; cd1 = nd1; cb1 = nb1; cv2 = nv2; cd2 = nd2; cb2 = nb2;
      }
    }
    // deferred: 16 independent rowsums (pipelined DPP) + stores
#pragma unroll
    for (int s = 0; s < CGRP; s++) pp[s] = row_sum16(pp[s]);
    if (kg == 0) {
#pragma unroll
      for (int s = 0; s < CGRP; s++)
        ob[(size_t)(g * CGRP + s) * (H_ * DV_)] = pp[s];
    }
    if (more) {
      STAGE_WRITE(nbuf);
      __syncthreads();
      READ_PAIR(nbuf, 0, q1, k1, q2, k2, c);
    }
  }
#undef STAGE_ISSUE
#undef STAGE_WRITE
#undef READ_PAIR
#undef CVT2
}

// -------- gated RMSNorm + SiLU(z) gate -> fp16; 16 heads per block ---------
// R6: grid 65,536 -> 4,096 wgs; loop over heads with next-head prefetch.
__global__ __launch_bounds__(128) void norm_gate(
    const float* __restrict__ o, const bf16* __restrict__ z,
    const float* __restrict__ norm_w, f16* __restrict__ on_h) {
  const int n = blockIdx.x, v = threadIdx.x;
  const float nw = norm_w[v];
  __shared__ float red[2];
  const size_t base = (size_t)n * (H_ * DV_) + v;

  float ov = o[base];
  float zv = __bfloat162float(z[base]);
#pragma unroll 4
  for (int h = 0; h < H_; h++) {
    // prefetch next head while reducing this one
    float ovn = 0.f, zvn = 0.f;
    if (h + 1 < H_) {
      ovn = o[base + (h + 1) * 128];
      zvn = __bfloat162float(z[base + (h + 1) * 128]);
    }
    float ss = ov * ov;
#pragma unroll
    for (int w = 32; w > 0; w >>= 1) ss += __shfl_xor(ss, w);
    if ((v & 63) == 0) red[v >> 6] = ss;
    __syncthreads();
    const float ms = (red[0] + red[1]) * (1.f / 128.f);
    __syncthreads();   // red consumed before next head overwrites
    const float res = ov * rsqrtf(ms + EPSF) * nw * (zv / (1.f + expf(-zv)));
    on_h[base + h * 128] = (f16)res;
    ov = ovn; zv = zvn;
  }
}

// ---------------------------------------------------------------------------
extern "C" void kernel_launch(void* const* d_in, const int* in_sizes, int n_in,
                              void* d_out, int out_size, void* d_ws, size_t ws_size,
                              hipStream_t stream) {
  const int NT = B_ * T_;  // 4096
  char* ws = (char*)d_ws;
  int*   flag   = (int*)(ws + FLAG_OFF);
  float* dt_f   = (float*)(ws + DT_OFF);
  float* al_f   = (float*)(ws + AL_OFF);
  float* nw_f   = (float*)(ws + NW_OFF);
  float* cw_f   = (float*)(ws + CW_OFF);
  float* wb_f   = (float*)(ws + WBF_OFF);
  float* wa_f   = (float*)(ws + WAF_OFF);
  float* betab  = (float*)(ws + BETA_OFF);
  float* decayb = (float*)(ws + DEC_OFF);
  f16*   x_hi   = (f16*)(ws + XH_OFF);
  f16*   x_lo   = (f16*)(ws + XL_OFF);
  f16*   wq_hi  = (f16*)(ws + WQH_OFF);
  f16*   wz_h   = (f16*)(ws + WZ_OFF);
  float* mixed  = (float*)(ws + MIX_OFF);
  f16*   wout_h = (f16*)(ws + WOUT_OFF);
  bf16*  z      = (bf16*)(ws + Z_OFF);
  float* y      = (float*)(ws + Y_OFF);
  float* o      = (float*)(ws + O_OFF);
  f16*   on_h   = (f16*)(ws + ONH_OFF);

  // 0. detect input dtype (flag=1 -> f32)
  detect_dtype<<<1, 256, 0, stream>>>((const unsigned short*)d_in[0], flag);

  // 1. canonicalize everything in one launch
  canon_all<<<14383, 256, 0, stream>>>(
      d_in[0], d_in[1], d_in[2], d_in[3], d_in[4], d_in[5], d_in[6], d_in[7],
      d_in[8], d_in[9], ws, flag);

  // 2. gates (f32-precision beta/decay; x = fp16 hi+lo ~22-bit)
  gates_kernel<<<NT, 256, 0, stream>>>(x_hi, x_lo, wb_f, wa_f, dt_f, al_f,
                                       betab, decayb);
  // 3. mixed = x @ w_qkv^T  (single-term fp16) -> f32
  gemm_f16<0, 0><<<dim3(CDIM / 128, NT / 128), 256, 0, stream>>>(
      x_hi, (const f16*)0, wq_hi, mixed, NT, CDIM, DM, flag);
  // 4. z = x @ w_z^T  (single-term fp16) -> bf16
  gemm_f16<0, 1><<<dim3((H_ * DV_) / 128, NT / 128), 256, 0, stream>>>(
      x_hi, (const f16*)0, wz_h, z, NT, H_ * DV_, DM, flag);
  // 5. conv + SiLU + l2norm -> y f32 (16 rows/block, overlays dead x/wq/wz)
  conv_silu_norm<<<dim3(CDIM / 128, NT / CROWS), 128, 0, stream>>>(
      mixed, cw_f, y);
  // 6. delta-rule scan (2-step fused, packed f32) -> o f32 (overlays MIX)
  scan_kernel<<<dim3(DV_ / 16, H_, B_), 256, 0, stream>>>(y, betab, decayb, o);
  // 7. gated RMSNorm -> on fp16 (16 heads/block, overlays dead y)
  norm_gate<<<NT, 128, 0, stream>>>(o, z, nw_f, on_h);
  // 8. out = on @ w_out^T (single-term fp16, dual-dtype out)
  gemm_f16<0, 2><<<dim3(DM / 128, NT / 128), 256, 0, stream>>>(
      on_h, (const f16*)0, wout_h, d_out, NT, DM, H_ * DV_, flag);
}

// Round 8
// 867.552 us; speedup vs baseline: 1.3923x; 1.0130x over previous
//
#include <hip/hip_runtime.h>
#include <hip/hip_bf16.h>

#define B_   2
#define T_   2048
#define DM   2048
#define H_   16
#define DK_  128
#define DV_  128
#define CDIM 6144
#define EPSF 1e-6f
#define CGRP 16   // scan: timesteps staged per LDS group
#define CROWS 16  // conv: rows per block (R6)

typedef __hip_bfloat16 bf16;
typedef _Float16 f16;
typedef short bf16x8 __attribute__((ext_vector_type(8)));
typedef _Float16 f16x8 __attribute__((ext_vector_type(8)));
typedef float f32x4 __attribute__((ext_vector_type(4)));
typedef float f32x2 __attribute__((ext_vector_type(2)));

// ---- workspace layout (bytes); peak unchanged (R7 reuses dead WQL region) --
#define FLAG_OFF   0
#define DT_OFF     1024
#define AL_OFF     2048
#define NW_OFF     4096
#define CW_OFF     8192
#define WBF_OFF    131072
#define WAF_OFF    262144
#define BETA_OFF   393216
#define DEC_OFF    655360
#define XH_OFF     1048576
#define XL_OFF     17825792
#define WQH_OFF    34603008     // wqkv fp16 [6144][2048] -> 59,768,832
#define WZCAT_OFF  59768832     // R7: wz fp16 [2048][2048] right after wqkv
                                //     => one [8192][2048] weight matrix
#define MIX_OFF    101711872
#define WOUT_OFF   202375168
#define Z_OFF      210763776
#define Y_OFF      1048576
#define O_OFF      101711872
#define ONH_OFF    1048576

__device__ inline float bf2f(unsigned int u) {
  union { unsigned int i; float f; } v; v.i = u << 16; return v.f;
}
__device__ inline void up8(uint4 p, float* d) {
  d[0] = bf2f(p.x & 0xffffu); d[1] = bf2f(p.x >> 16);
  d[2] = bf2f(p.y & 0xffffu); d[3] = bf2f(p.y >> 16);
  d[4] = bf2f(p.z & 0xffffu); d[5] = bf2f(p.z >> 16);
  d[6] = bf2f(p.w & 0xffffu); d[7] = bf2f(p.w >> 16);
}
// fp16 x8 unpack (v_cvt_f32_f16)
__device__ inline void up8h(uint4 p, float* d) {
  union { unsigned int i; _Float16 h[2]; } c;
  c.i = p.x; d[0] = (float)c.h[0]; d[1] = (float)c.h[1];
  c.i = p.y; d[2] = (float)c.h[0]; d[3] = (float)c.h[1];
  c.i = p.z; d[4] = (float)c.h[0]; d[5] = (float)c.h[1];
  c.i = p.w; d[6] = (float)c.h[0]; d[7] = (float)c.h[1];
}
__device__ inline void gl2lds16(const void* g, void* lds) {
  __builtin_amdgcn_global_load_lds(
      (const __attribute__((address_space(1))) unsigned int*)g,
      (__attribute__((address_space(3))) unsigned int*)lds, 16, 0, 0);
}
// R4 (proven): explicit drain of the global_load_lds DMA queue before the
// staging barrier — fixed the R3 post-timing replay race at ~zero cost.
__device__ inline void stage_fence() {
  asm volatile("s_waitcnt vmcnt(0) lgkmcnt(0)" ::: "memory");
}

// packed 2xf32 FMA -> v_pk_fma_f32 (VOP3P, gfx90a+/gfx950)
__device__ inline f32x2 pkfma(f32x2 a, f32x2 b, f32x2 c) {
  return __builtin_elementwise_fma(a, b, c);
}

// DPP butterfly add over a 16-lane row — stays on the VALU pipe.
template <int CTRL>
__device__ inline float radd(float v) {
  int t = __builtin_amdgcn_update_dpp(0, __float_as_int(v), CTRL, 0xF, 0xF, true);
  return v + __int_as_float(t);
}
__device__ inline float row_sum16(float v) {
  v = radd<0xB1>(v);   // quad_perm [1,0,3,2] : + xor1
  v = radd<0x4E>(v);   // quad_perm [2,3,0,1] : + xor2
  v = radd<0x141>(v);  // row_half_mirror     : + xor4
  v = radd<0x140>(v);  // row_mirror          : + xor8
  return v;
}

// ---------------- dtype detector: flag=1 if inputs are f32 -----------------
__global__ __launch_bounds__(256) void detect_dtype(
    const unsigned short* __restrict__ xh, int* __restrict__ flag) {
  __shared__ int cnt;
  if (threadIdx.x == 0) cnt = 0;
  __syncthreads();
  int c = 0;
  for (int i = threadIdx.x; i < 8192; i += 256) {
    unsigned int e = (xh[i] >> 7) & 0xFFu;
    if (e > 140u) c++;
  }
  atomicAdd(&cnt, c);
  __syncthreads();
  if (threadIdx.x == 0) *flag = (cnt > 512) ? 1 : 0;
}

// ---------------- fused canonicalize: 10 segments in one launch ------------
// mode 0: ->f32, mode 3: ->fp16 single, mode 4: ->fp16 split(hi,lo)
__device__ inline void canon_seg(const void* in, char* d0, char* d1, int n,
                                 int mode, int f32in, int i) {
  if (i >= n) return;
  float v[8];
  if (f32in) {
    const float* f = (const float*)in;
    *(float4*)(v)     = *(const float4*)(f + i);
    *(float4*)(v + 4) = *(const float4*)(f + i + 4);
  } else {
    up8(*(const uint4*)((const bf16*)in + i), v);
  }
  if (mode == 0) {
    *(float4*)((float*)d0 + i)     = *(const float4*)(v);
    *(float4*)((float*)d0 + i + 4) = *(const float4*)(v + 4);
  } else if (mode == 3) {
    f16 t[8];
#pragma unroll
    for (int j = 0; j < 8; j++) t[j] = (f16)v[j];
    *(uint4*)((f16*)d0 + i) = *(const uint4*)t;
  } else {
    f16 th[8], tl[8];
#pragma unroll
    for (int j = 0; j < 8; j++) {
      th[j] = (f16)v[j];
      tl[j] = (f16)(v[j] - (float)th[j]);
    }
    *(uint4*)((f16*)d0 + i) = *(const uint4*)th;
    *(uint4*)((f16*)d1 + i) = *(const uint4*)tl;
  }
}

// block ranges (2048 elems per block):
// [0,1) dt | [1,2) al | [2,3) nw | [3,15) cw | [15,31) wb | [31,47) wa |
// [47,4143) x-split16 | [4143,10287) wqkv-fp16 | [10287,12335) wz-fp16(cat) |
// [12335,14383) wout-fp16
__global__ __launch_bounds__(256) void canon_all(
    const void* x, const void* wqkv, const void* cw, const void* wz,
    const void* wb, const void* wa, const void* dt, const void* al,
    const void* nw, const void* wout, char* ws, const int* __restrict__ flag) {
  const int bk = blockIdx.x;
  const int f32in = *flag;
  if (bk < 1)
    canon_seg(dt, ws + DT_OFF, 0, 16, 0, f32in, (bk - 0) * 2048 + threadIdx.x * 8);
  else if (bk < 2)
    canon_seg(al, ws + AL_OFF, 0, 16, 0, f32in, (bk - 1) * 2048 + threadIdx.x * 8);
  else if (bk < 3)
    canon_seg(nw, ws + NW_OFF, 0, 128, 0, f32in, (bk - 2) * 2048 + threadIdx.x * 8);
  else if (bk < 15)
    canon_seg(cw, ws + CW_OFF, 0, CDIM * 4, 0, f32in, (bk - 3) * 2048 + threadIdx.x * 8);
  else if (bk < 31)
    canon_seg(wb, ws + WBF_OFF, 0, H_ * DM, 0, f32in, (bk - 15) * 2048 + threadIdx.x * 8);
  else if (bk < 47)
    canon_seg(wa, ws + WAF_OFF, 0, H_ * DM, 0, f32in, (bk - 31) * 2048 + threadIdx.x * 8);
  else if (bk < 4143)
    canon_seg(x, ws + XH_OFF, ws + XL_OFF, B_ * T_ * DM, 4, f32in,
              (bk - 47) * 2048 + threadIdx.x * 8);
  else if (bk < 10287)
    canon_seg(wqkv, ws + WQH_OFF, 0, CDIM * DM, 3, f32in,
              (bk - 4143) * 2048 + threadIdx.x * 8);
  else if (bk < 12335)
    canon_seg(wz, ws + WZCAT_OFF, 0, H_ * DV_ * DM, 3, f32in,
              (bk - 10287) * 2048 + threadIdx.x * 8);
  else
    canon_seg(wout, ws + WOUT_OFF, 0, DM * H_ * DV_, 3, f32in,
              (bk - 12335) * 2048 + threadIdx.x * 8);
}

// -------- fp16 GEMM, m97 structure (generic). OMODE 2: flag?f32:bf16 -------
template <int OMODE>
__global__ __launch_bounds__(256) void gemm_f16(
    const f16* __restrict__ Ah, const f16* __restrict__ Bm,
    void* __restrict__ C, int M, int N, int K, const int* __restrict__ flag) {
  __shared__ __align__(16) f16 sAh[128 * 32];
  __shared__ __align__(16) f16 sB[128 * 32];
  const int tid  = threadIdx.x;
  const int wave = tid >> 6;
  const int lane = tid & 63;
  const int m0 = blockIdx.y * 128;
  const int n0 = blockIdx.x * 128;
  const int wm = (wave >> 1) * 64;
  const int wn = (wave & 1) * 64;
  const int lrow = lane & 15;
  const int kq   = lane >> 4;

  f32x4 acc[4][4];
#pragma unroll
  for (int i = 0; i < 4; i++)
#pragma unroll
    for (int j = 0; j < 4; j++) acc[i][j] = (f32x4){0.f, 0.f, 0.f, 0.f};

  const int row0 = tid >> 2;
  const int cb   = (tid & 3) * 8;
  const size_t aoff = (size_t)(m0 + row0) * K + cb;
  const size_t boff = (size_t)(n0 + row0) * K + cb;

  for (int k0 = 0; k0 < K; k0 += 32) {
    gl2lds16(Ah + aoff + k0,                  sAh + wave * 512);
    gl2lds16(Ah + aoff + k0 + (size_t)64 * K, sAh + 2048 + wave * 512);
    gl2lds16(Bm + boff + k0,                  sB + wave * 512);
    gl2lds16(Bm + boff + k0 + (size_t)64 * K, sB + 2048 + wave * 512);
    stage_fence();        // R4: unconditional DMA drain before the barrier
    __syncthreads();

    f16x8 afh[4], bfr[4];
#pragma unroll
    for (int i = 0; i < 4; i++) {
      afh[i] = *(const f16x8*)(sAh + (wm + i * 16 + lrow) * 32 + kq * 8);
      bfr[i] = *(const f16x8*)(sB + (wn + i * 16 + lrow) * 32 + kq * 8);
    }
#pragma unroll
    for (int i = 0; i < 4; i++)
#pragma unroll
      for (int j = 0; j < 4; j++)
        acc[i][j] = __builtin_amdgcn_mfma_f32_16x16x32_f16(afh[i], bfr[j], acc[i][j], 0, 0, 0);
    __syncthreads();
  }

  const int f32o = (OMODE == 0) ? 1 : ((OMODE == 2) ? *flag : 0);
#pragma unroll
  for (int i = 0; i < 4; i++) {
    const int r0 = m0 + wm + i * 16 + kq * 4;
#pragma unroll
    for (int j = 0; j < 4; j++) {
      const int c = n0 + wn + j * 16 + lrow;
#pragma unroll
      for (int r = 0; r < 4; r++) {
        const size_t idx = (size_t)(r0 + r) * N + c;
        if (f32o) ((float*)C)[idx] = acc[i][j][r];
        else      ((bf16*)C)[idx] = __float2bfloat16(acc[i][j][r]);
      }
    }
  }
}

// -------- R7: fused qkv+z GEMM. B = [wqkv ; wz] (8192 x 2048 fp16).
// Block-level output branch (128 | 6144): n0 < 6144 -> mixed f32 (stride
// 6144); n0 >= 6144 -> z bf16 (stride 2048). Same math as split GEMMs.
__global__ __launch_bounds__(256) void gemm_qkvz(
    const f16* __restrict__ Ah, const f16* __restrict__ Bm,
    float* __restrict__ Cmix, bf16* __restrict__ Cz, int M, int K) {
  __shared__ __align__(16) f16 sAh[128 * 32];
  __shared__ __align__(16) f16 sB[128 * 32];
  const int tid  = threadIdx.x;
  const int wave = tid >> 6;
  const int lane = tid & 63;
  const int m0 = blockIdx.y * 128;
  const int n0 = blockIdx.x * 128;
  const int wm = (wave >> 1) * 64;
  const int wn = (wave & 1) * 64;
  const int lrow = lane & 15;
  const int kq   = lane >> 4;

  f32x4 acc[4][4];
#pragma unroll
  for (int i = 0; i < 4; i++)
#pragma unroll
    for (int j = 0; j < 4; j++) acc[i][j] = (f32x4){0.f, 0.f, 0.f, 0.f};

  const int row0 = tid >> 2;
  const int cb   = (tid & 3) * 8;
  const size_t aoff = (size_t)(m0 + row0) * K + cb;
  const size_t boff = (size_t)(n0 + row0) * K + cb;

  for (int k0 = 0; k0 < K; k0 += 32) {
    gl2lds16(Ah + aoff + k0,                  sAh + wave * 512);
    gl2lds16(Ah + aoff + k0 + (size_t)64 * K, sAh + 2048 + wave * 512);
    gl2lds16(Bm + boff + k0,                  sB + wave * 512);
    gl2lds16(Bm + boff + k0 + (size_t)64 * K, sB + 2048 + wave * 512);
    stage_fence();
    __syncthreads();

    f16x8 afh[4], bfr[4];
#pragma unroll
    for (int i = 0; i < 4; i++) {
      afh[i] = *(const f16x8*)(sAh + (wm + i * 16 + lrow) * 32 + kq * 8);
      bfr[i] = *(const f16x8*)(sB + (wn + i * 16 + lrow) * 32 + kq * 8);
    }
#pragma unroll
    for (int i = 0; i < 4; i++)
#pragma unroll
      for (int j = 0; j < 4; j++)
        acc[i][j] = __builtin_amdgcn_mfma_f32_16x16x32_f16(afh[i], bfr[j], acc[i][j], 0, 0, 0);
    __syncthreads();
  }

  const bool zout = (n0 >= CDIM);   // block-uniform
#pragma unroll
  for (int i = 0; i < 4; i++) {
    const int r0 = m0 + wm + i * 16 + kq * 4;
#pragma unroll
    for (int j = 0; j < 4; j++) {
      const int c = n0 + wn + j * 16 + lrow;
#pragma unroll
      for (int r = 0; r < 4; r++) {
        if (zout)
          Cz[(size_t)(r0 + r) * (H_ * DV_) + (c - CDIM)] =
              __float2bfloat16(acc[i][j][r]);
        else
          Cmix[(size_t)(r0 + r) * CDIM + c] = acc[i][j][r];
      }
    }
  }
}

// -------- conv (causal, KW=4) + SiLU + per-head l2norm, 16 rows/block ------
__global__ __launch_bounds__(128) void conv_silu_norm(
    const float* __restrict__ mixed, const float* __restrict__ convw,
    float* __restrict__ y) {
  const int g  = blockIdx.x;             // 48 channel groups of 128
  const int n0 = blockIdx.y * CROWS;     // first row of this chunk
  const int c  = g * 128 + threadIdx.x;

  const float4 w = *(const float4*)(convw + (size_t)c * 4);
  __shared__ float red[2];

  float x1, x2, x3;
  {
    const int t0 = n0 & (T_ - 1);
    const float* mc = mixed + (size_t)n0 * CDIM + c;
    x1 = (t0 >= 1) ? mc[-CDIM]     : 0.f;
    x2 = (t0 >= 2) ? mc[-2 * CDIM] : 0.f;
    x3 = (t0 >= 3) ? mc[-3 * CDIM] : 0.f;
  }
  float x0 = mixed[(size_t)n0 * CDIM + c];

#pragma unroll 4
  for (int i = 0; i < CROWS; i++) {
    const int n = n0 + i;
    float xn = 0.f;
    if (i + 1 < CROWS) xn = mixed[(size_t)(n + 1) * CDIM + c];

    float a = x0 * w.w + x1 * w.z + x2 * w.y + x3 * w.x;
    float s = a / (1.f + expf(-a));

    if (g < 32) {
      float ss = s * s;
#pragma unroll
      for (int o = 32; o > 0; o >>= 1) ss += __shfl_xor(ss, o);
      if ((threadIdx.x & 63) == 0) red[threadIdx.x >> 6] = ss;
      __syncthreads();
      s *= rsqrtf(red[0] + red[1] + EPSF);
      __syncthreads();
    }
    y[(size_t)n * CDIM + c] = s;

    x3 = x2; x2 = x1; x1 = x0; x0 = xn;
  }
}

// ---------------- gate projections: beta, decay (full f32) -----------------
__global__ __launch_bounds__(256) void gates_kernel(
    const f16* __restrict__ xh, const f16* __restrict__ xl,
    const float* __restrict__ w_b, const float* __restrict__ w_a,
    const float* __restrict__ dtb, const float* __restrict__ alog,
    float* __restrict__ beta, float* __restrict__ decay) {
  const int n = blockIdx.x, tid = threadIdx.x;
  __shared__ float xs[DM];
  __shared__ float red[32][8];
  {
    uint4 ph = ((const uint4*)(xh + (size_t)n * DM))[tid];
    uint4 pl = ((const uint4*)(xl + (size_t)n * DM))[tid];
    float h[8], l[8]; up8h(ph, h); up8h(pl, l);
    const int b = tid * 8;
#pragma unroll
    for (int j = 0; j < 8; j++) xs[b + j] = h[j] + l[j];
  }
  __syncthreads();
  const int hh = tid >> 3, part = tid & 7;
  const float* wrow =
      (hh < 16 ? w_b + (size_t)hh * DM : w_a + (size_t)(hh - 16) * DM) + part * 256;
  const float* xp = xs + part * 256;
  float sum = 0.f;
#pragma unroll 4
  for (int i = 0; i < 256; i += 4) {
    float4 p = *(const float4*)(wrow + i);
    sum += xp[i + 0] * p.x + xp[i + 1] * p.y + xp[i + 2] * p.z + xp[i + 3] * p.w;
  }
  red[hh][part] = sum;
  __syncthreads();
  if (tid < 32) {
    float d = 0.f;
#pragma unroll
    for (int p = 0; p < 8; p++) d += red[tid][p];
    if (tid < 16) {
      beta[(size_t)n * H_ + tid] = 1.f / (1.f + expf(-d));
    } else {
      const int h = tid - 16;
      float u = d + dtb[h];
      float sp = (u > 20.f) ? u : log1pf(expf(u));
      decay[(size_t)n * H_ + h] = expf(-expf(alog[h]) * sp);
    }
  }
}

// ---------------- delta-rule scan: 2-step rounds + packed f32 (R5) ---------
__global__ __launch_bounds__(256, 1) void scan_kernel(
    const float* __restrict__ y, const float* __restrict__ beta,
    const float* __restrict__ decay, float* __restrict__ o) {
  const int vb = blockIdx.x, h = blockIdx.y, b = blockIdx.z;
  const int tid = threadIdx.x;
  const int kg = tid & 15;
  const int vl = tid >> 4;

  __shared__ __align__(16) float sq[2][CGRP][128];
  __shared__ __align__(16) float sk[2][CGRP][128];
  __shared__ __align__(16) float sv[2][CGRP][16];
  __shared__ float sd[2][CGRP];
  __shared__ float sb[2][CGRP];

  const size_t rowbase = (size_t)b * T_ * CDIM;
  const int qoff = h * 128;
  const int koff = 2048 + h * 128;
  const int voff = 4096 + h * 128 + vb * 16;
  const float* bb = beta + (size_t)b * T_ * H_ + h;
  const float* db = decay + (size_t)b * T_ * H_ + h;
  float* ob = o + (size_t)b * T_ * (H_ * DV_) + h * 128 + vb * 16 + vl;

  const int ls = tid >> 4;       // staging: step within group
  const int lj = tid & 15;       // staging: float4 pair {lj*4, 64+lj*4}

  f32x2 S2[4];
#pragma unroll
  for (int j = 0; j < 4; j++) S2[j] = (f32x2){0.f, 0.f};

  float4 ga0, ga1, gb0, gb1, gv4;
  float gdd = 0.f, gbt = 0.f;

#define STAGE_ISSUE(t0)                                                      \
  {                                                                          \
    const float* r = y + rowbase + (size_t)((t0) + ls) * CDIM;               \
    ga0 = *(const float4*)(r + qoff + lj * 4);                               \
    ga1 = *(const float4*)(r + qoff + 64 + lj * 4);                          \
    gb0 = *(const float4*)(r + koff + lj * 4);                               \
    gb1 = *(const float4*)(r + koff + 64 + lj * 4);                          \
    if (tid < 64)                                                            \
      gv4 = *(const float4*)(y + rowbase + (size_t)((t0) + (tid >> 2)) * CDIM\
                             + voff + (tid & 3) * 4);                        \
    if (tid < 16) gdd = db[(size_t)((t0) + tid) * H_];                       \
    else if (tid < 32) gbt = bb[(size_t)((t0) + tid - 16) * H_];             \
  }

#define STAGE_WRITE(buf)                                                     \
  {                                                                          \
    *(float4*)&sq[buf][ls][lj * 4]      = ga0;                               \
    *(float4*)&sq[buf][ls][64 + lj * 4] = ga1;                               \
    *(float4*)&sk[buf][ls][lj * 4]      = gb0;                               \
    *(float4*)&sk[buf][ls][64 + lj * 4] = gb1;                               \
    if (tid < 64) *(float4*)&sv[buf][tid >> 2][(tid & 3) * 4] = gv4;         \
    if (tid < 16) sd[buf][tid] = gdd;                                        \
    else if (tid < 32) sb[buf][tid - 16] = gbt;                              \
  }

// float4 -> 2x f32x2 (sub-register rename, no VALU cost)
#define CVT2(dst, a, bfour)                                                  \
  {                                                                          \
    float4 _a = (a), _b = (bfour);                                           \
    dst[0] = (f32x2){_a.x, _a.y}; dst[1] = (f32x2){_a.z, _a.w};              \
    dst[2] = (f32x2){_b.x, _b.y}; dst[3] = (f32x2){_b.z, _b.w};              \
  }

// read BOTH steps of round r (steps 2r, 2r+1) into f32x2 registers
#define READ_PAIR(buf, r, Q1, K1, Q2, K2, P)                                 \
  {                                                                          \
    CVT2(Q1, *(const float4*)&sq[buf][2*(r)][kg * 4],                        \
             *(const float4*)&sq[buf][2*(r)][64 + kg * 4]);                  \
    CVT2(K1, *(const float4*)&sk[buf][2*(r)][kg * 4],                        \
             *(const float4*)&sk[buf][2*(r)][64 + kg * 4]);                  \
    CVT2(Q2, *(const float4*)&sq[buf][2*(r)+1][kg * 4],                      \
             *(const float4*)&sq[buf][2*(r)+1][64 + kg * 4]);                \
    CVT2(K2, *(const float4*)&sk[buf][2*(r)+1][kg * 4],                      \
             *(const float4*)&sk[buf][2*(r)+1][64 + kg * 4]);                \
    P##v1 = sv[buf][2*(r)][vl];   P##d1 = sd[buf][2*(r)];   P##b1 = sb[buf][2*(r)];   \
    P##v2 = sv[buf][2*(r)+1][vl]; P##d2 = sd[buf][2*(r)+1]; P##b2 = sb[buf][2*(r)+1]; \
  }

  // prime group 0
  STAGE_ISSUE(0);
  STAGE_WRITE(0);
  __syncthreads();

  f32x2 q1[4], k1[4], q2[4], k2[4];
  f32x2 nq1[4], nk1[4], nq2[4], nk2[4];
  float cv1, cd1, cb1, cv2, cd2, cb2;
  float nv1, nd1, nb1, nv2, nd2, nb2;
  float pp[CGRP];
  READ_PAIR(0, 0, q1, k1, q2, k2, c);

  const int NGRP = T_ / CGRP;
  const int NRND = CGRP / 2;
  for (int g = 0; g < NGRP; g++) {
    const int cbuf = g & 1, nbuf = cbuf ^ 1;
    const bool more = (g + 1 < NGRP);
    if (more) STAGE_ISSUE((g + 1) * CGRP);
#pragma unroll
    for (int r = 0; r < NRND; r++) {
      if (r < NRND - 1) READ_PAIR(cbuf, r + 1, nq1, nk1, nq2, nk2, n);
      // off-chain: m = k2 . k1 (packed tree: 2 pk_mul + 2 pk_fma + 1 pk_add)
      f32x2 ma = pkfma(k2[1], k1[1], k2[0] * k1[0]);
      f32x2 mb = pkfma(k2[3], k1[3], k2[2] * k1[2]);
      f32x2 mv = ma + mb;
      float mm = row_sum16(mv.x + mv.y);
      // chain: c1 = k1'S0 and w2 = k2'S0 in parallel (packed, 1 DPP depth)
      f32x2 ca = pkfma(S2[1], k1[1], S2[0] * k1[0]);
      f32x2 cb_ = pkfma(S2[3], k1[3], S2[2] * k1[2]);
      f32x2 cvv = ca + cb_;
      f32x2 wa = pkfma(S2[1], k2[1], S2[0] * k2[0]);
      f32x2 wb = pkfma(S2[3], k2[3], S2[2] * k2[2]);
      f32x2 wvv = wa + wb;
      float c1s = row_sum16(cvv.x + cvv.y);
      float w2s = row_sum16(wvv.x + wvv.y);
      // scalar chain
      const float u1 = fmaf(-cd1, c1s, cv1) * cb1;
      const float kv2 = fmaf(mm, u1, cd1 * w2s);
      const float u2 = fmaf(-cd2, kv2, cv2) * cb2;
      // S1 = d1*S0 + k1*u1 ; output partial for t1 (packed)
      {
        const f32x2 dv = (f32x2){cd1, cd1}, uv = (f32x2){u1, u1};
#pragma unroll
        for (int j = 0; j < 4; j++) S2[j] = pkfma(dv, S2[j], k1[j] * uv);
        f32x2 pa = pkfma(S2[1], q1[1], S2[0] * q1[0]);
        f32x2 pb = pkfma(S2[3], q1[3], S2[2] * q1[2]);
        f32x2 pv = pa + pb;
        pp[2 * r] = pv.x + pv.y;
      }
      // S2 = d2*S1 + k2*u2 ; output partial for t2 (packed)
      {
        const f32x2 dv = (f32x2){cd2, cd2}, uv = (f32x2){u2, u2};
#pragma unroll
        for (int j = 0; j < 4; j++) S2[j] = pkfma(dv, S2[j], k2[j] * uv);
        f32x2 pa = pkfma(S2[1], q2[1], S2[0] * q2[0]);
        f32x2 pb = pkfma(S2[3], q2[3], S2[2] * q2[2]);
        f32x2 pv = pa + pb;
        pp[2 * r + 1] = pv.x + pv.y;
      }
      if (r < NRND - 1) {
#pragma unroll
        for (int j = 0; j < 4; j++) {
          q1[j] = nq1[j]; k1[j] = nk1[j]; q2[j] = nq2[j]; k2[j] = nk2[j];
        }
        cv1 = nv1; cd1 = nd1; cb1 = nb1; cv2 = nv2; cd2 = nd2; cb2 = nb2;
      }
    }
    // deferred: 16 independent rowsums (pipelined DPP) + stores
#pragma unroll
    for (int s = 0; s < CGRP; s++) pp[s] = row_sum16(pp[s]);
    if (kg == 0) {
#pragma unroll
      for (int s = 0; s < CGRP; s++)
        ob[(size_t)(g * CGRP + s) * (H_ * DV_)] = pp[s];
    }
    if (more) {
      STAGE_WRITE(nbuf);
      __syncthreads();
      READ_PAIR(nbuf, 0, q1, k1, q2, k2, c);
    }
  }
#undef STAGE_ISSUE
#undef STAGE_WRITE
#undef READ_PAIR
#undef CVT2
}

// -------- gated RMSNorm + SiLU(z) gate -> fp16; 16 heads per block ---------
__global__ __launch_bounds__(128) void norm_gate(
    const float* __restrict__ o, const bf16* __restrict__ z,
    const float* __restrict__ norm_w, f16* __restrict__ on_h) {
  const int n = blockIdx.x, v = threadIdx.x;
  const float nw = norm_w[v];
  __shared__ float red[2];
  const size_t base = (size_t)n * (H_ * DV_) + v;

  float ov = o[base];
  float zv = __bfloat162float(z[base]);
#pragma unroll 4
  for (int h = 0; h < H_; h++) {
    float ovn = 0.f, zvn = 0.f;
    if (h + 1 < H_) {
      ovn = o[base + (h + 1) * 128];
      zvn = __bfloat162float(z[base + (h + 1) * 128]);
    }
    float ss = ov * ov;
#pragma unroll
    for (int w = 32; w > 0; w >>= 1) ss += __shfl_xor(ss, w);
    if ((v & 63) == 0) red[v >> 6] = ss;
    __syncthreads();
    const float ms = (red[0] + red[1]) * (1.f / 128.f);
    __syncthreads();
    const float res = ov * rsqrtf(ms + EPSF) * nw * (zv / (1.f + expf(-zv)));
    on_h[base + h * 128] = (f16)res;
    ov = ovn; zv = zvn;
  }
}

// ---------------------------------------------------------------------------
extern "C" void kernel_launch(void* const* d_in, const int* in_sizes, int n_in,
                              void* d_out, int out_size, void* d_ws, size_t ws_size,
                              hipStream_t stream) {
  const int NT = B_ * T_;  // 4096
  char* ws = (char*)d_ws;
  int*   flag   = (int*)(ws + FLAG_OFF);
  float* dt_f   = (float*)(ws + DT_OFF);
  float* al_f   = (float*)(ws + AL_OFF);
  float* nw_f   = (float*)(ws + NW_OFF);
  float* cw_f   = (float*)(ws + CW_OFF);
  float* wb_f   = (float*)(ws + WBF_OFF);
  float* wa_f   = (float*)(ws + WAF_OFF);
  float* betab  = (float*)(ws + BETA_OFF);
  float* decayb = (float*)(ws + DEC_OFF);
  f16*   x_hi   = (f16*)(ws + XH_OFF);
  f16*   x_lo   = (f16*)(ws + XL_OFF);
  f16*   wqz_h  = (f16*)(ws + WQH_OFF);   // [8192][2048] = wqkv ++ wz
  float* mixed  = (float*)(ws + MIX_OFF);
  f16*   wout_h = (f16*)(ws + WOUT_OFF);
  bf16*  z      = (bf16*)(ws + Z_OFF);
  float* y      = (float*)(ws + Y_OFF);
  float* o      = (float*)(ws + O_OFF);
  f16*   on_h   = (f16*)(ws + ONH_OFF);

  // 0. detect input dtype (flag=1 -> f32)
  detect_dtype<<<1, 256, 0, stream>>>((const unsigned short*)d_in[0], flag);

  // 1. canonicalize everything in one launch (wz lands right after wqkv)
  canon_all<<<14383, 256, 0, stream>>>(
      d_in[0], d_in[1], d_in[2], d_in[3], d_in[4], d_in[5], d_in[6], d_in[7],
      d_in[8], d_in[9], ws, flag);

  // 2. gates (f32-precision beta/decay; x = fp16 hi+lo ~22-bit)
  gates_kernel<<<NT, 256, 0, stream>>>(x_hi, x_lo, wb_f, wa_f, dt_f, al_f,
                                       betab, decayb);
  // 3+4 fused. [mixed | z] = x @ [wqkv ; wz]^T  (N=8192, A staged once)
  gemm_qkvz<<<dim3((CDIM + H_ * DV_) / 128, NT / 128), 256, 0, stream>>>(
      x_hi, wqz_h, mixed, z, NT, DM);
  // 5. conv + SiLU + l2norm -> y f32 (16 rows/block, overlays dead x/wq)
  conv_silu_norm<<<dim3(CDIM / 128, NT / CROWS), 128, 0, stream>>>(
      mixed, cw_f, y);
  // 6. delta-rule scan (2-step fused, packed f32) -> o f32 (overlays MIX)
  scan_kernel<<<dim3(DV_ / 16, H_, B_), 256, 0, stream>>>(y, betab, decayb, o);
  // 7. gated RMSNorm -> on fp16 (16 heads/block, overlays dead y)
  norm_gate<<<NT, 128, 0, stream>>>(o, z, nw_f, on_h);
  // 8. out = on @ w_out^T (single-term fp16, dual-dtype out)
  gemm_f16<2><<<dim3(DM / 128, NT / 128), 256, 0, stream>>>(
      on_h, wout_h, d_out, NT, DM, H_ * DV_, flag);
}

// Round 9
// 852.670 us; speedup vs baseline: 1.4166x; 1.0175x over previous
//
#include <hip/hip_runtime.h>
#include <hip/hip_bf16.h>

#define B_   2
#define T_   2048
#define DM   2048
#define H_   16
#define DK_  128
#define DV_  128
#define CDIM 6144
#define EPSF 1e-6f
#define CGRP 16   // scan: timesteps staged per LDS group
#define CROWS 16  // conv: rows per block (R6)

typedef __hip_bfloat16 bf16;
typedef _Float16 f16;
typedef short bf16x8 __attribute__((ext_vector_type(8)));
typedef _Float16 f16x8 __attribute__((ext_vector_type(8)));
typedef float f32x4 __attribute__((ext_vector_type(4)));
typedef float f32x2 __attribute__((ext_vector_type(2)));

// ---- workspace layout (bytes); peak unchanged ------------------------------
#define FLAG_OFF   0
#define DT_OFF     1024
#define AL_OFF     2048
#define NW_OFF     4096
#define CW_OFF     8192
#define WBF_OFF    131072
#define WAF_OFF    262144
#define BETA_OFF   393216
#define DEC_OFF    655360
#define XH_OFF     1048576
#define XL_OFF     17825792
#define WQH_OFF    34603008     // wqkv fp16 [6144][2048] -> 59,768,832
#define WZCAT_OFF  59768832     // wz fp16 [2048][2048] right after wqkv
#define MIX_OFF    101711872    // R8: fp16 now (50 MB; was f32 100 MB)
#define WOUT_OFF   202375168
#define Z_OFF      210763776
#define Y_OFF      1048576
#define O_OFF      101711872    // o f32 overlays dead mixed region
#define ONH_OFF    1048576

__device__ inline float bf2f(unsigned int u) {
  union { unsigned int i; float f; } v; v.i = u << 16; return v.f;
}
__device__ inline void up8(uint4 p, float* d) {
  d[0] = bf2f(p.x & 0xffffu); d[1] = bf2f(p.x >> 16);
  d[2] = bf2f(p.y & 0xffffu); d[3] = bf2f(p.y >> 16);
  d[4] = bf2f(p.z & 0xffffu); d[5] = bf2f(p.z >> 16);
  d[6] = bf2f(p.w & 0xffffu); d[7] = bf2f(p.w >> 16);
}
// fp16 x8 unpack (v_cvt_f32_f16)
__device__ inline void up8h(uint4 p, float* d) {
  union { unsigned int i; _Float16 h[2]; } c;
  c.i = p.x; d[0] = (float)c.h[0]; d[1] = (float)c.h[1];
  c.i = p.y; d[2] = (float)c.h[0]; d[3] = (float)c.h[1];
  c.i = p.z; d[4] = (float)c.h[0]; d[5] = (float)c.h[1];
  c.i = p.w; d[6] = (float)c.h[0]; d[7] = (float)c.h[1];
}
__device__ inline void gl2lds16(const void* g, void* lds) {
  __builtin_amdgcn_global_load_lds(
      (const __attribute__((address_space(1))) unsigned int*)g,
      (__attribute__((address_space(3))) unsigned int*)lds, 16, 0, 0);
}
// R4 (proven): explicit DMA drain before the staging barrier.
__device__ inline void stage_fence() {
  asm volatile("s_waitcnt vmcnt(0) lgkmcnt(0)" ::: "memory");
}

// packed 2xf32 FMA -> v_pk_fma_f32 (VOP3P)
__device__ inline f32x2 pkfma(f32x2 a, f32x2 b, f32x2 c) {
  return __builtin_elementwise_fma(a, b, c);
}

// R8: bijective XCD-aware block swizzle (m157/m204 form; valid: nwg%8==0).
// Consecutive logical tiles (sharing A/B panels) land on the same XCD's L2.
__device__ inline void xcd_swz(int& bx, int& by) {
  const int gx = gridDim.x;
  const int nwg = gx * gridDim.y;
  const int flat = by * gx + bx;
  const int q = nwg >> 3;
  const int wg = (flat & 7) * q + (flat >> 3);
  bx = wg % gx;
  by = wg / gx;
}

// DPP butterfly add over a 16-lane row — stays on the VALU pipe.
template <int CTRL>
__device__ inline float radd(float v) {
  int t = __builtin_amdgcn_update_dpp(0, __float_as_int(v), CTRL, 0xF, 0xF, true);
  return v + __int_as_float(t);
}
__device__ inline float row_sum16(float v) {
  v = radd<0xB1>(v);   // quad_perm [1,0,3,2] : + xor1
  v = radd<0x4E>(v);   // quad_perm [2,3,0,1] : + xor2
  v = radd<0x141>(v);  // row_half_mirror     : + xor4
  v = radd<0x140>(v);  // row_mirror          : + xor8
  return v;
}

// ---------------- dtype detector: flag=1 if inputs are f32 -----------------
__global__ __launch_bounds__(256) void detect_dtype(
    const unsigned short* __restrict__ xh, int* __restrict__ flag) {
  __shared__ int cnt;
  if (threadIdx.x == 0) cnt = 0;
  __syncthreads();
  int c = 0;
  for (int i = threadIdx.x; i < 8192; i += 256) {
    unsigned int e = (xh[i] >> 7) & 0xFFu;
    if (e > 140u) c++;
  }
  atomicAdd(&cnt, c);
  __syncthreads();
  if (threadIdx.x == 0) *flag = (cnt > 512) ? 1 : 0;
}

// ---------------- fused canonicalize: 10 segments in one launch ------------
// mode 0: ->f32, mode 3: ->fp16 single, mode 4: ->fp16 split(hi,lo)
__device__ inline void canon_seg(const void* in, char* d0, char* d1, int n,
                                 int mode, int f32in, int i) {
  if (i >= n) return;
  float v[8];
  if (f32in) {
    const float* f = (const float*)in;
    *(float4*)(v)     = *(const float4*)(f + i);
    *(float4*)(v + 4) = *(const float4*)(f + i + 4);
  } else {
    up8(*(const uint4*)((const bf16*)in + i), v);
  }
  if (mode == 0) {
    *(float4*)((float*)d0 + i)     = *(const float4*)(v);
    *(float4*)((float*)d0 + i + 4) = *(const float4*)(v + 4);
  } else if (mode == 3) {
    f16 t[8];
#pragma unroll
    for (int j = 0; j < 8; j++) t[j] = (f16)v[j];
    *(uint4*)((f16*)d0 + i) = *(const uint4*)t;
  } else {
    f16 th[8], tl[8];
#pragma unroll
    for (int j = 0; j < 8; j++) {
      th[j] = (f16)v[j];
      tl[j] = (f16)(v[j] - (float)th[j]);
    }
    *(uint4*)((f16*)d0 + i) = *(const uint4*)th;
    *(uint4*)((f16*)d1 + i) = *(const uint4*)tl;
  }
}

// block ranges (2048 elems per block):
// [0,1) dt | [1,2) al | [2,3) nw | [3,15) cw | [15,31) wb | [31,47) wa |
// [47,4143) x-split16 | [4143,10287) wqkv-fp16 | [10287,12335) wz-fp16(cat) |
// [12335,14383) wout-fp16
__global__ __launch_bounds__(256) void canon_all(
    const void* x, const void* wqkv, const void* cw, const void* wz,
    const void* wb, const void* wa, const void* dt, const void* al,
    const void* nw, const void* wout, char* ws, const int* __restrict__ flag) {
  const int bk = blockIdx.x;
  const int f32in = *flag;
  if (bk < 1)
    canon_seg(dt, ws + DT_OFF, 0, 16, 0, f32in, (bk - 0) * 2048 + threadIdx.x * 8);
  else if (bk < 2)
    canon_seg(al, ws + AL_OFF, 0, 16, 0, f32in, (bk - 1) * 2048 + threadIdx.x * 8);
  else if (bk < 3)
    canon_seg(nw, ws + NW_OFF, 0, 128, 0, f32in, (bk - 2) * 2048 + threadIdx.x * 8);
  else if (bk < 15)
    canon_seg(cw, ws + CW_OFF, 0, CDIM * 4, 0, f32in, (bk - 3) * 2048 + threadIdx.x * 8);
  else if (bk < 31)
    canon_seg(wb, ws + WBF_OFF, 0, H_ * DM, 0, f32in, (bk - 15) * 2048 + threadIdx.x * 8);
  else if (bk < 47)
    canon_seg(wa, ws + WAF_OFF, 0, H_ * DM, 0, f32in, (bk - 31) * 2048 + threadIdx.x * 8);
  else if (bk < 4143)
    canon_seg(x, ws + XH_OFF, ws + XL_OFF, B_ * T_ * DM, 4, f32in,
              (bk - 47) * 2048 + threadIdx.x * 8);
  else if (bk < 10287)
    canon_seg(wqkv, ws + WQH_OFF, 0, CDIM * DM, 3, f32in,
              (bk - 4143) * 2048 + threadIdx.x * 8);
  else if (bk < 12335)
    canon_seg(wz, ws + WZCAT_OFF, 0, H_ * DV_ * DM, 3, f32in,
              (bk - 10287) * 2048 + threadIdx.x * 8);
  else
    canon_seg(wout, ws + WOUT_OFF, 0, DM * H_ * DV_, 3, f32in,
              (bk - 12335) * 2048 + threadIdx.x * 8);
}

// -------- fp16 GEMM, m97 structure (generic). OMODE 2: flag?f32:bf16 -------
template <int OMODE>
__global__ __launch_bounds__(256) void gemm_f16(
    const f16* __restrict__ Ah, const f16* __restrict__ Bm,
    void* __restrict__ C, int M, int N, int K, const int* __restrict__ flag) {
  __shared__ __align__(16) f16 sAh[128 * 32];
  __shared__ __align__(16) f16 sB[128 * 32];
  const int tid  = threadIdx.x;
  const int wave = tid >> 6;
  const int lane = tid & 63;
  int bx = blockIdx.x, by = blockIdx.y;
  xcd_swz(bx, by);                        // R8: L2 locality
  const int m0 = by * 128;
  const int n0 = bx * 128;
  const int wm = (wave >> 1) * 64;
  const int wn = (wave & 1) * 64;
  const int lrow = lane & 15;
  const int kq   = lane >> 4;

  f32x4 acc[4][4];
#pragma unroll
  for (int i = 0; i < 4; i++)
#pragma unroll
    for (int j = 0; j < 4; j++) acc[i][j] = (f32x4){0.f, 0.f, 0.f, 0.f};

  const int row0 = tid >> 2;
  const int cb   = (tid & 3) * 8;
  const size_t aoff = (size_t)(m0 + row0) * K + cb;
  const size_t boff = (size_t)(n0 + row0) * K + cb;

  for (int k0 = 0; k0 < K; k0 += 32) {
    gl2lds16(Ah + aoff + k0,                  sAh + wave * 512);
    gl2lds16(Ah + aoff + k0 + (size_t)64 * K, sAh + 2048 + wave * 512);
    gl2lds16(Bm + boff + k0,                  sB + wave * 512);
    gl2lds16(Bm + boff + k0 + (size_t)64 * K, sB + 2048 + wave * 512);
    stage_fence();        // R4: unconditional DMA drain before the barrier
    __syncthreads();

    f16x8 afh[4], bfr[4];
#pragma unroll
    for (int i = 0; i < 4; i++) {
      afh[i] = *(const f16x8*)(sAh + (wm + i * 16 + lrow) * 32 + kq * 8);
      bfr[i] = *(const f16x8*)(sB + (wn + i * 16 + lrow) * 32 + kq * 8);
    }
#pragma unroll
    for (int i = 0; i < 4; i++)
#pragma unroll
      for (int j = 0; j < 4; j++)
        acc[i][j] = __builtin_amdgcn_mfma_f32_16x16x32_f16(afh[i], bfr[j], acc[i][j], 0, 0, 0);
    __syncthreads();
  }

  const int f32o = (OMODE == 0) ? 1 : ((OMODE == 2) ? *flag : 0);
#pragma unroll
  for (int i = 0; i < 4; i++) {
    const int r0 = m0 + wm + i * 16 + kq * 4;
#pragma unroll
    for (int j = 0; j < 4; j++) {
      const int c = n0 + wn + j * 16 + lrow;
#pragma unroll
      for (int r = 0; r < 4; r++) {
        const size_t idx = (size_t)(r0 + r) * N + c;
        if (f32o) ((float*)C)[idx] = acc[i][j][r];
        else      ((bf16*)C)[idx] = __float2bfloat16(acc[i][j][r]);
      }
    }
  }
}

// -------- R7: fused qkv+z GEMM. B = [wqkv ; wz] (8192 x 2048 fp16).
// R8: mixed output is fp16 (halves C-write bytes); XCD swizzle for L2.
__global__ __launch_bounds__(256) void gemm_qkvz(
    const f16* __restrict__ Ah, const f16* __restrict__ Bm,
    f16* __restrict__ Cmix, bf16* __restrict__ Cz, int M, int K) {
  __shared__ __align__(16) f16 sAh[128 * 32];
  __shared__ __align__(16) f16 sB[128 * 32];
  const int tid  = threadIdx.x;
  const int wave = tid >> 6;
  const int lane = tid & 63;
  int bx = blockIdx.x, by = blockIdx.y;
  xcd_swz(bx, by);                        // R8: L2 locality
  const int m0 = by * 128;
  const int n0 = bx * 128;
  const int wm = (wave >> 1) * 64;
  const int wn = (wave & 1) * 64;
  const int lrow = lane & 15;
  const int kq   = lane >> 4;

  f32x4 acc[4][4];
#pragma unroll
  for (int i = 0; i < 4; i++)
#pragma unroll
    for (int j = 0; j < 4; j++) acc[i][j] = (f32x4){0.f, 0.f, 0.f, 0.f};

  const int row0 = tid >> 2;
  const int cb   = (tid & 3) * 8;
  const size_t aoff = (size_t)(m0 + row0) * K + cb;
  const size_t boff = (size_t)(n0 + row0) * K + cb;

  for (int k0 = 0; k0 < K; k0 += 32) {
    gl2lds16(Ah + aoff + k0,                  sAh + wave * 512);
    gl2lds16(Ah + aoff + k0 + (size_t)64 * K, sAh + 2048 + wave * 512);
    gl2lds16(Bm + boff + k0,                  sB + wave * 512);
    gl2lds16(Bm + boff + k0 + (size_t)64 * K, sB + 2048 + wave * 512);
    stage_fence();
    __syncthreads();

    f16x8 afh[4], bfr[4];
#pragma unroll
    for (int i = 0; i < 4; i++) {
      afh[i] = *(const f16x8*)(sAh + (wm + i * 16 + lrow) * 32 + kq * 8);
      bfr[i] = *(const f16x8*)(sB + (wn + i * 16 + lrow) * 32 + kq * 8);
    }
#pragma unroll
    for (int i = 0; i < 4; i++)
#pragma unroll
      for (int j = 0; j < 4; j++)
        acc[i][j] = __builtin_amdgcn_mfma_f32_16x16x32_f16(afh[i], bfr[j], acc[i][j], 0, 0, 0);
    __syncthreads();
  }

  const bool zout = (n0 >= CDIM);   // block-uniform (6144 = 48*128)
#pragma unroll
  for (int i = 0; i < 4; i++) {
    const int r0 = m0 + wm + i * 16 + kq * 4;
#pragma unroll
    for (int j = 0; j < 4; j++) {
      const int c = n0 + wn + j * 16 + lrow;
#pragma unroll
      for (int r = 0; r < 4; r++) {
        if (zout)
          Cz[(size_t)(r0 + r) * (H_ * DV_) + (c - CDIM)] =
              __float2bfloat16(acc[i][j][r]);
        else
          Cmix[(size_t)(r0 + r) * CDIM + c] = (f16)acc[i][j][r];
      }
    }
  }
}

// -------- conv (causal, KW=4) + SiLU + per-head l2norm, 16 rows/block ------
// R8: mixed is fp16 (halved read traffic).
__global__ __launch_bounds__(128) void conv_silu_norm(
    const f16* __restrict__ mixed, const float* __restrict__ convw,
    float* __restrict__ y) {
  const int g  = blockIdx.x;             // 48 channel groups of 128
  const int n0 = blockIdx.y * CROWS;     // first row of this chunk
  const int c  = g * 128 + threadIdx.x;

  const float4 w = *(const float4*)(convw + (size_t)c * 4);
  __shared__ float red[2];

  float x1, x2, x3;
  {
    const int t0 = n0 & (T_ - 1);
    const f16* mc = mixed + (size_t)n0 * CDIM + c;
    x1 = (t0 >= 1) ? (float)mc[-CDIM]     : 0.f;
    x2 = (t0 >= 2) ? (float)mc[-2 * CDIM] : 0.f;
    x3 = (t0 >= 3) ? (float)mc[-3 * CDIM] : 0.f;
  }
  float x0 = (float)mixed[(size_t)n0 * CDIM + c];

#pragma unroll 4
  for (int i = 0; i < CROWS; i++) {
    const int n = n0 + i;
    float xn = 0.f;
    if (i + 1 < CROWS) xn = (float)mixed[(size_t)(n + 1) * CDIM + c];

    float a = x0 * w.w + x1 * w.z + x2 * w.y + x3 * w.x;
    float s = a / (1.f + expf(-a));

    if (g < 32) {
      float ss = s * s;
#pragma unroll
      for (int o = 32; o > 0; o >>= 1) ss += __shfl_xor(ss, o);
      if ((threadIdx.x & 63) == 0) red[threadIdx.x >> 6] = ss;
      __syncthreads();
      s *= rsqrtf(red[0] + red[1] + EPSF);
      __syncthreads();
    }
    y[(size_t)n * CDIM + c] = s;

    x3 = x2; x2 = x1; x1 = x0; x0 = xn;
  }
}

// ---------------- gate projections: beta, decay (full f32) -----------------
__global__ __launch_bounds__(256) void gates_kernel(
    const f16* __restrict__ xh, const f16* __restrict__ xl,
    const float* __restrict__ w_b, const float* __restrict__ w_a,
    const float* __restrict__ dtb, const float* __restrict__ alog,
    float* __restrict__ beta, float* __restrict__ decay) {
  const int n = blockIdx.x, tid = threadIdx.x;
  __shared__ float xs[DM];
  __shared__ float red[32][8];
  {
    uint4 ph = ((const uint4*)(xh + (size_t)n * DM))[tid];
    uint4 pl = ((const uint4*)(xl + (size_t)n * DM))[tid];
    float h[8], l[8]; up8h(ph, h); up8h(pl, l);
    const int b = tid * 8;
#pragma unroll
    for (int j = 0; j < 8; j++) xs[b + j] = h[j] + l[j];
  }
  __syncthreads();
  const int hh = tid >> 3, part = tid & 7;
  const float* wrow =
      (hh < 16 ? w_b + (size_t)hh * DM : w_a + (size_t)(hh - 16) * DM) + part * 256;
  const float* xp = xs + part * 256;
  float sum = 0.f;
#pragma unroll 4
  for (int i = 0; i < 256; i += 4) {
    float4 p = *(const float4*)(wrow + i);
    sum += xp[i + 0] * p.x + xp[i + 1] * p.y + xp[i + 2] * p.z + xp[i + 3] * p.w;
  }
  red[hh][part] = sum;
  __syncthreads();
  if (tid < 32) {
    float d = 0.f;
#pragma unroll
    for (int p = 0; p < 8; p++) d += red[tid][p];
    if (tid < 16) {
      beta[(size_t)n * H_ + tid] = 1.f / (1.f + expf(-d));
    } else {
      const int h = tid - 16;
      float u = d + dtb[h];
      float sp = (u > 20.f) ? u : log1pf(expf(u));
      decay[(size_t)n * H_ + h] = expf(-expf(alog[h]) * sp);
    }
  }
}

// ---------------- delta-rule scan: 2-step rounds + packed f32 (R5) ---------
__global__ __launch_bounds__(256, 1) void scan_kernel(
    const float* __restrict__ y, const float* __restrict__ beta,
    const float* __restrict__ decay, float* __restrict__ o) {
  const int vb = blockIdx.x, h = blockIdx.y, b = blockIdx.z;
  const int tid = threadIdx.x;
  const int kg = tid & 15;
  const int vl = tid >> 4;

  __shared__ __align__(16) float sq[2][CGRP][128];
  __shared__ __align__(16) float sk[2][CGRP][128];
  __shared__ __align__(16) float sv[2][CGRP][16];
  __shared__ float sd[2][CGRP];
  __shared__ float sb[2][CGRP];

  const size_t rowbase = (size_t)b * T_ * CDIM;
  const int qoff = h * 128;
  const int koff = 2048 + h * 128;
  const int voff = 4096 + h * 128 + vb * 16;
  const float* bb = beta + (size_t)b * T_ * H_ + h;
  const float* db = decay + (size_t)b * T_ * H_ + h;
  float* ob = o + (size_t)b * T_ * (H_ * DV_) + h * 128 + vb * 16 + vl;

  const int ls = tid >> 4;       // staging: step within group
  const int lj = tid & 15;       // staging: float4 pair {lj*4, 64+lj*4}

  f32x2 S2[4];
#pragma unroll
  for (int j = 0; j < 4; j++) S2[j] = (f32x2){0.f, 0.f};

  float4 ga0, ga1, gb0, gb1, gv4;
  float gdd = 0.f, gbt = 0.f;

#define STAGE_ISSUE(t0)                                                      \
  {                                                                          \
    const float* r = y + rowbase + (size_t)((t0) + ls) * CDIM;               \
    ga0 = *(const float4*)(r + qoff + lj * 4);                               \
    ga1 = *(const float4*)(r + qoff + 64 + lj * 4);                          \
    gb0 = *(const float4*)(r + koff + lj * 4);                               \
    gb1 = *(const float4*)(r + koff + 64 + lj * 4);                          \
    if (tid < 64)                                                            \
      gv4 = *(const float4*)(y + rowbase + (size_t)((t0) + (tid >> 2)) * CDIM\
                             + voff + (tid & 3) * 4);                        \
    if (tid < 16) gdd = db[(size_t)((t0) + tid) * H_];                       \
    else if (tid < 32) gbt = bb[(size_t)((t0) + tid - 16) * H_];             \
  }

#define STAGE_WRITE(buf)                                                     \
  {                                                                          \
    *(float4*)&sq[buf][ls][lj * 4]      = ga0;                               \
    *(float4*)&sq[buf][ls][64 + lj * 4] = ga1;                               \
    *(float4*)&sk[buf][ls][lj * 4]      = gb0;                               \
    *(float4*)&sk[buf][ls][64 + lj * 4] = gb1;                               \
    if (tid < 64) *(float4*)&sv[buf][tid >> 2][(tid & 3) * 4] = gv4;         \
    if (tid < 16) sd[buf][tid] = gdd;                                        \
    else if (tid < 32) sb[buf][tid - 16] = gbt;                              \
  }

// float4 -> 2x f32x2 (sub-register rename, no VALU cost)
#define CVT2(dst, a, bfour)                                                  \
  {                                                                          \
    float4 _a = (a), _b = (bfour);                                           \
    dst[0] = (f32x2){_a.x, _a.y}; dst[1] = (f32x2){_a.z, _a.w};              \
    dst[2] = (f32x2){_b.x, _b.y}; dst[3] = (f32x2){_b.z, _b.w};              \
  }

// read BOTH steps of round r (steps 2r, 2r+1) into f32x2 registers
#define READ_PAIR(buf, r, Q1, K1, Q2, K2, P)                                 \
  {                                                                          \
    CVT2(Q1, *(const float4*)&sq[buf][2*(r)][kg * 4],                        \
             *(const float4*)&sq[buf][2*(r)][64 + kg * 4]);                  \
    CVT2(K1, *(const float4*)&sk[buf][2*(r)][kg * 4],                        \
             *(const float4*)&sk[buf][2*(r)][64 + kg * 4]);                  \
    CVT2(Q2, *(const float4*)&sq[buf][2*(r)+1][kg * 4],                      \
             *(const float4*)&sq[buf][2*(r)+1][64 + kg * 4]);                \
    CVT2(K2, *(const float4*)&sk[buf][2*(r)+1][kg * 4],                      \
             *(const float4*)&sk[buf][2*(r)+1][64 + kg * 4]);                \
    P##v1 = sv[buf][2*(r)][vl];   P##d1 = sd[buf][2*(r)];   P##b1 = sb[buf][2*(r)];   \
    P##v2 = sv[buf][2*(r)+1][vl]; P##d2 = sd[buf][2*(r)+1]; P##b2 = sb[buf][2*(r)+1]; \
  }

  // prime group 0
  STAGE_ISSUE(0);
  STAGE_WRITE(0);
  __syncthreads();

  f32x2 q1[4], k1[4], q2[4], k2[4];
  f32x2 nq1[4], nk1[4], nq2[4], nk2[4];
  float cv1, cd1, cb1, cv2, cd2, cb2;
  float nv1, nd1, nb1, nv2, nd2, nb2;
  float pp[CGRP];
  READ_PAIR(0, 0, q1, k1, q2, k2, c);

  const int NGRP = T_ / CGRP;
  const int NRND = CGRP / 2;
  for (int g = 0; g < NGRP; g++) {
    const int cbuf = g & 1, nbuf = cbuf ^ 1;
    const bool more = (g + 1 < NGRP);
    if (more) STAGE_ISSUE((g + 1) * CGRP);
#pragma unroll
    for (int r = 0; r < NRND; r++) {
      if (r < NRND - 1) READ_PAIR(cbuf, r + 1, nq1, nk1, nq2, nk2, n);
      // off-chain: m = k2 . k1 (packed tree)
      f32x2 ma = pkfma(k2[1], k1[1], k2[0] * k1[0]);
      f32x2 mb = pkfma(k2[3], k1[3], k2[2] * k1[2]);
      f32x2 mv = ma + mb;
      float mm = row_sum16(mv.x + mv.y);
      // chain: c1 = k1'S0 and w2 = k2'S0 in parallel (packed, 1 DPP depth)
      f32x2 ca = pkfma(S2[1], k1[1], S2[0] * k1[0]);
      f32x2 cb_ = pkfma(S2[3], k1[3], S2[2] * k1[2]);
      f32x2 cvv = ca + cb_;
      f32x2 wa = pkfma(S2[1], k2[1], S2[0] * k2[0]);
      f32x2 wb = pkfma(S2[3], k2[3], S2[2] * k2[2]);
      f32x2 wvv = wa + wb;
      float c1s = row_sum16(cvv.x + cvv.y);
      float w2s = row_sum16(wvv.x + wvv.y);
      // scalar chain
      const float u1 = fmaf(-cd1, c1s, cv1) * cb1;
      const float kv2 = fmaf(mm, u1, cd1 * w2s);
      const float u2 = fmaf(-cd2, kv2, cv2) * cb2;
      // S1 = d1*S0 + k1*u1 ; output partial for t1 (packed)
      {
        const f32x2 dv = (f32x2){cd1, cd1}, uv = (f32x2){u1, u1};
#pragma unroll
        for (int j = 0; j < 4; j++) S2[j] = pkfma(dv, S2[j], k1[j] * uv);
        f32x2 pa = pkfma(S2[1], q1[1], S2[0] * q1[0]);
        f32x2 pb = pkfma(S2[3], q1[3], S2[2] * q1[2]);
        f32x2 pv = pa + pb;
        pp[2 * r] = pv.x + pv.y;
      }
      // S2 = d2*S1 + k2*u2 ; output partial for t2 (packed)
      {
        const f32x2 dv = (f32x2){cd2, cd2}, uv = (f32x2){u2, u2};
#pragma unroll
        for (int j = 0; j < 4; j++) S2[j] = pkfma(dv, S2[j], k2[j] * uv);
        f32x2 pa = pkfma(S2[1], q2[1], S2[0] * q2[0]);
        f32x2 pb = pkfma(S2[3], q2[3], S2[2] * q2[2]);
        f32x2 pv = pa + pb;
        pp[2 * r + 1] = pv.x + pv.y;
      }
      if (r < NRND - 1) {
#pragma unroll
        for (int j = 0; j < 4; j++) {
          q1[j] = nq1[j]; k1[j] = nk1[j]; q2[j] = nq2[j]; k2[j] = nk2[j];
        }
        cv1 = nv1; cd1 = nd1; cb1 = nb1; cv2 = nv2; cd2 = nd2; cb2 = nb2;
      }
    }
    // deferred: 16 independent rowsums (pipelined DPP) + stores
#pragma unroll
    for (int s = 0; s < CGRP; s++) pp[s] = row_sum16(pp[s]);
    if (kg == 0) {
#pragma unroll
      for (int s = 0; s < CGRP; s++)
        ob[(size_t)(g * CGRP + s) * (H_ * DV_)] = pp[s];
    }
    if (more) {
      STAGE_WRITE(nbuf);
      __syncthreads();
      READ_PAIR(nbuf, 0, q1, k1, q2, k2, c);
    }
  }
#undef STAGE_ISSUE
#undef STAGE_WRITE
#undef READ_PAIR
#undef CVT2
}

// -------- gated RMSNorm + SiLU(z) gate -> fp16; 16 heads per block ---------
__global__ __launch_bounds__(128) void norm_gate(
    const float* __restrict__ o, const bf16* __restrict__ z,
    const float* __restrict__ norm_w, f16* __restrict__ on_h) {
  const int n = blockIdx.x, v = threadIdx.x;
  const float nw = norm_w[v];
  __shared__ float red[2];
  const size_t base = (size_t)n * (H_ * DV_) + v;

  float ov = o[base];
  float zv = __bfloat162float(z[base]);
#pragma unroll 4
  for (int h = 0; h < H_; h++) {
    float ovn = 0.f, zvn = 0.f;
    if (h + 1 < H_) {
      ovn = o[base + (h + 1) * 128];
      zvn = __bfloat162float(z[base + (h + 1) * 128]);
    }
    float ss = ov * ov;
#pragma unroll
    for (int w = 32; w > 0; w >>= 1) ss += __shfl_xor(ss, w);
    if ((v & 63) == 0) red[v >> 6] = ss;
    __syncthreads();
    const float ms = (red[0] + red[1]) * (1.f / 128.f);
    __syncthreads();
    const float res = ov * rsqrtf(ms + EPSF) * nw * (zv / (1.f + expf(-zv)));
    on_h[base + h * 128] = (f16)res;
    ov = ovn; zv = zvn;
  }
}

// ---------------------------------------------------------------------------
extern "C" void kernel_launch(void* const* d_in, const int* in_sizes, int n_in,
                              void* d_out, int out_size, void* d_ws, size_t ws_size,
                              hipStream_t stream) {
  const int NT = B_ * T_;  // 4096
  char* ws = (char*)d_ws;
  int*   flag   = (int*)(ws + FLAG_OFF);
  float* dt_f   = (float*)(ws + DT_OFF);
  float* al_f   = (float*)(ws + AL_OFF);
  float* nw_f   = (float*)(ws + NW_OFF);
  float* cw_f   = (float*)(ws + CW_OFF);
  float* wb_f   = (float*)(ws + WBF_OFF);
  float* wa_f   = (float*)(ws + WAF_OFF);
  float* betab  = (float*)(ws + BETA_OFF);
  float* decayb = (float*)(ws + DEC_OFF);
  f16*   x_hi   = (f16*)(ws + XH_OFF);
  f16*   x_lo   = (f16*)(ws + XL_OFF);
  f16*   wqz_h  = (f16*)(ws + WQH_OFF);   // [8192][2048] = wqkv ++ wz
  f16*   mixed  = (f16*)(ws + MIX_OFF);   // R8: fp16
  f16*   wout_h = (f16*)(ws + WOUT_OFF);
  bf16*  z      = (bf16*)(ws + Z_OFF);
  float* y      = (float*)(ws + Y_OFF);
  float* o      = (float*)(ws + O_OFF);
  f16*   on_h   = (f16*)(ws + ONH_OFF);

  // 0. detect input dtype (flag=1 -> f32)
  detect_dtype<<<1, 256, 0, stream>>>((const unsigned short*)d_in[0], flag);

  // 1. canonicalize everything in one launch (wz lands right after wqkv)
  canon_all<<<14383, 256, 0, stream>>>(
      d_in[0], d_in[1], d_in[2], d_in[3], d_in[4], d_in[5], d_in[6], d_in[7],
      d_in[8], d_in[9], ws, flag);

  // 2. gates (f32-precision beta/decay; x = fp16 hi+lo ~22-bit)
  gates_kernel<<<NT, 256, 0, stream>>>(x_hi, x_lo, wb_f, wa_f, dt_f, al_f,
                                       betab, decayb);
  // 3+4 fused. [mixed | z] = x @ [wqkv ; wz]^T  (N=8192, fp16 mixed out)
  gemm_qkvz<<<dim3((CDIM + H_ * DV_) / 128, NT / 128), 256, 0, stream>>>(
      x_hi, wqz_h, mixed, z, NT, DM);
  // 5. conv + SiLU + l2norm -> y f32 (16 rows/block; fp16 mixed in)
  conv_silu_norm<<<dim3(CDIM / 128, NT / CROWS), 128, 0, stream>>>(
      mixed, cw_f, y);
  // 6. delta-rule scan (2-step fused, packed f32) -> o f32 (overlays MIX)
  scan_kernel<<<dim3(DV_ / 16, H_, B_), 256, 0, stream>>>(y, betab, decayb, o);
  // 7. gated RMSNorm -> on fp16 (16 heads/block, overlays dead y)
  norm_gate<<<NT, 128, 0, stream>>>(o, z, nw_f, on_h);
  // 8. out = on @ w_out^T (single-term fp16, dual-dtype out)
  gemm_f16<2><<<dim3(DM / 128, NT / 128), 256, 0, stream>>>(
      on_h, wout_h, d_out, NT, DM, H_ * DV_, flag);
}